// Round 1
// baseline (2900.127 us; speedup 1.0000x reference)
//
#include <hip/hip_runtime.h>
#include <hip/hip_bf16.h>

#define NN 100000
#define EE 1600000
#define GG 128
#define DD 128
#define LL 3
#define EAA 7
#define BN_EPS 1e-5f

// ---------------------------------------------------------------------------
// K0: h[i,:] = node_emb[x[i],:]; vn[g,:] = vn_emb[0,:]
// ---------------------------------------------------------------------------
__global__ __launch_bounds__(256) void init_kernel(
    const int* __restrict__ x, const float* __restrict__ node_emb,
    const float* __restrict__ vn_emb, float* __restrict__ h,
    float* __restrict__ vn)
{
    long i = (long)blockIdx.x * 256 + threadIdx.x;
    if (i < (long)NN * DD) {
        int node = (int)(i >> 7), d = (int)(i & 127);
        h[i] = node_emb[(long)x[node] * DD + d];
    }
    if (i < GG * DD) vn[i] = vn_emb[i & 127];
}

// ---------------------------------------------------------------------------
// K1: in-place h -> h_in = h + vn[batch];  agg = (1+eps_l)*h_in;
//     optional vt[g] += sum of h_in rows (segment-sum with run-length fusion)
// Block: 256 threads = 2 row-groups x 128 cols; 16 rows per block.
// ---------------------------------------------------------------------------
#define R1 8
__global__ __launch_bounds__(256) void hin_kernel(
    float* __restrict__ hbuf,            // in: h, out: h_in (in place, d_out)
    const float* __restrict__ vn,
    const int* __restrict__ batch,
    const float* __restrict__ eps,
    float* __restrict__ agg,
    float* __restrict__ vt,
    int layer, int accum_vt)
{
    const int d  = threadIdx.x & 127;
    const int rg = threadIdx.x >> 7;          // 0..1
    const float epl = 1.0f + eps[layer];
    const long row0 = (long)blockIdx.x * (R1 * 2);

    float vacc = 0.0f;
    int   vb   = -1;
    #pragma unroll
    for (int r = 0; r < R1; ++r) {
        long row = row0 + rg + 2 * r;
        if (row >= NN) break;
        int b = batch[row];
        long idx = row * DD + d;
        float hv = hbuf[idx] + vn[(long)b * DD + d];
        hbuf[idx] = hv;
        agg[idx]  = epl * hv;
        if (accum_vt) {
            if (b != vb) {
                if (vb >= 0) atomicAdd(&vt[(long)vb * DD + d], vacc);
                vb = b; vacc = 0.0f;
            }
            vacc += hv;
        }
    }
    if (accum_vt && vb >= 0) atomicAdd(&vt[(long)vb * DD + d], vacc);
}

// ---------------------------------------------------------------------------
// K2: per edge e: msg = relu(h_in[src] + edge_attr[e] @ edge_W[l] + edge_b[l])
//     agg[dst] += msg   (fp32 global atomics, coalesced 512B per edge)
// Block: 256 threads = 2 edge-lanes x 128 cols. Edge weights in registers.
// ---------------------------------------------------------------------------
#define EPB 64
__global__ __launch_bounds__(256) void edge_kernel(
    const float* __restrict__ h_in,
    const int* __restrict__ ei,
    const float* __restrict__ eattr,
    const float* __restrict__ eW,
    const float* __restrict__ eb,
    float* __restrict__ agg,
    int layer)
{
    const int d    = threadIdx.x & 127;
    const int esub = threadIdx.x >> 7;        // 0..1
    float w[EAA];
    #pragma unroll
    for (int a = 0; a < EAA; ++a) w[a] = eW[layer * EAA * DD + a * DD + d];
    const float bias = eb[layer * DD + d];

    const long base = (long)blockIdx.x * EPB;
    for (int k = esub; k < EPB; k += 2) {
        long e = base + k;
        if (e >= EE) break;
        int s = ei[e];
        int t = ei[EE + e];
        float acc = bias;
        #pragma unroll
        for (int a = 0; a < EAA; ++a)
            acc = fmaf(eattr[e * EAA + a], w[a], acc);
        float m = h_in[(long)s * DD + d] + acc;
        m = m > 0.0f ? m : 0.0f;
        atomicAdd(&agg[(long)t * DD + d], m);
    }
}

// ---------------------------------------------------------------------------
// K3: per node row z (=agg): u = relu(bn1(z@W1 + b1)); h2 = bn2(u@W2 + b2);
//     h = relu(h2) unless last layer. 8 rows per 256-thread block.
// ---------------------------------------------------------------------------
#define T3 8
__global__ __launch_bounds__(256) void mlp_kernel(
    const float* __restrict__ z_in,
    const float* __restrict__ W1, const float* __restrict__ b1,
    const float* __restrict__ g1, const float* __restrict__ be1,
    const float* __restrict__ m1, const float* __restrict__ v1,
    const float* __restrict__ W2, const float* __restrict__ b2,
    const float* __restrict__ g2, const float* __restrict__ be2,
    const float* __restrict__ m2, const float* __restrict__ v2,
    float* __restrict__ h_out, int layer, int do_relu)
{
    __shared__ float zs[T3][DD];
    __shared__ float us[T3][2 * DD];
    const long row0 = (long)blockIdx.x * T3;

    for (int i = threadIdx.x; i < T3 * DD; i += 256) {
        int r = i >> 7, c = i & 127;
        zs[r][c] = z_in[(row0 + r) * DD + c];
    }
    __syncthreads();

    // phase A: 256 outputs, each thread owns one column j of W1
    {
        const int j = threadIdx.x;
        const float* W1l = W1 + (long)layer * DD * 2 * DD;
        float acc[T3];
        #pragma unroll
        for (int r = 0; r < T3; ++r) acc[r] = 0.0f;
        for (int k = 0; k < DD; ++k) {
            float w = W1l[k * 2 * DD + j];
            #pragma unroll
            for (int r = 0; r < T3; ++r) acc[r] = fmaf(zs[r][k], w, acc[r]);
        }
        const long o = (long)layer * 2 * DD + j;
        float sc = g1[o] / sqrtf(v1[o] + BN_EPS);
        float sh = be1[o] - m1[o] * sc;
        float bb = b1[o];
        #pragma unroll
        for (int r = 0; r < T3; ++r) {
            float t = (acc[r] + bb) * sc + sh;
            us[r][j] = t > 0.0f ? t : 0.0f;
        }
    }
    __syncthreads();

    // phase B: 128 outputs, 2 threads-halves x 4 rows each
    {
        const int j  = threadIdx.x & 127;
        const int rh = threadIdx.x >> 7;      // 0..1
        const float* W2l = W2 + (long)layer * 2 * DD * DD;
        float acc[T3 / 2];
        #pragma unroll
        for (int r = 0; r < T3 / 2; ++r) acc[r] = 0.0f;
        for (int k = 0; k < 2 * DD; ++k) {
            float w = W2l[k * DD + j];
            #pragma unroll
            for (int r = 0; r < T3 / 2; ++r)
                acc[r] = fmaf(us[rh + 2 * r][k], w, acc[r]);
        }
        const long o = (long)layer * DD + j;
        float sc = g2[o] / sqrtf(v2[o] + BN_EPS);
        float sh = be2[o] - m2[o] * sc;
        float bb = b2[o];
        #pragma unroll
        for (int r = 0; r < T3 / 2; ++r) {
            int rr = rh + 2 * r;
            float t = (acc[r] + bb) * sc + sh;
            if (do_relu) t = t > 0.0f ? t : 0.0f;
            h_out[(row0 + rr) * DD + j] = t;
        }
    }
}

// ---------------------------------------------------------------------------
// K4: virtual-node MLP. One block per graph g.
//     row = vt[g] + vn[g]; t = relu(bn1(row@vnW1+b1)); vn[g] = relu(bn2(t@vnW2+b2))
// ---------------------------------------------------------------------------
__global__ __launch_bounds__(256) void vn_kernel(
    const float* __restrict__ vt, float* __restrict__ vn,
    const float* __restrict__ W1, const float* __restrict__ b1,
    const float* __restrict__ g1, const float* __restrict__ be1,
    const float* __restrict__ m1, const float* __restrict__ v1,
    const float* __restrict__ W2, const float* __restrict__ b2,
    const float* __restrict__ g2, const float* __restrict__ be2,
    const float* __restrict__ m2, const float* __restrict__ v2,
    int layer)
{
    __shared__ float row[DD];
    __shared__ float u[2 * DD];
    const int g = blockIdx.x;
    const int t = threadIdx.x;

    if (t < DD) row[t] = vt[(long)g * DD + t] + vn[(long)g * DD + t];
    __syncthreads();

    {
        const float* W = W1 + (long)layer * DD * 2 * DD;
        float acc = 0.0f;
        for (int k = 0; k < DD; ++k) acc = fmaf(row[k], W[k * 2 * DD + t], acc);
        const long o = (long)layer * 2 * DD + t;
        float sc = g1[o] / sqrtf(v1[o] + BN_EPS);
        float sh = be1[o] - m1[o] * sc;
        float val = (acc + b1[o]) * sc + sh;
        u[t] = val > 0.0f ? val : 0.0f;
    }
    __syncthreads();

    if (t < DD) {
        const float* W = W2 + (long)layer * 2 * DD * DD;
        float acc = 0.0f;
        for (int k = 0; k < 2 * DD; ++k) acc = fmaf(u[k], W[k * DD + t], acc);
        const long o = (long)layer * DD + t;
        float sc = g2[o] / sqrtf(v2[o] + BN_EPS);
        float sh = be2[o] - m2[o] * sc;
        float val = (acc + b2[o]) * sc + sh;
        vn[(long)g * DD + t] = val > 0.0f ? val : 0.0f;
    }
}

// ---------------------------------------------------------------------------
extern "C" void kernel_launch(void* const* d_in, const int* in_sizes, int n_in,
                              void* d_out, int out_size, void* d_ws, size_t ws_size,
                              hipStream_t stream)
{
    const int*   x       = (const int*)  d_in[0];
    const int*   ei      = (const int*)  d_in[1];
    const float* eattr   = (const float*)d_in[2];
    const int*   batch   = (const int*)  d_in[3];
    const float* node_emb= (const float*)d_in[4];
    const float* vn_emb  = (const float*)d_in[5];
    const float* edge_W  = (const float*)d_in[6];
    const float* edge_b  = (const float*)d_in[7];
    const float* eps     = (const float*)d_in[8];
    const float* mlp_W1  = (const float*)d_in[9];
    const float* mlp_b1  = (const float*)d_in[10];
    const float* mbn_g   = (const float*)d_in[11];
    const float* mbn_b   = (const float*)d_in[12];
    const float* mbn_m   = (const float*)d_in[13];
    const float* mbn_v   = (const float*)d_in[14];
    const float* mlp_W2  = (const float*)d_in[15];
    const float* mlp_b2  = (const float*)d_in[16];
    const float* bn_g    = (const float*)d_in[17];
    const float* bn_b    = (const float*)d_in[18];
    const float* bn_m    = (const float*)d_in[19];
    const float* bn_v    = (const float*)d_in[20];
    const float* vn_W1   = (const float*)d_in[21];
    const float* vn_b1   = (const float*)d_in[22];
    const float* vbn1_g  = (const float*)d_in[23];
    const float* vbn1_b  = (const float*)d_in[24];
    const float* vbn1_m  = (const float*)d_in[25];
    const float* vbn1_v  = (const float*)d_in[26];
    const float* vn_W2   = (const float*)d_in[27];
    const float* vn_b2   = (const float*)d_in[28];
    const float* vbn2_g  = (const float*)d_in[29];
    const float* vbn2_b  = (const float*)d_in[30];
    const float* vbn2_m  = (const float*)d_in[31];
    const float* vbn2_v  = (const float*)d_in[32];

    float* h = (float*)d_out;                    // h / h_in (in place per layer)
    char*  ws = (char*)d_ws;
    const size_t NB = (size_t)NN * DD * sizeof(float);   // 51.2 MB
    float* agg = (float*)ws;                             // [N, D] -> z
    float* vn  = (float*)(ws + NB);                      // [G, D]
    float* vt  = (float*)(ws + NB + (size_t)GG * DD * sizeof(float)); // [G, D]

    // K0: init h and vn
    {
        long total = (long)NN * DD;
        int grid = (int)((total + 255) / 256);
        init_kernel<<<grid, 256, 0, stream>>>(x, node_emb, vn_emb, h, vn);
    }

    for (int l = 0; l < LL; ++l) {
        int accum = (l < LL - 1) ? 1 : 0;
        if (accum)
            hipMemsetAsync(vt, 0, (size_t)GG * DD * sizeof(float), stream);

        // K1: h -> h_in (in place), agg = (1+eps)h_in, vt atomics
        hin_kernel<<<NN / (R1 * 2), 256, 0, stream>>>(
            h, vn, batch, eps, agg, vt, l, accum);

        // K2: edge messages + scatter-add into agg
        edge_kernel<<<(EE + EPB - 1) / EPB, 256, 0, stream>>>(
            h, ei, eattr, edge_W, edge_b, agg, l);

        // K3: node MLP -> new h
        mlp_kernel<<<NN / T3, 256, 0, stream>>>(
            agg, mlp_W1, mlp_b1, mbn_g, mbn_b, mbn_m, mbn_v,
            mlp_W2, mlp_b2, bn_g, bn_b, bn_m, bn_v,
            h, l, accum /* relu except last layer */);

        // K4: virtual-node update
        if (accum)
            vn_kernel<<<GG, 256, 0, stream>>>(
                vt, vn, vn_W1, vn_b1, vbn1_g, vbn1_b, vbn1_m, vbn1_v,
                vn_W2, vn_b2, vbn2_g, vbn2_b, vbn2_m, vbn2_v, l);
    }
}

// Round 2
// 1828.739 us; speedup vs baseline: 1.5859x; 1.5859x over previous
//
#include <hip/hip_runtime.h>
#include <hip/hip_bf16.h>

#define NN 100000
#define EE 1600000
#define GG 128
#define DD 128
#define LL 3
#define EAA 7
#define BN_EPS 1e-5f

// ---------------------------------------------------------------------------
// K0: h[i,:] = node_emb[x[i],:]; vn[g,:] = vn_emb[0,:]
// ---------------------------------------------------------------------------
__global__ __launch_bounds__(256) void init_kernel(
    const int* __restrict__ x, const float* __restrict__ node_emb,
    const float* __restrict__ vn_emb, float* __restrict__ h,
    float* __restrict__ vn)
{
    long i = (long)blockIdx.x * 256 + threadIdx.x;
    if (i < (long)NN * DD) {
        int node = (int)(i >> 7), d = (int)(i & 127);
        h[i] = node_emb[(long)x[node] * DD + d];
    }
    if (i < GG * DD) vn[i] = vn_emb[i & 127];
}

// ---------------------------------------------------------------------------
// K1: in-place h -> h_in = h + vn[batch]; optional agg=(1+eps)h_in (atomic
// fallback path only); optional vt[g] += h_in rows (run-length fused atomics)
// ---------------------------------------------------------------------------
#define R1 8
__global__ __launch_bounds__(256) void hin_kernel(
    float* __restrict__ hbuf,
    const float* __restrict__ vn,
    const int* __restrict__ batch,
    const float* __restrict__ eps,
    float* __restrict__ agg,
    float* __restrict__ vt,
    int layer, int accum_vt, int write_agg)
{
    const int d  = threadIdx.x & 127;
    const int rg = threadIdx.x >> 7;
    const float epl = 1.0f + eps[layer];
    const long row0 = (long)blockIdx.x * (R1 * 2);

    float vacc = 0.0f;
    int   vb   = -1;
    #pragma unroll
    for (int r = 0; r < R1; ++r) {
        long row = row0 + rg + 2 * r;
        if (row >= NN) break;
        int b = batch[row];
        long idx = row * DD + d;
        float hv = hbuf[idx] + vn[(long)b * DD + d];
        hbuf[idx] = hv;
        if (write_agg) agg[idx] = epl * hv;
        if (accum_vt) {
            if (b != vb) {
                if (vb >= 0) atomicAdd(&vt[(long)vb * DD + d], vacc);
                vb = b; vacc = 0.0f;
            }
            vacc += hv;
        }
    }
    if (accum_vt && vb >= 0) atomicAdd(&vt[(long)vb * DD + d], vacc);
}

// ---------------------------------------------------------------------------
// CSR build: count -> scan -> scatter. Built once, reused by all 3 layers.
// ---------------------------------------------------------------------------
__global__ __launch_bounds__(256) void count_kernel(
    const int* __restrict__ ei, int* __restrict__ deg)
{
    long e = (long)blockIdx.x * 256 + threadIdx.x;
    if (e < EE) atomicAdd(&deg[ei[EE + e]], 1);
}

__global__ __launch_bounds__(1024) void scan_a(
    const int* __restrict__ deg, int* __restrict__ rp, int* __restrict__ partials)
{
    __shared__ int s[1024];
    int t = threadIdx.x;
    long i = (long)blockIdx.x * 1024 + t;
    int v = (i < NN) ? deg[i] : 0;
    s[t] = v;
    __syncthreads();
    for (int off = 1; off < 1024; off <<= 1) {
        int u = (t >= off) ? s[t - off] : 0;
        __syncthreads();
        s[t] += u;
        __syncthreads();
    }
    if (i < NN) rp[i] = s[t] - v;                 // block-local exclusive
    if (t == 1023) partials[blockIdx.x] = s[1023];
}

__global__ void scan_b(int* __restrict__ partials, int nb)
{
    if (threadIdx.x == 0) {
        int run = 0;
        for (int i = 0; i < nb; ++i) { int v = partials[i]; partials[i] = run; run += v; }
    }
}

__global__ __launch_bounds__(1024) void scan_c(
    int* __restrict__ rp, int* __restrict__ fill, const int* __restrict__ partials)
{
    long i = (long)blockIdx.x * 1024 + threadIdx.x;
    if (i < NN) {
        int v = rp[i] + partials[blockIdx.x];
        rp[i] = v;
        fill[i] = v;
    }
    if (i == 0) rp[NN] = EE;
}

__global__ __launch_bounds__(256) void scatter_kernel(
    const int* __restrict__ ei, const float* __restrict__ eattr,
    int* __restrict__ fill, float* __restrict__ rec, int* __restrict__ eid_perm)
{
    long e = (long)blockIdx.x * 256 + threadIdx.x;
    if (e >= EE) return;
    int dst = ei[EE + e];
    int pos = atomicAdd(&fill[dst], 1);
    if (rec) {
        float* r = rec + (long)pos * 8;
        #pragma unroll
        for (int a = 0; a < EAA; ++a) r[a] = eattr[e * EAA + a];
        r[7] = __int_as_float(ei[e]);             // src packed in slot 7
    } else {
        eid_perm[pos] = (int)e;
    }
}

// ---------------------------------------------------------------------------
// K2 (CSR): per dst node n: z[n] = (1+eps)h_in[n] + sum relu(h_in[src] + e@W+b)
// 2 nodes per 256-thread block; no atomics, one coalesced write per node.
// ---------------------------------------------------------------------------
__global__ __launch_bounds__(256) void gin_agg_kernel(
    const float* __restrict__ h_in,
    const int* __restrict__ rp,
    const float* __restrict__ rec,
    const int* __restrict__ eid_perm,
    const int* __restrict__ ei,
    const float* __restrict__ eattr,
    const float* __restrict__ eW, const float* __restrict__ eb,
    const float* __restrict__ eps,
    float* __restrict__ agg, int layer)
{
    const int d    = threadIdx.x & 127;
    const int half = threadIdx.x >> 7;
    const long n   = (long)blockIdx.x * 2 + half;

    float w[EAA];
    #pragma unroll
    for (int a = 0; a < EAA; ++a) w[a] = eW[layer * EAA * DD + a * DD + d];
    const float bias = eb[layer * DD + d];
    const float epl  = 1.0f + eps[layer];

    float acc = epl * h_in[n * DD + d];
    const int p0 = rp[n], p1 = rp[n + 1];

    if (rec) {
        for (int p = p0; p < p1; ++p) {
            const float4* r4 = (const float4*)(rec + (long)p * 8);
            float4 ra = r4[0];
            float4 rb = r4[1];
            int src = __float_as_int(rb.w);
            float ea = bias;
            ea = fmaf(ra.x, w[0], ea); ea = fmaf(ra.y, w[1], ea);
            ea = fmaf(ra.z, w[2], ea); ea = fmaf(ra.w, w[3], ea);
            ea = fmaf(rb.x, w[4], ea); ea = fmaf(rb.y, w[5], ea);
            ea = fmaf(rb.z, w[6], ea);
            float m = h_in[(long)src * DD + d] + ea;
            acc += m > 0.0f ? m : 0.0f;
        }
    } else {
        for (int p = p0; p < p1; ++p) {
            int e = eid_perm[p];
            int src = ei[e];
            float ea = bias;
            #pragma unroll
            for (int a = 0; a < EAA; ++a)
                ea = fmaf(eattr[(long)e * EAA + a], w[a], ea);
            float m = h_in[(long)src * DD + d] + ea;
            acc += m > 0.0f ? m : 0.0f;
        }
    }
    agg[n * DD + d] = acc;
}

// ---------------------------------------------------------------------------
// K2 fallback (atomic path, only if workspace too small for CSR)
// ---------------------------------------------------------------------------
#define EPB 64
__global__ __launch_bounds__(256) void edge_kernel(
    const float* __restrict__ h_in,
    const int* __restrict__ ei,
    const float* __restrict__ eattr,
    const float* __restrict__ eW,
    const float* __restrict__ eb,
    float* __restrict__ agg,
    int layer)
{
    const int d    = threadIdx.x & 127;
    const int esub = threadIdx.x >> 7;
    float w[EAA];
    #pragma unroll
    for (int a = 0; a < EAA; ++a) w[a] = eW[layer * EAA * DD + a * DD + d];
    const float bias = eb[layer * DD + d];

    const long base = (long)blockIdx.x * EPB;
    for (int k = esub; k < EPB; k += 2) {
        long e = base + k;
        if (e >= EE) break;
        int s = ei[e];
        int t = ei[EE + e];
        float acc = bias;
        #pragma unroll
        for (int a = 0; a < EAA; ++a)
            acc = fmaf(eattr[e * EAA + a], w[a], acc);
        float m = h_in[(long)s * DD + d] + acc;
        m = m > 0.0f ? m : 0.0f;
        atomicAdd(&agg[(long)t * DD + d], m);
    }
}

// ---------------------------------------------------------------------------
// K3: register-tiled node MLP. 32 rows/block, 256 threads as 8(ty) x 32(tx).
// Phase A: thread owns 4 rows x 8 cols of z@W1 (256 cols).
// Phase B: thread owns 4 rows x 4 cols of u@W2 (128 cols).
// ---------------------------------------------------------------------------
#define MROWS 32
__global__ __launch_bounds__(256) void mlp_kernel(
    const float* __restrict__ z_in,
    const float* __restrict__ W1, const float* __restrict__ b1,
    const float* __restrict__ g1, const float* __restrict__ be1,
    const float* __restrict__ m1, const float* __restrict__ v1,
    const float* __restrict__ W2, const float* __restrict__ b2,
    const float* __restrict__ g2, const float* __restrict__ be2,
    const float* __restrict__ m2, const float* __restrict__ v2,
    float* __restrict__ h_out, int layer, int do_relu)
{
    __shared__ float zs[MROWS][DD + 4];
    __shared__ float us[MROWS][2 * DD + 4];
    const long row0 = (long)blockIdx.x * MROWS;
    const int tx = threadIdx.x & 31;
    const int ty = threadIdx.x >> 5;

    // stage z rows (32x128 contiguous) into LDS via float4
    {
        const float4* zi = (const float4*)(z_in + row0 * DD);
        #pragma unroll
        for (int i = 0; i < 4; ++i) {
            int idx = threadIdx.x + i * 256;
            float4 v = zi[idx];
            int r = idx >> 5;
            int c = (idx & 31) * 4;
            zs[r][c] = v.x; zs[r][c + 1] = v.y; zs[r][c + 2] = v.z; zs[r][c + 3] = v.w;
        }
    }
    __syncthreads();

    // phase A
    {
        const float* W1l = W1 + (long)layer * DD * 2 * DD + tx * 8;
        float acc[4][8];
        #pragma unroll
        for (int r = 0; r < 4; ++r)
            #pragma unroll
            for (int j = 0; j < 8; ++j) acc[r][j] = 0.0f;

        for (int k = 0; k < DD; ++k) {
            float4 wa = *(const float4*)(W1l + (long)k * 2 * DD);
            float4 wb = *(const float4*)(W1l + (long)k * 2 * DD + 4);
            float w8[8] = {wa.x, wa.y, wa.z, wa.w, wb.x, wb.y, wb.z, wb.w};
            float zr[4];
            #pragma unroll
            for (int r = 0; r < 4; ++r) zr[r] = zs[ty * 4 + r][k];
            #pragma unroll
            for (int r = 0; r < 4; ++r)
                #pragma unroll
                for (int j = 0; j < 8; ++j)
                    acc[r][j] = fmaf(zr[r], w8[j], acc[r][j]);
        }

        #pragma unroll
        for (int j = 0; j < 8; ++j) {
            long o = (long)layer * 2 * DD + tx * 8 + j;
            float sc = g1[o] / sqrtf(v1[o] + BN_EPS);
            float sh = (b1[o] - m1[o]) * sc + be1[o];
            #pragma unroll
            for (int r = 0; r < 4; ++r) {
                float t = fmaf(acc[r][j], sc, sh);
                acc[r][j] = t > 0.0f ? t : 0.0f;
            }
        }
        #pragma unroll
        for (int r = 0; r < 4; ++r) {
            *(float4*)&us[ty * 4 + r][tx * 8]     = make_float4(acc[r][0], acc[r][1], acc[r][2], acc[r][3]);
            *(float4*)&us[ty * 4 + r][tx * 8 + 4] = make_float4(acc[r][4], acc[r][5], acc[r][6], acc[r][7]);
        }
    }
    __syncthreads();

    // phase B
    {
        const float* W2l = W2 + (long)layer * 2 * DD * DD + tx * 4;
        float acc[4][4];
        #pragma unroll
        for (int r = 0; r < 4; ++r)
            #pragma unroll
            for (int j = 0; j < 4; ++j) acc[r][j] = 0.0f;

        for (int k = 0; k < 2 * DD; ++k) {
            float4 w = *(const float4*)(W2l + (long)k * DD);
            float w4[4] = {w.x, w.y, w.z, w.w};
            float ur[4];
            #pragma unroll
            for (int r = 0; r < 4; ++r) ur[r] = us[ty * 4 + r][k];
            #pragma unroll
            for (int r = 0; r < 4; ++r)
                #pragma unroll
                for (int j = 0; j < 4; ++j)
                    acc[r][j] = fmaf(ur[r], w4[j], acc[r][j]);
        }

        float sc[4], sh[4];
        #pragma unroll
        for (int j = 0; j < 4; ++j) {
            long o = (long)layer * DD + tx * 4 + j;
            sc[j] = g2[o] / sqrtf(v2[o] + BN_EPS);
            sh[j] = (b2[o] - m2[o]) * sc[j] + be2[o];
        }
        #pragma unroll
        for (int r = 0; r < 4; ++r) {
            float4 o4;
            float t0 = fmaf(acc[r][0], sc[0], sh[0]);
            float t1 = fmaf(acc[r][1], sc[1], sh[1]);
            float t2 = fmaf(acc[r][2], sc[2], sh[2]);
            float t3 = fmaf(acc[r][3], sc[3], sh[3]);
            if (do_relu) {
                t0 = t0 > 0.0f ? t0 : 0.0f; t1 = t1 > 0.0f ? t1 : 0.0f;
                t2 = t2 > 0.0f ? t2 : 0.0f; t3 = t3 > 0.0f ? t3 : 0.0f;
            }
            o4 = make_float4(t0, t1, t2, t3);
            *(float4*)&h_out[(row0 + ty * 4 + r) * DD + tx * 4] = o4;
        }
    }
}

// ---------------------------------------------------------------------------
// K4: virtual-node MLP. One block per graph g.
// ---------------------------------------------------------------------------
__global__ __launch_bounds__(256) void vn_kernel(
    const float* __restrict__ vt, float* __restrict__ vn,
    const float* __restrict__ W1, const float* __restrict__ b1,
    const float* __restrict__ g1, const float* __restrict__ be1,
    const float* __restrict__ m1, const float* __restrict__ v1,
    const float* __restrict__ W2, const float* __restrict__ b2,
    const float* __restrict__ g2, const float* __restrict__ be2,
    const float* __restrict__ m2, const float* __restrict__ v2,
    int layer)
{
    __shared__ float row[DD];
    __shared__ float u[2 * DD];
    const int g = blockIdx.x;
    const int t = threadIdx.x;

    if (t < DD) row[t] = vt[(long)g * DD + t] + vn[(long)g * DD + t];
    __syncthreads();

    {
        const float* W = W1 + (long)layer * DD * 2 * DD;
        float acc = 0.0f;
        for (int k = 0; k < DD; ++k) acc = fmaf(row[k], W[k * 2 * DD + t], acc);
        const long o = (long)layer * 2 * DD + t;
        float sc = g1[o] / sqrtf(v1[o] + BN_EPS);
        float sh = be1[o] - m1[o] * sc;
        float val = (acc + b1[o]) * sc + sh;
        u[t] = val > 0.0f ? val : 0.0f;
    }
    __syncthreads();

    if (t < DD) {
        const float* W = W2 + (long)layer * 2 * DD * DD;
        float acc = 0.0f;
        for (int k = 0; k < 2 * DD; ++k) acc = fmaf(u[k], W[k * DD + t], acc);
        const long o = (long)layer * DD + t;
        float sc = g2[o] / sqrtf(v2[o] + BN_EPS);
        float sh = be2[o] - m2[o] * sc;
        float val = (acc + b2[o]) * sc + sh;
        vn[(long)g * DD + t] = val > 0.0f ? val : 0.0f;
    }
}

// ---------------------------------------------------------------------------
extern "C" void kernel_launch(void* const* d_in, const int* in_sizes, int n_in,
                              void* d_out, int out_size, void* d_ws, size_t ws_size,
                              hipStream_t stream)
{
    const int*   x       = (const int*)  d_in[0];
    const int*   ei      = (const int*)  d_in[1];
    const float* eattr   = (const float*)d_in[2];
    const int*   batch   = (const int*)  d_in[3];
    const float* node_emb= (const float*)d_in[4];
    const float* vn_emb  = (const float*)d_in[5];
    const float* edge_W  = (const float*)d_in[6];
    const float* edge_b  = (const float*)d_in[7];
    const float* eps     = (const float*)d_in[8];
    const float* mlp_W1  = (const float*)d_in[9];
    const float* mlp_b1  = (const float*)d_in[10];
    const float* mbn_g   = (const float*)d_in[11];
    const float* mbn_b   = (const float*)d_in[12];
    const float* mbn_m   = (const float*)d_in[13];
    const float* mbn_v   = (const float*)d_in[14];
    const float* mlp_W2  = (const float*)d_in[15];
    const float* mlp_b2  = (const float*)d_in[16];
    const float* bn_g    = (const float*)d_in[17];
    const float* bn_b    = (const float*)d_in[18];
    const float* bn_m    = (const float*)d_in[19];
    const float* bn_v    = (const float*)d_in[20];
    const float* vn_W1   = (const float*)d_in[21];
    const float* vn_b1   = (const float*)d_in[22];
    const float* vbn1_g  = (const float*)d_in[23];
    const float* vbn1_b  = (const float*)d_in[24];
    const float* vbn1_m  = (const float*)d_in[25];
    const float* vbn1_v  = (const float*)d_in[26];
    const float* vn_W2   = (const float*)d_in[27];
    const float* vn_b2   = (const float*)d_in[28];
    const float* vbn2_g  = (const float*)d_in[29];
    const float* vbn2_b  = (const float*)d_in[30];
    const float* vbn2_m  = (const float*)d_in[31];
    const float* vbn2_v  = (const float*)d_in[32];

    float* h = (float*)d_out;
    char*  ws = (char*)d_ws;

    size_t off = 0;
    auto alloc = [&](size_t bytes) -> void* {
        void* p = ws + off;
        off += (bytes + 255) & ~(size_t)255;
        return p;
    };
    const size_t NB  = (size_t)NN * DD * sizeof(float);
    const size_t GDB = (size_t)GG * DD * sizeof(float);

    float* agg      = (float*)alloc(NB);
    float* vn       = (float*)alloc(GDB);
    float* vt       = (float*)alloc(GDB);
    int*   rp       = (int*)  alloc((NN + 1) * sizeof(int));
    int*   fill     = (int*)  alloc(NN * sizeof(int));
    int*   partials = (int*)  alloc(128 * sizeof(int));
    const size_t base_end = off;

    float* rec = nullptr;
    int*   eid_perm = nullptr;
    if (ws_size >= base_end + (size_t)EE * 8 * sizeof(float))
        rec = (float*)alloc((size_t)EE * 8 * sizeof(float));
    else if (ws_size >= base_end + (size_t)EE * sizeof(int))
        eid_perm = (int*)alloc((size_t)EE * sizeof(int));
    const bool csr = (rec != nullptr) || (eid_perm != nullptr);

    // K0: init h and vn
    {
        long total = (long)NN * DD;
        init_kernel<<<(int)((total + 255) / 256), 256, 0, stream>>>(
            x, node_emb, vn_emb, h, vn);
    }

    // CSR build (once; reused by all layers)
    if (csr) {
        const int egrid = (EE + 255) / 256;
        const int ngrid = (NN + 1023) / 1024;
        hipMemsetAsync(fill, 0, NN * sizeof(int), stream);
        count_kernel<<<egrid, 256, 0, stream>>>(ei, fill);
        scan_a<<<ngrid, 1024, 0, stream>>>(fill, rp, partials);
        scan_b<<<1, 64, 0, stream>>>(partials, ngrid);
        scan_c<<<ngrid, 1024, 0, stream>>>(rp, fill, partials);
        scatter_kernel<<<egrid, 256, 0, stream>>>(ei, eattr, fill, rec, eid_perm);
    }

    for (int l = 0; l < LL; ++l) {
        int accum = (l < LL - 1) ? 1 : 0;
        if (accum)
            hipMemsetAsync(vt, 0, GDB, stream);

        hin_kernel<<<NN / (R1 * 2), 256, 0, stream>>>(
            h, vn, batch, eps, agg, vt, l, accum, csr ? 0 : 1);

        if (csr) {
            gin_agg_kernel<<<NN / 2, 256, 0, stream>>>(
                h, rp, rec, eid_perm, ei, eattr, edge_W, edge_b, eps, agg, l);
        } else {
            edge_kernel<<<(EE + EPB - 1) / EPB, 256, 0, stream>>>(
                h, ei, eattr, edge_W, edge_b, agg, l);
        }

        mlp_kernel<<<NN / MROWS, 256, 0, stream>>>(
            agg, mlp_W1, mlp_b1, mbn_g, mbn_b, mbn_m, mbn_v,
            mlp_W2, mlp_b2, bn_g, bn_b, bn_m, bn_v,
            h, l, accum);

        if (accum)
            vn_kernel<<<GG, 256, 0, stream>>>(
                vt, vn, vn_W1, vn_b1, vbn1_g, vbn1_b, vbn1_m, vbn1_v,
                vn_W2, vn_b2, vbn2_g, vbn2_b, vbn2_m, vbn2_v, l);
    }
}

// Round 3
// 1438.477 us; speedup vs baseline: 2.0161x; 1.2713x over previous
//
#include <hip/hip_runtime.h>
#include <hip/hip_bf16.h>

#define NN 100000
#define EE 1600000
#define GG 128
#define DD 128
#define LL 3
#define EAA 7
#define BN_EPS 1e-5f

// ---------------------------------------------------------------------------
// K0: h[i,:] = node_emb[x[i],:]; vn[g,:] = vn_emb[0,:]
// ---------------------------------------------------------------------------
__global__ __launch_bounds__(256) void init_kernel(
    const int* __restrict__ x, const float* __restrict__ node_emb,
    const float* __restrict__ vn_emb, float* __restrict__ h,
    float* __restrict__ vn)
{
    long i = (long)blockIdx.x * 256 + threadIdx.x;
    if (i < (long)NN * DD) {
        int node = (int)(i >> 7), d = (int)(i & 127);
        h[i] = node_emb[(long)x[node] * DD + d];
    }
    if (i < GG * DD) vn[i] = vn_emb[i & 127];
}

// ---------------------------------------------------------------------------
// K1: in-place h -> h_in = h + vn[batch]; optional agg=(1+eps)h_in (atomic
// fallback path only); optional vt[g] += h_in rows (run-length fused atomics)
// ---------------------------------------------------------------------------
#define R1 8
__global__ __launch_bounds__(256) void hin_kernel(
    float* __restrict__ hbuf,
    const float* __restrict__ vn,
    const int* __restrict__ batch,
    const float* __restrict__ eps,
    float* __restrict__ agg,
    float* __restrict__ vt,
    int layer, int accum_vt, int write_agg)
{
    const int d  = threadIdx.x & 127;
    const int rg = threadIdx.x >> 7;
    const float epl = 1.0f + eps[layer];
    const long row0 = (long)blockIdx.x * (R1 * 2);

    float vacc = 0.0f;
    int   vb   = -1;
    #pragma unroll
    for (int r = 0; r < R1; ++r) {
        long row = row0 + rg + 2 * r;
        if (row >= NN) break;
        int b = batch[row];
        long idx = row * DD + d;
        float hv = hbuf[idx] + vn[(long)b * DD + d];
        hbuf[idx] = hv;
        if (write_agg) agg[idx] = epl * hv;
        if (accum_vt) {
            if (b != vb) {
                if (vb >= 0) atomicAdd(&vt[(long)vb * DD + d], vacc);
                vb = b; vacc = 0.0f;
            }
            vacc += hv;
        }
    }
    if (accum_vt && vb >= 0) atomicAdd(&vt[(long)vb * DD + d], vacc);
}

// ---------------------------------------------------------------------------
// CSR build: count -> scan -> scatter. Built once, reused by all 3 layers.
// ---------------------------------------------------------------------------
__global__ __launch_bounds__(256) void count_kernel(
    const int* __restrict__ ei, int* __restrict__ deg)
{
    long e = (long)blockIdx.x * 256 + threadIdx.x;
    if (e < EE) atomicAdd(&deg[ei[EE + e]], 1);
}

__global__ __launch_bounds__(1024) void scan_a(
    const int* __restrict__ deg, int* __restrict__ rp, int* __restrict__ partials)
{
    __shared__ int s[1024];
    int t = threadIdx.x;
    long i = (long)blockIdx.x * 1024 + t;
    int v = (i < NN) ? deg[i] : 0;
    s[t] = v;
    __syncthreads();
    for (int off = 1; off < 1024; off <<= 1) {
        int u = (t >= off) ? s[t - off] : 0;
        __syncthreads();
        s[t] += u;
        __syncthreads();
    }
    if (i < NN) rp[i] = s[t] - v;                 // block-local exclusive
    if (t == 1023) partials[blockIdx.x] = s[1023];
}

__global__ void scan_b(int* __restrict__ partials, int nb)
{
    if (threadIdx.x == 0) {
        int run = 0;
        for (int i = 0; i < nb; ++i) { int v = partials[i]; partials[i] = run; run += v; }
    }
}

__global__ __launch_bounds__(1024) void scan_c(
    int* __restrict__ rp, int* __restrict__ fill, const int* __restrict__ partials)
{
    long i = (long)blockIdx.x * 1024 + threadIdx.x;
    if (i < NN) {
        int v = rp[i] + partials[blockIdx.x];
        rp[i] = v;
        fill[i] = v;
    }
    if (i == 0) rp[NN] = EE;
}

__global__ __launch_bounds__(256) void scatter_kernel(
    const int* __restrict__ ei, const float* __restrict__ eattr,
    int* __restrict__ fill, float* __restrict__ rec, int* __restrict__ src_arr,
    int* __restrict__ eid_perm)
{
    long e = (long)blockIdx.x * 256 + threadIdx.x;
    if (e >= EE) return;
    int dst = ei[EE + e];
    int pos = atomicAdd(&fill[dst], 1);
    if (rec) {
        float* r = rec + (long)pos * 8;
        #pragma unroll
        for (int a = 0; a < EAA; ++a) r[a] = eattr[e * EAA + a];
        r[7] = 0.0f;
        src_arr[pos] = ei[e];
    } else {
        eid_perm[pos] = (int)e;
    }
}

// ---------------------------------------------------------------------------
// K2 (CSR, ILP version): one WAVE per dst node; lane owns cols {2l, 2l+1}.
// z[n] = (1+eps)h_in[n] + sum_e relu(h_in[src_e] + attr_e @ W + b)
// Edge loop unrolled x4 with all loads issued before any use; src comes from
// a separate src_arr so gathers don't wait on the 32B attr record.
// ---------------------------------------------------------------------------
__global__ __launch_bounds__(256) void gin_agg_kernel(
    const float* __restrict__ h_in,
    const int* __restrict__ rp,
    const float* __restrict__ rec,
    const int* __restrict__ src_arr,
    const float* __restrict__ eW, const float* __restrict__ eb,
    const float* __restrict__ eps,
    float* __restrict__ agg, int layer)
{
    const int lane = threadIdx.x & 63;
    const int wid  = threadIdx.x >> 6;
    const long n   = (long)blockIdx.x * 4 + wid;
    const int d0   = lane * 2;

    const float* eWl = eW + (long)layer * EAA * DD;
    float2 w2[EAA];
    #pragma unroll
    for (int a = 0; a < EAA; ++a)
        w2[a] = *(const float2*)&eWl[a * DD + d0];
    const float2 bias = *(const float2*)&eb[layer * DD + d0];
    const float  epl  = 1.0f + eps[layer];

    float2 hn = *(const float2*)&h_in[n * DD + d0];
    float accx = epl * hn.x, accy = epl * hn.y;

    int p  = rp[n];
    const int p1 = rp[n + 1];

    for (; p + 4 <= p1; p += 4) {
        int s0 = src_arr[p];
        int s1 = src_arr[p + 1];
        int s2 = src_arr[p + 2];
        int s3 = src_arr[p + 3];
        const float4* r4 = (const float4*)(rec + (long)p * 8);
        float4 ra0 = r4[0], rb0 = r4[1];
        float4 ra1 = r4[2], rb1 = r4[3];
        float4 ra2 = r4[4], rb2 = r4[5];
        float4 ra3 = r4[6], rb3 = r4[7];
        float2 h0 = *(const float2*)&h_in[(long)s0 * DD + d0];
        float2 h1 = *(const float2*)&h_in[(long)s1 * DD + d0];
        float2 h2 = *(const float2*)&h_in[(long)s2 * DD + d0];
        float2 h3 = *(const float2*)&h_in[(long)s3 * DD + d0];

        #define EDGE(RA, RB, HV)                                              \
        {                                                                     \
            float ex = bias.x, ey = bias.y;                                   \
            ex = fmaf(RA.x, w2[0].x, ex); ey = fmaf(RA.x, w2[0].y, ey);       \
            ex = fmaf(RA.y, w2[1].x, ex); ey = fmaf(RA.y, w2[1].y, ey);       \
            ex = fmaf(RA.z, w2[2].x, ex); ey = fmaf(RA.z, w2[2].y, ey);       \
            ex = fmaf(RA.w, w2[3].x, ex); ey = fmaf(RA.w, w2[3].y, ey);       \
            ex = fmaf(RB.x, w2[4].x, ex); ey = fmaf(RB.x, w2[4].y, ey);       \
            ex = fmaf(RB.y, w2[5].x, ex); ey = fmaf(RB.y, w2[5].y, ey);       \
            ex = fmaf(RB.z, w2[6].x, ex); ey = fmaf(RB.z, w2[6].y, ey);       \
            float mx = HV.x + ex, my = HV.y + ey;                             \
            accx += fmaxf(mx, 0.0f); accy += fmaxf(my, 0.0f);                 \
        }
        EDGE(ra0, rb0, h0)
        EDGE(ra1, rb1, h1)
        EDGE(ra2, rb2, h2)
        EDGE(ra3, rb3, h3)
    }
    for (; p < p1; ++p) {
        int s = src_arr[p];
        const float4* r4 = (const float4*)(rec + (long)p * 8);
        float4 ra = r4[0], rb = r4[1];
        float2 hv = *(const float2*)&h_in[(long)s * DD + d0];
        EDGE(ra, rb, hv)
        #undef EDGE
    }

    *(float2*)&agg[n * DD + d0] = make_float2(accx, accy);
}

// ---------------------------------------------------------------------------
// K2 fallback A (eid indirection, if ws too small for records)
// ---------------------------------------------------------------------------
__global__ __launch_bounds__(256) void gin_agg_eid_kernel(
    const float* __restrict__ h_in,
    const int* __restrict__ rp,
    const int* __restrict__ eid_perm,
    const int* __restrict__ ei,
    const float* __restrict__ eattr,
    const float* __restrict__ eW, const float* __restrict__ eb,
    const float* __restrict__ eps,
    float* __restrict__ agg, int layer)
{
    const int d    = threadIdx.x & 127;
    const int half = threadIdx.x >> 7;
    const long n   = (long)blockIdx.x * 2 + half;

    float w[EAA];
    #pragma unroll
    for (int a = 0; a < EAA; ++a) w[a] = eW[layer * EAA * DD + a * DD + d];
    const float bias = eb[layer * DD + d];
    const float epl  = 1.0f + eps[layer];

    float acc = epl * h_in[n * DD + d];
    const int p0 = rp[n], p1 = rp[n + 1];
    for (int p = p0; p < p1; ++p) {
        int e = eid_perm[p];
        int src = ei[e];
        float ea = bias;
        #pragma unroll
        for (int a = 0; a < EAA; ++a)
            ea = fmaf(eattr[(long)e * EAA + a], w[a], ea);
        float m = h_in[(long)src * DD + d] + ea;
        acc += m > 0.0f ? m : 0.0f;
    }
    agg[n * DD + d] = acc;
}

// ---------------------------------------------------------------------------
// K2 fallback B (atomic path, minimal workspace)
// ---------------------------------------------------------------------------
#define EPB 64
__global__ __launch_bounds__(256) void edge_kernel(
    const float* __restrict__ h_in,
    const int* __restrict__ ei,
    const float* __restrict__ eattr,
    const float* __restrict__ eW,
    const float* __restrict__ eb,
    float* __restrict__ agg,
    int layer)
{
    const int d    = threadIdx.x & 127;
    const int esub = threadIdx.x >> 7;
    float w[EAA];
    #pragma unroll
    for (int a = 0; a < EAA; ++a) w[a] = eW[layer * EAA * DD + a * DD + d];
    const float bias = eb[layer * DD + d];

    const long base = (long)blockIdx.x * EPB;
    for (int k = esub; k < EPB; k += 2) {
        long e = base + k;
        if (e >= EE) break;
        int s = ei[e];
        int t = ei[EE + e];
        float acc = bias;
        #pragma unroll
        for (int a = 0; a < EAA; ++a)
            acc = fmaf(eattr[e * EAA + a], w[a], acc);
        float m = h_in[(long)s * DD + d] + acc;
        m = m > 0.0f ? m : 0.0f;
        atomicAdd(&agg[(long)t * DD + d], m);
    }
}

// ---------------------------------------------------------------------------
// K3: register-tiled node MLP. 32 rows/block, 256 threads as 8(ty) x 32(tx).
// ---------------------------------------------------------------------------
#define MROWS 32
__global__ __launch_bounds__(256) void mlp_kernel(
    const float* __restrict__ z_in,
    const float* __restrict__ W1, const float* __restrict__ b1,
    const float* __restrict__ g1, const float* __restrict__ be1,
    const float* __restrict__ m1, const float* __restrict__ v1,
    const float* __restrict__ W2, const float* __restrict__ b2,
    const float* __restrict__ g2, const float* __restrict__ be2,
    const float* __restrict__ m2, const float* __restrict__ v2,
    float* __restrict__ h_out, int layer, int do_relu)
{
    __shared__ float zs[MROWS][DD + 4];
    __shared__ float us[MROWS][2 * DD + 4];
    const long row0 = (long)blockIdx.x * MROWS;
    const int tx = threadIdx.x & 31;
    const int ty = threadIdx.x >> 5;

    {
        const float4* zi = (const float4*)(z_in + row0 * DD);
        #pragma unroll
        for (int i = 0; i < 4; ++i) {
            int idx = threadIdx.x + i * 256;
            float4 v = zi[idx];
            int r = idx >> 5;
            int c = (idx & 31) * 4;
            zs[r][c] = v.x; zs[r][c + 1] = v.y; zs[r][c + 2] = v.z; zs[r][c + 3] = v.w;
        }
    }
    __syncthreads();

    // phase A
    {
        const float* W1l = W1 + (long)layer * DD * 2 * DD + tx * 8;
        float acc[4][8];
        #pragma unroll
        for (int r = 0; r < 4; ++r)
            #pragma unroll
            for (int j = 0; j < 8; ++j) acc[r][j] = 0.0f;

        for (int k = 0; k < DD; ++k) {
            float4 wa = *(const float4*)(W1l + (long)k * 2 * DD);
            float4 wb = *(const float4*)(W1l + (long)k * 2 * DD + 4);
            float w8[8] = {wa.x, wa.y, wa.z, wa.w, wb.x, wb.y, wb.z, wb.w};
            float zr[4];
            #pragma unroll
            for (int r = 0; r < 4; ++r) zr[r] = zs[ty * 4 + r][k];
            #pragma unroll
            for (int r = 0; r < 4; ++r)
                #pragma unroll
                for (int j = 0; j < 8; ++j)
                    acc[r][j] = fmaf(zr[r], w8[j], acc[r][j]);
        }

        #pragma unroll
        for (int j = 0; j < 8; ++j) {
            long o = (long)layer * 2 * DD + tx * 8 + j;
            float sc = g1[o] / sqrtf(v1[o] + BN_EPS);
            float sh = (b1[o] - m1[o]) * sc + be1[o];
            #pragma unroll
            for (int r = 0; r < 4; ++r) {
                float t = fmaf(acc[r][j], sc, sh);
                acc[r][j] = t > 0.0f ? t : 0.0f;
            }
        }
        #pragma unroll
        for (int r = 0; r < 4; ++r) {
            *(float4*)&us[ty * 4 + r][tx * 8]     = make_float4(acc[r][0], acc[r][1], acc[r][2], acc[r][3]);
            *(float4*)&us[ty * 4 + r][tx * 8 + 4] = make_float4(acc[r][4], acc[r][5], acc[r][6], acc[r][7]);
        }
    }
    __syncthreads();

    // phase B
    {
        const float* W2l = W2 + (long)layer * 2 * DD * DD + tx * 4;
        float acc[4][4];
        #pragma unroll
        for (int r = 0; r < 4; ++r)
            #pragma unroll
            for (int j = 0; j < 4; ++j) acc[r][j] = 0.0f;

        for (int k = 0; k < 2 * DD; ++k) {
            float4 w = *(const float4*)(W2l + (long)k * DD);
            float w4[4] = {w.x, w.y, w.z, w.w};
            float ur[4];
            #pragma unroll
            for (int r = 0; r < 4; ++r) ur[r] = us[ty * 4 + r][k];
            #pragma unroll
            for (int r = 0; r < 4; ++r)
                #pragma unroll
                for (int j = 0; j < 4; ++j)
                    acc[r][j] = fmaf(ur[r], w4[j], acc[r][j]);
        }

        float sc[4], sh[4];
        #pragma unroll
        for (int j = 0; j < 4; ++j) {
            long o = (long)layer * DD + tx * 4 + j;
            sc[j] = g2[o] / sqrtf(v2[o] + BN_EPS);
            sh[j] = (b2[o] - m2[o]) * sc[j] + be2[o];
        }
        #pragma unroll
        for (int r = 0; r < 4; ++r) {
            float4 o4;
            float t0 = fmaf(acc[r][0], sc[0], sh[0]);
            float t1 = fmaf(acc[r][1], sc[1], sh[1]);
            float t2 = fmaf(acc[r][2], sc[2], sh[2]);
            float t3 = fmaf(acc[r][3], sc[3], sh[3]);
            if (do_relu) {
                t0 = t0 > 0.0f ? t0 : 0.0f; t1 = t1 > 0.0f ? t1 : 0.0f;
                t2 = t2 > 0.0f ? t2 : 0.0f; t3 = t3 > 0.0f ? t3 : 0.0f;
            }
            o4 = make_float4(t0, t1, t2, t3);
            *(float4*)&h_out[(row0 + ty * 4 + r) * DD + tx * 4] = o4;
        }
    }
}

// ---------------------------------------------------------------------------
// K4: virtual-node MLP. One block per graph g.
// ---------------------------------------------------------------------------
__global__ __launch_bounds__(256) void vn_kernel(
    const float* __restrict__ vt, float* __restrict__ vn,
    const float* __restrict__ W1, const float* __restrict__ b1,
    const float* __restrict__ g1, const float* __restrict__ be1,
    const float* __restrict__ m1, const float* __restrict__ v1,
    const float* __restrict__ W2, const float* __restrict__ b2,
    const float* __restrict__ g2, const float* __restrict__ be2,
    const float* __restrict__ m2, const float* __restrict__ v2,
    int layer)
{
    __shared__ float row[DD];
    __shared__ float u[2 * DD];
    const int g = blockIdx.x;
    const int t = threadIdx.x;

    if (t < DD) row[t] = vt[(long)g * DD + t] + vn[(long)g * DD + t];
    __syncthreads();

    {
        const float* W = W1 + (long)layer * DD * 2 * DD;
        float acc = 0.0f;
        for (int k = 0; k < DD; ++k) acc = fmaf(row[k], W[k * 2 * DD + t], acc);
        const long o = (long)layer * 2 * DD + t;
        float sc = g1[o] / sqrtf(v1[o] + BN_EPS);
        float sh = be1[o] - m1[o] * sc;
        float val = (acc + b1[o]) * sc + sh;
        u[t] = val > 0.0f ? val : 0.0f;
    }
    __syncthreads();

    if (t < DD) {
        const float* W = W2 + (long)layer * 2 * DD * DD;
        float acc = 0.0f;
        for (int k = 0; k < 2 * DD; ++k) acc = fmaf(u[k], W[k * DD + t], acc);
        const long o = (long)layer * DD + t;
        float sc = g2[o] / sqrtf(v2[o] + BN_EPS);
        float sh = be2[o] - m2[o] * sc;
        float val = (acc + b2[o]) * sc + sh;
        vn[(long)g * DD + t] = val > 0.0f ? val : 0.0f;
    }
}

// ---------------------------------------------------------------------------
extern "C" void kernel_launch(void* const* d_in, const int* in_sizes, int n_in,
                              void* d_out, int out_size, void* d_ws, size_t ws_size,
                              hipStream_t stream)
{
    const int*   x       = (const int*)  d_in[0];
    const int*   ei      = (const int*)  d_in[1];
    const float* eattr   = (const float*)d_in[2];
    const int*   batch   = (const int*)  d_in[3];
    const float* node_emb= (const float*)d_in[4];
    const float* vn_emb  = (const float*)d_in[5];
    const float* edge_W  = (const float*)d_in[6];
    const float* edge_b  = (const float*)d_in[7];
    const float* eps     = (const float*)d_in[8];
    const float* mlp_W1  = (const float*)d_in[9];
    const float* mlp_b1  = (const float*)d_in[10];
    const float* mbn_g   = (const float*)d_in[11];
    const float* mbn_b   = (const float*)d_in[12];
    const float* mbn_m   = (const float*)d_in[13];
    const float* mbn_v   = (const float*)d_in[14];
    const float* mlp_W2  = (const float*)d_in[15];
    const float* mlp_b2  = (const float*)d_in[16];
    const float* bn_g    = (const float*)d_in[17];
    const float* bn_b    = (const float*)d_in[18];
    const float* bn_m    = (const float*)d_in[19];
    const float* bn_v    = (const float*)d_in[20];
    const float* vn_W1   = (const float*)d_in[21];
    const float* vn_b1   = (const float*)d_in[22];
    const float* vbn1_g  = (const float*)d_in[23];
    const float* vbn1_b  = (const float*)d_in[24];
    const float* vbn1_m  = (const float*)d_in[25];
    const float* vbn1_v  = (const float*)d_in[26];
    const float* vn_W2   = (const float*)d_in[27];
    const float* vn_b2   = (const float*)d_in[28];
    const float* vbn2_g  = (const float*)d_in[29];
    const float* vbn2_b  = (const float*)d_in[30];
    const float* vbn2_m  = (const float*)d_in[31];
    const float* vbn2_v  = (const float*)d_in[32];

    float* h = (float*)d_out;
    char*  ws = (char*)d_ws;

    size_t off = 0;
    auto alloc = [&](size_t bytes) -> void* {
        void* p = ws + off;
        off += (bytes + 255) & ~(size_t)255;
        return p;
    };
    const size_t NB  = (size_t)NN * DD * sizeof(float);
    const size_t GDB = (size_t)GG * DD * sizeof(float);

    float* agg      = (float*)alloc(NB);
    float* vn       = (float*)alloc(GDB);
    float* vt       = (float*)alloc(GDB);
    int*   rp       = (int*)  alloc((NN + 1) * sizeof(int));
    int*   fill     = (int*)  alloc(NN * sizeof(int));
    int*   partials = (int*)  alloc(128 * sizeof(int));
    int*   src_arr  = (int*)  alloc((size_t)EE * sizeof(int));
    const size_t base_end = off;

    float* rec = nullptr;
    int*   eid_perm = nullptr;
    if (ws_size >= base_end + (size_t)EE * 8 * sizeof(float))
        rec = (float*)alloc((size_t)EE * 8 * sizeof(float));
    else if (ws_size >= base_end + (size_t)EE * sizeof(int))
        eid_perm = (int*)alloc((size_t)EE * sizeof(int));
    const bool csr = (rec != nullptr) || (eid_perm != nullptr);

    // K0: init h and vn
    {
        long total = (long)NN * DD;
        init_kernel<<<(int)((total + 255) / 256), 256, 0, stream>>>(
            x, node_emb, vn_emb, h, vn);
    }

    // CSR build (once; reused by all layers)
    if (csr) {
        const int egrid = (EE + 255) / 256;
        const int ngrid = (NN + 1023) / 1024;
        hipMemsetAsync(fill, 0, NN * sizeof(int), stream);
        count_kernel<<<egrid, 256, 0, stream>>>(ei, fill);
        scan_a<<<ngrid, 1024, 0, stream>>>(fill, rp, partials);
        scan_b<<<1, 64, 0, stream>>>(partials, ngrid);
        scan_c<<<ngrid, 1024, 0, stream>>>(rp, fill, partials);
        scatter_kernel<<<egrid, 256, 0, stream>>>(ei, eattr, fill, rec, src_arr, eid_perm);
    }

    for (int l = 0; l < LL; ++l) {
        int accum = (l < LL - 1) ? 1 : 0;
        if (accum)
            hipMemsetAsync(vt, 0, GDB, stream);

        hin_kernel<<<NN / (R1 * 2), 256, 0, stream>>>(
            h, vn, batch, eps, agg, vt, l, accum, csr ? 0 : 1);

        if (rec) {
            gin_agg_kernel<<<NN / 4, 256, 0, stream>>>(
                h, rp, rec, src_arr, edge_W, edge_b, eps, agg, l);
        } else if (eid_perm) {
            gin_agg_eid_kernel<<<NN / 2, 256, 0, stream>>>(
                h, rp, eid_perm, ei, eattr, edge_W, edge_b, eps, agg, l);
        } else {
            edge_kernel<<<(EE + EPB - 1) / EPB, 256, 0, stream>>>(
                h, ei, eattr, edge_W, edge_b, agg, l);
        }

        mlp_kernel<<<NN / MROWS, 256, 0, stream>>>(
            agg, mlp_W1, mlp_b1, mbn_g, mbn_b, mbn_m, mbn_v,
            mlp_W2, mlp_b2, bn_g, bn_b, bn_m, bn_v,
            h, l, accum);

        if (accum)
            vn_kernel<<<GG, 256, 0, stream>>>(
                vt, vn, vn_W1, vn_b1, vbn1_g, vbn1_b, vbn1_m, vbn1_v,
                vn_W2, vn_b2, vbn2_g, vbn2_b, vbn2_m, vbn2_v, l);
    }
}

// Round 4
// 1020.137 us; speedup vs baseline: 2.8429x; 1.4101x over previous
//
#include <hip/hip_runtime.h>
#include <hip/hip_bf16.h>

#define NN 100000
#define NP 100032              // NN rounded up to 64
#define EE 1600000
#define GG 128
#define DD 128
#define LL 3
#define EAA 7
#define BN_EPS 1e-5f

typedef __attribute__((ext_vector_type(8))) short bf16x8;
typedef __attribute__((ext_vector_type(4))) float f32x4;
typedef __attribute__((ext_vector_type(4))) unsigned short u16x4;

__device__ __forceinline__ unsigned short f2bf(float x) {
    unsigned int u = __float_as_uint(x);
    u = (u + 0x7FFF + ((u >> 16) & 1)) >> 16;
    return (unsigned short)u;
}
__device__ __forceinline__ float bf2f(unsigned short h) {
    return __uint_as_float(((unsigned int)h) << 16);
}

// ---------------------------------------------------------------------------
// K0: h[i,:] = node_emb[x[i],:]; vn[g,:] = vn_emb[0,:]
// ---------------------------------------------------------------------------
__global__ __launch_bounds__(256) void init_kernel(
    const int* __restrict__ x, const float* __restrict__ node_emb,
    const float* __restrict__ vn_emb, float* __restrict__ h,
    float* __restrict__ vn)
{
    long i = (long)blockIdx.x * 256 + threadIdx.x;
    if (i < (long)NN * DD) {
        int node = (int)(i >> 7), d = (int)(i & 127);
        h[i] = node_emb[(long)x[node] * DD + d];
    }
    if (i < GG * DD) vn[i] = vn_emb[i & 127];
}

// ---------------------------------------------------------------------------
// K1: in-place h -> h_in = h + vn[batch]; optional agg=(1+eps)h_in (atomic
// fallback only); optional vt[g] += h_in rows (run-length fused atomics)
// ---------------------------------------------------------------------------
#define R1 8
__global__ __launch_bounds__(256) void hin_kernel(
    float* __restrict__ hbuf,
    const float* __restrict__ vn,
    const int* __restrict__ batch,
    const float* __restrict__ eps,
    float* __restrict__ agg,
    float* __restrict__ vt,
    int layer, int accum_vt, int write_agg)
{
    const int d  = threadIdx.x & 127;
    const int rg = threadIdx.x >> 7;
    const float epl = 1.0f + eps[layer];
    const long row0 = (long)blockIdx.x * (R1 * 2);

    float vacc = 0.0f;
    int   vb   = -1;
    #pragma unroll
    for (int r = 0; r < R1; ++r) {
        long row = row0 + rg + 2 * r;
        if (row >= NN) break;
        int b = batch[row];
        long idx = row * DD + d;
        float hv = hbuf[idx] + vn[(long)b * DD + d];
        hbuf[idx] = hv;
        if (write_agg) agg[idx] = epl * hv;
        if (accum_vt) {
            if (b != vb) {
                if (vb >= 0) atomicAdd(&vt[(long)vb * DD + d], vacc);
                vb = b; vacc = 0.0f;
            }
            vacc += hv;
        }
    }
    if (accum_vt && vb >= 0) atomicAdd(&vt[(long)vb * DD + d], vacc);
}

// ---------------------------------------------------------------------------
// CSR build: count -> scan -> scatter. Built once, reused by all 3 layers.
// ---------------------------------------------------------------------------
__global__ __launch_bounds__(256) void count_kernel(
    const int* __restrict__ ei, int* __restrict__ deg)
{
    long e = (long)blockIdx.x * 256 + threadIdx.x;
    if (e < EE) atomicAdd(&deg[ei[EE + e]], 1);
}

__global__ __launch_bounds__(1024) void scan_a(
    const int* __restrict__ deg, int* __restrict__ rp, int* __restrict__ partials)
{
    __shared__ int s[1024];
    int t = threadIdx.x;
    long i = (long)blockIdx.x * 1024 + t;
    int v = (i < NN) ? deg[i] : 0;
    s[t] = v;
    __syncthreads();
    for (int off = 1; off < 1024; off <<= 1) {
        int u = (t >= off) ? s[t - off] : 0;
        __syncthreads();
        s[t] += u;
        __syncthreads();
    }
    if (i < NN) rp[i] = s[t] - v;
    if (t == 1023) partials[blockIdx.x] = s[1023];
}

__global__ void scan_b(int* __restrict__ partials, int nb)
{
    if (threadIdx.x == 0) {
        int run = 0;
        for (int i = 0; i < nb; ++i) { int v = partials[i]; partials[i] = run; run += v; }
    }
}

__global__ __launch_bounds__(1024) void scan_c(
    int* __restrict__ rp, int* __restrict__ fill, const int* __restrict__ partials)
{
    long i = (long)blockIdx.x * 1024 + threadIdx.x;
    if (i < NN) {
        int v = rp[i] + partials[blockIdx.x];
        rp[i] = v;
        fill[i] = v;
    }
    if (i == 0) rp[NN] = EE;
}

__global__ __launch_bounds__(256) void scatter_kernel(
    const int* __restrict__ ei, const float* __restrict__ eattr,
    int* __restrict__ fill, float* __restrict__ rec, int* __restrict__ src_arr,
    int* __restrict__ eid_perm)
{
    long e = (long)blockIdx.x * 256 + threadIdx.x;
    if (e >= EE) return;
    int dst = ei[EE + e];
    int pos = atomicAdd(&fill[dst], 1);
    if (rec) {
        float* r = rec + (long)pos * 8;
        #pragma unroll
        for (int a = 0; a < EAA; ++a) r[a] = eattr[e * EAA + a];
        r[7] = 0.0f;
        src_arr[pos] = ei[e];
    } else {
        eid_perm[pos] = (int)e;
    }
}

// ---------------------------------------------------------------------------
// K2 (CSR, ILP): one wave per dst node; lane owns cols {2l, 2l+1}; x4 unroll.
// ---------------------------------------------------------------------------
__global__ __launch_bounds__(256) void gin_agg_kernel(
    const float* __restrict__ h_in,
    const int* __restrict__ rp,
    const float* __restrict__ rec,
    const int* __restrict__ src_arr,
    const float* __restrict__ eW, const float* __restrict__ eb,
    const float* __restrict__ eps,
    float* __restrict__ agg, int layer)
{
    const int lane = threadIdx.x & 63;
    const int wid  = threadIdx.x >> 6;
    const long n   = (long)blockIdx.x * 4 + wid;
    const int d0   = lane * 2;

    const float* eWl = eW + (long)layer * EAA * DD;
    float2 w2[EAA];
    #pragma unroll
    for (int a = 0; a < EAA; ++a)
        w2[a] = *(const float2*)&eWl[a * DD + d0];
    const float2 bias = *(const float2*)&eb[layer * DD + d0];
    const float  epl  = 1.0f + eps[layer];

    float2 hn = *(const float2*)&h_in[n * DD + d0];
    float accx = epl * hn.x, accy = epl * hn.y;

    int p  = rp[n];
    const int p1 = rp[n + 1];

    for (; p + 4 <= p1; p += 4) {
        int s0 = src_arr[p];
        int s1 = src_arr[p + 1];
        int s2 = src_arr[p + 2];
        int s3 = src_arr[p + 3];
        const float4* r4 = (const float4*)(rec + (long)p * 8);
        float4 ra0 = r4[0], rb0 = r4[1];
        float4 ra1 = r4[2], rb1 = r4[3];
        float4 ra2 = r4[4], rb2 = r4[5];
        float4 ra3 = r4[6], rb3 = r4[7];
        float2 h0 = *(const float2*)&h_in[(long)s0 * DD + d0];
        float2 h1 = *(const float2*)&h_in[(long)s1 * DD + d0];
        float2 h2 = *(const float2*)&h_in[(long)s2 * DD + d0];
        float2 h3 = *(const float2*)&h_in[(long)s3 * DD + d0];

        #define EDGE(RA, RB, HV)                                              \
        {                                                                     \
            float ex = bias.x, ey = bias.y;                                   \
            ex = fmaf(RA.x, w2[0].x, ex); ey = fmaf(RA.x, w2[0].y, ey);       \
            ex = fmaf(RA.y, w2[1].x, ex); ey = fmaf(RA.y, w2[1].y, ey);       \
            ex = fmaf(RA.z, w2[2].x, ex); ey = fmaf(RA.z, w2[2].y, ey);       \
            ex = fmaf(RA.w, w2[3].x, ex); ey = fmaf(RA.w, w2[3].y, ey);       \
            ex = fmaf(RB.x, w2[4].x, ex); ey = fmaf(RB.x, w2[4].y, ey);       \
            ex = fmaf(RB.y, w2[5].x, ex); ey = fmaf(RB.y, w2[5].y, ey);       \
            ex = fmaf(RB.z, w2[6].x, ex); ey = fmaf(RB.z, w2[6].y, ey);       \
            float mx = HV.x + ex, my = HV.y + ey;                             \
            accx += fmaxf(mx, 0.0f); accy += fmaxf(my, 0.0f);                 \
        }
        EDGE(ra0, rb0, h0)
        EDGE(ra1, rb1, h1)
        EDGE(ra2, rb2, h2)
        EDGE(ra3, rb3, h3)
    }
    for (; p < p1; ++p) {
        int s = src_arr[p];
        const float4* r4 = (const float4*)(rec + (long)p * 8);
        float4 ra = r4[0], rb = r4[1];
        float2 hv = *(const float2*)&h_in[(long)s * DD + d0];
        EDGE(ra, rb, hv)
        #undef EDGE
    }

    *(float2*)&agg[n * DD + d0] = make_float2(accx, accy);
}

// ---------------------------------------------------------------------------
// K2 fallback A (eid indirection)
// ---------------------------------------------------------------------------
__global__ __launch_bounds__(256) void gin_agg_eid_kernel(
    const float* __restrict__ h_in,
    const int* __restrict__ rp,
    const int* __restrict__ eid_perm,
    const int* __restrict__ ei,
    const float* __restrict__ eattr,
    const float* __restrict__ eW, const float* __restrict__ eb,
    const float* __restrict__ eps,
    float* __restrict__ agg, int layer)
{
    const int d    = threadIdx.x & 127;
    const int half = threadIdx.x >> 7;
    const long n   = (long)blockIdx.x * 2 + half;

    float w[EAA];
    #pragma unroll
    for (int a = 0; a < EAA; ++a) w[a] = eW[layer * EAA * DD + a * DD + d];
    const float bias = eb[layer * DD + d];
    const float epl  = 1.0f + eps[layer];

    float acc = epl * h_in[n * DD + d];
    const int p0 = rp[n], p1 = rp[n + 1];
    for (int p = p0; p < p1; ++p) {
        int e = eid_perm[p];
        int src = ei[e];
        float ea = bias;
        #pragma unroll
        for (int a = 0; a < EAA; ++a)
            ea = fmaf(eattr[(long)e * EAA + a], w[a], ea);
        float m = h_in[(long)src * DD + d] + ea;
        acc += m > 0.0f ? m : 0.0f;
    }
    agg[n * DD + d] = acc;
}

// ---------------------------------------------------------------------------
// K2 fallback B (atomic path)
// ---------------------------------------------------------------------------
#define EPB 64
__global__ __launch_bounds__(256) void edge_kernel(
    const float* __restrict__ h_in,
    const int* __restrict__ ei,
    const float* __restrict__ eattr,
    const float* __restrict__ eW,
    const float* __restrict__ eb,
    float* __restrict__ agg,
    int layer)
{
    const int d    = threadIdx.x & 127;
    const int esub = threadIdx.x >> 7;
    float w[EAA];
    #pragma unroll
    for (int a = 0; a < EAA; ++a) w[a] = eW[layer * EAA * DD + a * DD + d];
    const float bias = eb[layer * DD + d];

    const long base = (long)blockIdx.x * EPB;
    for (int k = esub; k < EPB; k += 2) {
        long e = base + k;
        if (e >= EE) break;
        int s = ei[e];
        int t = ei[EE + e];
        float acc = bias;
        #pragma unroll
        for (int a = 0; a < EAA; ++a)
            acc = fmaf(eattr[e * EAA + a], w[a], acc);
        float m = h_in[(long)s * DD + d] + acc;
        m = m > 0.0f ? m : 0.0f;
        atomicAdd(&agg[(long)t * DD + d], m);
    }
}

// ---------------------------------------------------------------------------
// Weight prep: split W1/W2 into bf16 hi/lo, swizzled to MFMA fragment order.
// W1 frag idx: fi = ((kk*16 + ct)*64 + lane)*8 + b ; k=kk*32+(lane>>4)*8+b,
//              j=ct*16+(lane&15).  W2: ct in 0..7, kk in 0..7.
// ---------------------------------------------------------------------------
__global__ __launch_bounds__(256) void wprep_kernel(
    const float* __restrict__ W1, const float* __restrict__ W2,
    unsigned short* __restrict__ w1h, unsigned short* __restrict__ w1l,
    unsigned short* __restrict__ w2h, unsigned short* __restrict__ w2l)
{
    int tid = blockIdx.x * 256 + threadIdx.x;
    if (tid >= LL * 2 * 32768) return;
    int l = tid / 65536;
    int rem = tid - l * 65536;
    int mat = rem >> 15;
    int fi = rem & 32767;
    int b = fi & 7, lane = (fi >> 3) & 63;
    if (mat == 0) {
        int ct = (fi >> 9) & 15, kk = fi >> 13;
        int k = kk * 32 + ((lane >> 4) << 3) + b;
        int j = (ct << 4) + (lane & 15);
        float v = W1[(long)l * DD * 2 * DD + (long)k * 2 * DD + j];
        unsigned short hi = f2bf(v);
        w1h[(long)l * 32768 + fi] = hi;
        w1l[(long)l * 32768 + fi] = f2bf(v - bf2f(hi));
    } else {
        int ct = (fi >> 9) & 7, kk = fi >> 12;
        int k = kk * 32 + ((lane >> 4) << 3) + b;
        int j = (ct << 4) + (lane & 15);
        float v = W2[(long)l * 2 * DD * DD + (long)k * DD + j];
        unsigned short hi = f2bf(v);
        w2h[(long)l * 32768 + fi] = hi;
        w2l[(long)l * 32768 + fi] = f2bf(v - bf2f(hi));
    }
}

// ---------------------------------------------------------------------------
// BN prep: fold bias+BN into per-column scale/shift.
// ---------------------------------------------------------------------------
__global__ __launch_bounds__(256) void bnprep_kernel(
    const float* __restrict__ b1, const float* __restrict__ g1,
    const float* __restrict__ be1, const float* __restrict__ m1,
    const float* __restrict__ v1,
    const float* __restrict__ b2, const float* __restrict__ g2,
    const float* __restrict__ be2, const float* __restrict__ m2,
    const float* __restrict__ v2,
    float* __restrict__ sc1, float* __restrict__ sh1,
    float* __restrict__ sc2, float* __restrict__ sh2)
{
    int tid = blockIdx.x * 256 + threadIdx.x;
    if (tid < LL * 2 * DD) {
        float sc = g1[tid] / sqrtf(v1[tid] + BN_EPS);
        sc1[tid] = sc;
        sh1[tid] = (b1[tid] - m1[tid]) * sc + be1[tid];
    }
    int t2 = tid - LL * 2 * DD;
    if (t2 >= 0 && t2 < LL * DD) {
        float sc = g2[t2] / sqrtf(v2[t2] + BN_EPS);
        sc2[t2] = sc;
        sh2[t2] = (b2[t2] - m2[t2]) * sc + be2[t2];
    }
}

// ---------------------------------------------------------------------------
// K3 (MFMA): per 64-row block: u = relu(bn1(z@W1)); h = bn2(u@W2) [+relu].
// Split precision: X ~ Xh + Xl (bf16 each); X@Y ~ Xh@Yh + Xh@Yl + Xl@Yh.
// 4 waves: GEMM1 wave owns col-tiles 4w..4w+3 (of 16); GEMM2 owns 2w..2w+1
// (of 8). z/u share one 64KB LDS buffer, XOR-swizzled byte^=(row&7)<<4.
// ---------------------------------------------------------------------------
__global__ __launch_bounds__(256, 2) void mlp_mfma_kernel(
    const float* __restrict__ z_in,
    const unsigned short* __restrict__ w1h, const unsigned short* __restrict__ w1l,
    const unsigned short* __restrict__ w2h, const unsigned short* __restrict__ w2l,
    const float* __restrict__ sc1, const float* __restrict__ sh1,
    const float* __restrict__ sc2, const float* __restrict__ sh2,
    float* __restrict__ h_out, int layer, int do_relu)
{
    __shared__ char lds[65536];
    const int tid  = threadIdx.x;
    const int lane = tid & 63;
    const int wv   = tid >> 6;
    const long row0 = (long)blockIdx.x * 64;

    // ---- stage z [64][128] fp32 -> hi/lo bf16 (z-hi at 0, z-lo at 16384) ----
    {
        const float4* zi = (const float4*)(z_in + row0 * DD);
        #pragma unroll
        for (int i = 0; i < 8; ++i) {
            int idx = tid + i * 256;
            float4 v = zi[idx];
            int r = idx >> 5;
            int c = (idx & 31) << 2;
            u16x4 hv, lv;
            hv.x = f2bf(v.x); lv.x = f2bf(v.x - bf2f(hv.x));
            hv.y = f2bf(v.y); lv.y = f2bf(v.y - bf2f(hv.y));
            hv.z = f2bf(v.z); lv.z = f2bf(v.z - bf2f(hv.z));
            hv.w = f2bf(v.w); lv.w = f2bf(v.w - bf2f(hv.w));
            int off = ((r << 8) + (c << 1)) ^ ((r & 7) << 4);
            *(u16x4*)(lds + off)         = hv;
            *(u16x4*)(lds + 16384 + off) = lv;
        }
    }
    __syncthreads();

    // ---- A1 fragments: all 4 row-tiles x 4 k-steps into registers ----
    bf16x8 A1h[4][4], A1l[4][4];
    {
        const int kb = (lane >> 4) << 3;
        #pragma unroll
        for (int rt = 0; rt < 4; ++rt) {
            int r = (rt << 4) + (lane & 15);
            #pragma unroll
            for (int kk = 0; kk < 4; ++kk) {
                int off = ((r << 8) + (((kk << 5) + kb) << 1)) ^ ((r & 7) << 4);
                A1h[rt][kk] = *(const bf16x8*)(lds + off);
                A1l[rt][kk] = *(const bf16x8*)(lds + 16384 + off);
            }
        }
    }
    __syncthreads();   // all z reads done; LDS becomes u (hi at 0, lo at 32768)

    // ---- GEMM1 + BN1 + relu -> u in LDS ----
    const unsigned short* w1hl = w1h + (long)layer * 32768;
    const unsigned short* w1ll = w1l + (long)layer * 32768;
    #pragma unroll
    for (int ct = 0; ct < 4; ++ct) {
        const int cg = (wv << 2) + ct;
        f32x4 acc[4];
        #pragma unroll
        for (int rt = 0; rt < 4; ++rt) acc[rt] = (f32x4){0.f, 0.f, 0.f, 0.f};
        #pragma unroll
        for (int kk = 0; kk < 4; ++kk) {
            const long boff = ((long)((kk << 4) + cg) * 64 + lane) << 3;
            bf16x8 Bh = *(const bf16x8*)(w1hl + boff);
            bf16x8 Bl = *(const bf16x8*)(w1ll + boff);
            #pragma unroll
            for (int rt = 0; rt < 4; ++rt) {
                acc[rt] = __builtin_amdgcn_mfma_f32_16x16x32_bf16(A1h[rt][kk], Bh, acc[rt], 0, 0, 0);
                acc[rt] = __builtin_amdgcn_mfma_f32_16x16x32_bf16(A1h[rt][kk], Bl, acc[rt], 0, 0, 0);
                acc[rt] = __builtin_amdgcn_mfma_f32_16x16x32_bf16(A1l[rt][kk], Bh, acc[rt], 0, 0, 0);
            }
        }
        const int j = (cg << 4) + (lane & 15);
        const float s = sc1[layer * 2 * DD + j];
        const float t = sh1[layer * 2 * DD + j];
        #pragma unroll
        for (int rt = 0; rt < 4; ++rt) {
            const int rb = (rt << 4) + ((lane >> 4) << 2);
            #pragma unroll
            for (int r = 0; r < 4; ++r) {
                float u = fmaf(acc[rt][r], s, t);
                u = fmaxf(u, 0.0f);
                unsigned short hi = f2bf(u);
                unsigned short lo = f2bf(u - bf2f(hi));
                int row = rb + r;
                int off = ((row << 9) + (j << 1)) ^ ((row & 7) << 4);
                *(unsigned short*)(lds + off)         = hi;
                *(unsigned short*)(lds + 32768 + off) = lo;
            }
        }
    }
    __syncthreads();

    // ---- GEMM2 + BN2 (+relu) -> h ----
    const unsigned short* w2hl = w2h + (long)layer * 32768;
    const unsigned short* w2ll = w2l + (long)layer * 32768;
    f32x4 acc2[2][4];
    #pragma unroll
    for (int c2 = 0; c2 < 2; ++c2)
        #pragma unroll
        for (int rt = 0; rt < 4; ++rt) acc2[c2][rt] = (f32x4){0.f, 0.f, 0.f, 0.f};

    #pragma unroll
    for (int kk = 0; kk < 8; ++kk) {
        bf16x8 A2h[4], A2l[4];
        const int kb = (kk << 5) + ((lane >> 4) << 3);
        #pragma unroll
        for (int rt = 0; rt < 4; ++rt) {
            int r = (rt << 4) + (lane & 15);
            int off = ((r << 9) + (kb << 1)) ^ ((r & 7) << 4);
            A2h[rt] = *(const bf16x8*)(lds + off);
            A2l[rt] = *(const bf16x8*)(lds + 32768 + off);
        }
        #pragma unroll
        for (int c2 = 0; c2 < 2; ++c2) {
            const int cg = (wv << 1) + c2;
            const long boff = ((long)((kk << 3) + cg) * 64 + lane) << 3;
            bf16x8 Bh = *(const bf16x8*)(w2hl + boff);
            bf16x8 Bl = *(const bf16x8*)(w2ll + boff);
            #pragma unroll
            for (int rt = 0; rt < 4; ++rt) {
                acc2[c2][rt] = __builtin_amdgcn_mfma_f32_16x16x32_bf16(A2h[rt], Bh, acc2[c2][rt], 0, 0, 0);
                acc2[c2][rt] = __builtin_amdgcn_mfma_f32_16x16x32_bf16(A2h[rt], Bl, acc2[c2][rt], 0, 0, 0);
                acc2[c2][rt] = __builtin_amdgcn_mfma_f32_16x16x32_bf16(A2l[rt], Bh, acc2[c2][rt], 0, 0, 0);
            }
        }
    }
    #pragma unroll
    for (int c2 = 0; c2 < 2; ++c2) {
        const int j = (((wv << 1) + c2) << 4) + (lane & 15);
        const float s = sc2[layer * DD + j];
        const float t = sh2[layer * DD + j];
        #pragma unroll
        for (int rt = 0; rt < 4; ++rt) {
            const int rb = (rt << 4) + ((lane >> 4) << 2);
            #pragma unroll
            for (int r = 0; r < 4; ++r) {
                long row = row0 + rb + r;
                if (row < NN) {
                    float u = fmaf(acc2[c2][rt][r], s, t);
                    if (do_relu) u = fmaxf(u, 0.0f);
                    h_out[row * DD + j] = u;
                }
            }
        }
    }
}

// ---------------------------------------------------------------------------
// K4: virtual-node MLP. One block per graph g.
// ---------------------------------------------------------------------------
__global__ __launch_bounds__(256) void vn_kernel(
    const float* __restrict__ vt, float* __restrict__ vn,
    const float* __restrict__ W1, const float* __restrict__ b1,
    const float* __restrict__ g1, const float* __restrict__ be1,
    const float* __restrict__ m1, const float* __restrict__ v1,
    const float* __restrict__ W2, const float* __restrict__ b2,
    const float* __restrict__ g2, const float* __restrict__ be2,
    const float* __restrict__ m2, const float* __restrict__ v2,
    int layer)
{
    __shared__ float row[DD];
    __shared__ float u[2 * DD];
    const int g = blockIdx.x;
    const int t = threadIdx.x;

    if (t < DD) row[t] = vt[(long)g * DD + t] + vn[(long)g * DD + t];
    __syncthreads();

    {
        const float* W = W1 + (long)layer * DD * 2 * DD;
        float acc = 0.0f;
        for (int k = 0; k < DD; ++k) acc = fmaf(row[k], W[k * 2 * DD + t], acc);
        const long o = (long)layer * 2 * DD + t;
        float sc = g1[o] / sqrtf(v1[o] + BN_EPS);
        float sh = be1[o] - m1[o] * sc;
        float val = (acc + b1[o]) * sc + sh;
        u[t] = val > 0.0f ? val : 0.0f;
    }
    __syncthreads();

    if (t < DD) {
        const float* W = W2 + (long)layer * 2 * DD * DD;
        float acc = 0.0f;
        for (int k = 0; k < 2 * DD; ++k) acc = fmaf(u[k], W[k * DD + t], acc);
        const long o = (long)layer * DD + t;
        float sc = g2[o] / sqrtf(v2[o] + BN_EPS);
        float sh = be2[o] - m2[o] * sc;
        float val = (acc + b2[o]) * sc + sh;
        vn[(long)g * DD + t] = val > 0.0f ? val : 0.0f;
    }
}

// ---------------------------------------------------------------------------
extern "C" void kernel_launch(void* const* d_in, const int* in_sizes, int n_in,
                              void* d_out, int out_size, void* d_ws, size_t ws_size,
                              hipStream_t stream)
{
    const int*   x       = (const int*)  d_in[0];
    const int*   ei      = (const int*)  d_in[1];
    const float* eattr   = (const float*)d_in[2];
    const int*   batch   = (const int*)  d_in[3];
    const float* node_emb= (const float*)d_in[4];
    const float* vn_emb  = (const float*)d_in[5];
    const float* edge_W  = (const float*)d_in[6];
    const float* edge_b  = (const float*)d_in[7];
    const float* eps     = (const float*)d_in[8];
    const float* mlp_W1  = (const float*)d_in[9];
    const float* mlp_b1  = (const float*)d_in[10];
    const float* mbn_g   = (const float*)d_in[11];
    const float* mbn_b   = (const float*)d_in[12];
    const float* mbn_m   = (const float*)d_in[13];
    const float* mbn_v   = (const float*)d_in[14];
    const float* mlp_W2  = (const float*)d_in[15];
    const float* mlp_b2  = (const float*)d_in[16];
    const float* bn_g    = (const float*)d_in[17];
    const float* bn_b    = (const float*)d_in[18];
    const float* bn_m    = (const float*)d_in[19];
    const float* bn_v    = (const float*)d_in[20];
    const float* vn_W1   = (const float*)d_in[21];
    const float* vn_b1   = (const float*)d_in[22];
    const float* vbn1_g  = (const float*)d_in[23];
    const float* vbn1_b  = (const float*)d_in[24];
    const float* vbn1_m  = (const float*)d_in[25];
    const float* vbn1_v  = (const float*)d_in[26];
    const float* vn_W2   = (const float*)d_in[27];
    const float* vn_b2   = (const float*)d_in[28];
    const float* vbn2_g  = (const float*)d_in[29];
    const float* vbn2_b  = (const float*)d_in[30];
    const float* vbn2_m  = (const float*)d_in[31];
    const float* vbn2_v  = (const float*)d_in[32];

    float* h = (float*)d_out;
    char*  ws = (char*)d_ws;

    size_t off = 0;
    auto alloc = [&](size_t bytes) -> void* {
        void* p = ws + off;
        off += (bytes + 255) & ~(size_t)255;
        return p;
    };
    const size_t GDB = (size_t)GG * DD * sizeof(float);

    float* agg      = (float*)alloc((size_t)NP * DD * sizeof(float));  // padded to 64 rows
    float* vn       = (float*)alloc(GDB);
    float* vt       = (float*)alloc(GDB);
    int*   rp       = (int*)  alloc((NN + 1) * sizeof(int));
    int*   fill     = (int*)  alloc(NN * sizeof(int));
    int*   partials = (int*)  alloc(128 * sizeof(int));
    int*   src_arr  = (int*)  alloc((size_t)EE * sizeof(int));
    unsigned short* w1h = (unsigned short*)alloc(LL * 32768 * sizeof(unsigned short));
    unsigned short* w1l = (unsigned short*)alloc(LL * 32768 * sizeof(unsigned short));
    unsigned short* w2h = (unsigned short*)alloc(LL * 32768 * sizeof(unsigned short));
    unsigned short* w2l = (unsigned short*)alloc(LL * 32768 * sizeof(unsigned short));
    float* bn1sc = (float*)alloc(LL * 2 * DD * sizeof(float));
    float* bn1sh = (float*)alloc(LL * 2 * DD * sizeof(float));
    float* bn2sc = (float*)alloc(LL * DD * sizeof(float));
    float* bn2sh = (float*)alloc(LL * DD * sizeof(float));
    const size_t base_end = off;

    float* rec = nullptr;
    int*   eid_perm = nullptr;
    if (ws_size >= base_end + (size_t)EE * 8 * sizeof(float))
        rec = (float*)alloc((size_t)EE * 8 * sizeof(float));
    else if (ws_size >= base_end + (size_t)EE * sizeof(int))
        eid_perm = (int*)alloc((size_t)EE * sizeof(int));
    const bool csr = (rec != nullptr) || (eid_perm != nullptr);

    // K0: init h and vn
    {
        long total = (long)NN * DD;
        init_kernel<<<(int)((total + 255) / 256), 256, 0, stream>>>(
            x, node_emb, vn_emb, h, vn);
    }

    // Weight/BN prep (once)
    wprep_kernel<<<(LL * 2 * 32768 + 255) / 256, 256, 0, stream>>>(
        mlp_W1, mlp_W2, w1h, w1l, w2h, w2l);
    bnprep_kernel<<<(LL * 2 * DD + LL * DD + 255) / 256, 256, 0, stream>>>(
        mlp_b1, mbn_g, mbn_b, mbn_m, mbn_v,
        mlp_b2, bn_g, bn_b, bn_m, bn_v,
        bn1sc, bn1sh, bn2sc, bn2sh);

    // CSR build (once)
    if (csr) {
        const int egrid = (EE + 255) / 256;
        const int ngrid = (NN + 1023) / 1024;
        hipMemsetAsync(fill, 0, NN * sizeof(int), stream);
        count_kernel<<<egrid, 256, 0, stream>>>(ei, fill);
        scan_a<<<ngrid, 1024, 0, stream>>>(fill, rp, partials);
        scan_b<<<1, 64, 0, stream>>>(partials, ngrid);
        scan_c<<<ngrid, 1024, 0, stream>>>(rp, fill, partials);
        scatter_kernel<<<egrid, 256, 0, stream>>>(ei, eattr, fill, rec, src_arr, eid_perm);
    }

    for (int l = 0; l < LL; ++l) {
        int accum = (l < LL - 1) ? 1 : 0;
        if (accum)
            hipMemsetAsync(vt, 0, GDB, stream);

        hin_kernel<<<NN / (R1 * 2), 256, 0, stream>>>(
            h, vn, batch, eps, agg, vt, l, accum, csr ? 0 : 1);

        if (rec) {
            gin_agg_kernel<<<NN / 4, 256, 0, stream>>>(
                h, rp, rec, src_arr, edge_W, edge_b, eps, agg, l);
        } else if (eid_perm) {
            gin_agg_eid_kernel<<<NN / 2, 256, 0, stream>>>(
                h, rp, eid_perm, ei, eattr, edge_W, edge_b, eps, agg, l);
        } else {
            edge_kernel<<<(EE + EPB - 1) / EPB, 256, 0, stream>>>(
                h, ei, eattr, edge_W, edge_b, agg, l);
        }

        mlp_mfma_kernel<<<NP / 64, 256, 0, stream>>>(
            agg, w1h, w1l, w2h, w2l, bn1sc, bn1sh, bn2sc, bn2sh,
            h, l, accum);

        if (accum)
            vn_kernel<<<GG, 256, 0, stream>>>(
                vt, vn, vn_W1, vn_b1, vbn1_g, vbn1_b, vbn1_m, vbn1_v,
                vn_W2, vn_b2, vbn2_g, vbn2_b, vbn2_m, vbn2_v, l);
    }
}

// Round 5
// 840.675 us; speedup vs baseline: 3.4498x; 1.2135x over previous
//
#include <hip/hip_runtime.h>
#include <hip/hip_bf16.h>

#define NN 100000
#define NP 100032              // NN rounded up to 64
#define EE 1600000
#define GG 128
#define DD 128
#define LL 3
#define EAA 7
#define BN_EPS 1e-5f

typedef __attribute__((ext_vector_type(8))) short bf16x8;
typedef __attribute__((ext_vector_type(4))) float f32x4;
typedef __attribute__((ext_vector_type(4))) unsigned short u16x4;

__device__ __forceinline__ unsigned short f2bf(float x) {
    unsigned int u = __float_as_uint(x);
    u = (u + 0x7FFF + ((u >> 16) & 1)) >> 16;
    return (unsigned short)u;
}
__device__ __forceinline__ float bf2f(unsigned short h) {
    return __uint_as_float(((unsigned int)h) << 16);
}
__device__ __forceinline__ float bflo(unsigned int u) {
    return __uint_as_float(u << 16);
}
__device__ __forceinline__ float bfhi(unsigned int u) {
    return __uint_as_float(u & 0xFFFF0000u);
}

// ---------------------------------------------------------------------------
// K0: h[i,:] = node_emb[x[i],:]; vn[g,:] = vn_emb[0,:]
// ---------------------------------------------------------------------------
__global__ __launch_bounds__(256) void init_kernel(
    const int* __restrict__ x, const float* __restrict__ node_emb,
    const float* __restrict__ vn_emb, float* __restrict__ h,
    float* __restrict__ vn)
{
    long i = (long)blockIdx.x * 256 + threadIdx.x;
    if (i < (long)NN * DD) {
        int node = (int)(i >> 7), d = (int)(i & 127);
        h[i] = node_emb[(long)x[node] * DD + d];
    }
    if (i < GG * DD) vn[i] = vn_emb[i & 127];
}

// ---------------------------------------------------------------------------
// K1: in-place h -> h_in = h + vn[batch]; bf16 shadow copy h16 for gathers;
// optional agg=(1+eps)h_in (atomic fallback); optional vt[g] += h_in rows.
// ---------------------------------------------------------------------------
#define R1 8
__global__ __launch_bounds__(256) void hin_kernel(
    float* __restrict__ hbuf,
    unsigned short* __restrict__ h16,
    const float* __restrict__ vn,
    const int* __restrict__ batch,
    const float* __restrict__ eps,
    float* __restrict__ agg,
    float* __restrict__ vt,
    int layer, int accum_vt, int write_agg)
{
    const int d  = threadIdx.x & 127;
    const int rg = threadIdx.x >> 7;
    const float epl = 1.0f + eps[layer];
    const long row0 = (long)blockIdx.x * (R1 * 2);

    float vacc = 0.0f;
    int   vb   = -1;
    #pragma unroll
    for (int r = 0; r < R1; ++r) {
        long row = row0 + rg + 2 * r;
        if (row >= NN) break;
        int b = batch[row];
        long idx = row * DD + d;
        float hv = hbuf[idx] + vn[(long)b * DD + d];
        hbuf[idx] = hv;
        h16[idx]  = f2bf(hv);
        if (write_agg) agg[idx] = epl * hv;
        if (accum_vt) {
            if (b != vb) {
                if (vb >= 0) atomicAdd(&vt[(long)vb * DD + d], vacc);
                vb = b; vacc = 0.0f;
            }
            vacc += hv;
        }
    }
    if (accum_vt && vb >= 0) atomicAdd(&vt[(long)vb * DD + d], vacc);
}

// ---------------------------------------------------------------------------
// CSR build: count -> scan -> scatter. Built once, reused by all 3 layers.
// ---------------------------------------------------------------------------
__global__ __launch_bounds__(256) void count_kernel(
    const int* __restrict__ ei, int* __restrict__ deg)
{
    long e = (long)blockIdx.x * 256 + threadIdx.x;
    if (e < EE) atomicAdd(&deg[ei[EE + e]], 1);
}

__global__ __launch_bounds__(1024) void scan_a(
    const int* __restrict__ deg, int* __restrict__ rp, int* __restrict__ partials)
{
    __shared__ int s[1024];
    int t = threadIdx.x;
    long i = (long)blockIdx.x * 1024 + t;
    int v = (i < NN) ? deg[i] : 0;
    s[t] = v;
    __syncthreads();
    for (int off = 1; off < 1024; off <<= 1) {
        int u = (t >= off) ? s[t - off] : 0;
        __syncthreads();
        s[t] += u;
        __syncthreads();
    }
    if (i < NN) rp[i] = s[t] - v;
    if (t == 1023) partials[blockIdx.x] = s[1023];
}

__global__ void scan_b(int* __restrict__ partials, int nb)
{
    if (threadIdx.x == 0) {
        int run = 0;
        for (int i = 0; i < nb; ++i) { int v = partials[i]; partials[i] = run; run += v; }
    }
}

__global__ __launch_bounds__(1024) void scan_c(
    int* __restrict__ rp, int* __restrict__ fill, const int* __restrict__ partials)
{
    long i = (long)blockIdx.x * 1024 + threadIdx.x;
    if (i < NN) {
        int v = rp[i] + partials[blockIdx.x];
        rp[i] = v;
        fill[i] = v;
    }
    if (i == 0) rp[NN] = EE;
}

// Tier-1: attr16 = 8 ushorts per edge (7 bf16 attrs + pad), src separate.
__global__ __launch_bounds__(256) void scatter_kernel(
    const int* __restrict__ ei, const float* __restrict__ eattr,
    int* __restrict__ fill, unsigned short* __restrict__ attr16,
    int* __restrict__ src_arr, int* __restrict__ eid_perm)
{
    long e = (long)blockIdx.x * 256 + threadIdx.x;
    if (e >= EE) return;
    int dst = ei[EE + e];
    int pos = atomicAdd(&fill[dst], 1);
    if (attr16) {
        u16x4 w0, w1;
        w0.x = f2bf(eattr[e * EAA + 0]);
        w0.y = f2bf(eattr[e * EAA + 1]);
        w0.z = f2bf(eattr[e * EAA + 2]);
        w0.w = f2bf(eattr[e * EAA + 3]);
        w1.x = f2bf(eattr[e * EAA + 4]);
        w1.y = f2bf(eattr[e * EAA + 5]);
        w1.z = f2bf(eattr[e * EAA + 6]);
        w1.w = 0;
        *(u16x4*)(attr16 + (long)pos * 8)     = w0;
        *(u16x4*)(attr16 + (long)pos * 8 + 4) = w1;
        src_arr[pos] = ei[e];
    } else {
        eid_perm[pos] = (int)e;
    }
}

// ---------------------------------------------------------------------------
// K2 (CSR, ILP): one wave per dst node; lane owns cols {2l, 2l+1}; x4 unroll.
// Gathers read the bf16 shadow h16 (4 B/lane); attrs read packed bf16 (16 B).
// ---------------------------------------------------------------------------
__global__ __launch_bounds__(256) void gin_agg_kernel(
    const float* __restrict__ h_in,
    const unsigned short* __restrict__ h16,
    const int* __restrict__ rp,
    const unsigned short* __restrict__ attr16,
    const int* __restrict__ src_arr,
    const float* __restrict__ eW, const float* __restrict__ eb,
    const float* __restrict__ eps,
    float* __restrict__ agg, int layer)
{
    const int lane = threadIdx.x & 63;
    const int wid  = threadIdx.x >> 6;
    const long n   = (long)blockIdx.x * 4 + wid;
    const int d0   = lane * 2;

    const float* eWl = eW + (long)layer * EAA * DD;
    float2 w2[EAA];
    #pragma unroll
    for (int a = 0; a < EAA; ++a)
        w2[a] = *(const float2*)&eWl[a * DD + d0];
    const float2 bias = *(const float2*)&eb[layer * DD + d0];
    const float  epl  = 1.0f + eps[layer];

    float2 hn = *(const float2*)&h_in[n * DD + d0];
    float accx = epl * hn.x, accy = epl * hn.y;

    int p  = rp[n];
    const int p1 = rp[n + 1];

    #define EDGE(AU, GU)                                                      \
    {                                                                         \
        float a0 = bflo(AU.x), a1 = bfhi(AU.x);                               \
        float a2 = bflo(AU.y), a3 = bfhi(AU.y);                               \
        float a4 = bflo(AU.z), a5 = bfhi(AU.z);                               \
        float a6 = bflo(AU.w);                                                \
        float ex = bias.x, ey = bias.y;                                       \
        ex = fmaf(a0, w2[0].x, ex); ey = fmaf(a0, w2[0].y, ey);               \
        ex = fmaf(a1, w2[1].x, ex); ey = fmaf(a1, w2[1].y, ey);               \
        ex = fmaf(a2, w2[2].x, ex); ey = fmaf(a2, w2[2].y, ey);               \
        ex = fmaf(a3, w2[3].x, ex); ey = fmaf(a3, w2[3].y, ey);               \
        ex = fmaf(a4, w2[4].x, ex); ey = fmaf(a4, w2[4].y, ey);               \
        ex = fmaf(a5, w2[5].x, ex); ey = fmaf(a5, w2[5].y, ey);               \
        ex = fmaf(a6, w2[6].x, ex); ey = fmaf(a6, w2[6].y, ey);               \
        float mx = bflo(GU) + ex, my = bfhi(GU) + ey;                         \
        accx += fmaxf(mx, 0.0f); accy += fmaxf(my, 0.0f);                     \
    }

    for (; p + 4 <= p1; p += 4) {
        int s0 = src_arr[p];
        int s1 = src_arr[p + 1];
        int s2 = src_arr[p + 2];
        int s3 = src_arr[p + 3];
        const uint4* a4p = (const uint4*)(attr16 + (long)p * 8);
        uint4 A0 = a4p[0];
        uint4 A1 = a4p[1];
        uint4 A2 = a4p[2];
        uint4 A3 = a4p[3];
        unsigned int g0 = *(const unsigned int*)(h16 + (long)s0 * DD + d0);
        unsigned int g1 = *(const unsigned int*)(h16 + (long)s1 * DD + d0);
        unsigned int g2 = *(const unsigned int*)(h16 + (long)s2 * DD + d0);
        unsigned int g3 = *(const unsigned int*)(h16 + (long)s3 * DD + d0);
        EDGE(A0, g0)
        EDGE(A1, g1)
        EDGE(A2, g2)
        EDGE(A3, g3)
    }
    for (; p < p1; ++p) {
        int s = src_arr[p];
        uint4 A = *(const uint4*)(attr16 + (long)p * 8);
        unsigned int g = *(const unsigned int*)(h16 + (long)s * DD + d0);
        EDGE(A, g)
    }
    #undef EDGE

    *(float2*)&agg[n * DD + d0] = make_float2(accx, accy);
}

// ---------------------------------------------------------------------------
// K2 fallback A (eid indirection)
// ---------------------------------------------------------------------------
__global__ __launch_bounds__(256) void gin_agg_eid_kernel(
    const float* __restrict__ h_in,
    const int* __restrict__ rp,
    const int* __restrict__ eid_perm,
    const int* __restrict__ ei,
    const float* __restrict__ eattr,
    const float* __restrict__ eW, const float* __restrict__ eb,
    const float* __restrict__ eps,
    float* __restrict__ agg, int layer)
{
    const int d    = threadIdx.x & 127;
    const int half = threadIdx.x >> 7;
    const long n   = (long)blockIdx.x * 2 + half;

    float w[EAA];
    #pragma unroll
    for (int a = 0; a < EAA; ++a) w[a] = eW[layer * EAA * DD + a * DD + d];
    const float bias = eb[layer * DD + d];
    const float epl  = 1.0f + eps[layer];

    float acc = epl * h_in[n * DD + d];
    const int p0 = rp[n], p1 = rp[n + 1];
    for (int p = p0; p < p1; ++p) {
        int e = eid_perm[p];
        int src = ei[e];
        float ea = bias;
        #pragma unroll
        for (int a = 0; a < EAA; ++a)
            ea = fmaf(eattr[(long)e * EAA + a], w[a], ea);
        float m = h_in[(long)src * DD + d] + ea;
        acc += m > 0.0f ? m : 0.0f;
    }
    agg[n * DD + d] = acc;
}

// ---------------------------------------------------------------------------
// K2 fallback B (atomic path)
// ---------------------------------------------------------------------------
#define EPB 64
__global__ __launch_bounds__(256) void edge_kernel(
    const float* __restrict__ h_in,
    const int* __restrict__ ei,
    const float* __restrict__ eattr,
    const float* __restrict__ eW,
    const float* __restrict__ eb,
    float* __restrict__ agg,
    int layer)
{
    const int d    = threadIdx.x & 127;
    const int esub = threadIdx.x >> 7;
    float w[EAA];
    #pragma unroll
    for (int a = 0; a < EAA; ++a) w[a] = eW[layer * EAA * DD + a * DD + d];
    const float bias = eb[layer * DD + d];

    const long base = (long)blockIdx.x * EPB;
    for (int k = esub; k < EPB; k += 2) {
        long e = base + k;
        if (e >= EE) break;
        int s = ei[e];
        int t = ei[EE + e];
        float acc = bias;
        #pragma unroll
        for (int a = 0; a < EAA; ++a)
            acc = fmaf(eattr[e * EAA + a], w[a], acc);
        float m = h_in[(long)s * DD + d] + acc;
        m = m > 0.0f ? m : 0.0f;
        atomicAdd(&agg[(long)t * DD + d], m);
    }
}

// ---------------------------------------------------------------------------
// Weight prep: split W1/W2 into bf16 hi/lo, swizzled to MFMA fragment order.
// ---------------------------------------------------------------------------
__global__ __launch_bounds__(256) void wprep_kernel(
    const float* __restrict__ W1, const float* __restrict__ W2,
    unsigned short* __restrict__ w1h, unsigned short* __restrict__ w1l,
    unsigned short* __restrict__ w2h, unsigned short* __restrict__ w2l)
{
    int tid = blockIdx.x * 256 + threadIdx.x;
    if (tid >= LL * 2 * 32768) return;
    int l = tid / 65536;
    int rem = tid - l * 65536;
    int mat = rem >> 15;
    int fi = rem & 32767;
    int b = fi & 7, lane = (fi >> 3) & 63;
    if (mat == 0) {
        int ct = (fi >> 9) & 15, kk = fi >> 13;
        int k = kk * 32 + ((lane >> 4) << 3) + b;
        int j = (ct << 4) + (lane & 15);
        float v = W1[(long)l * DD * 2 * DD + (long)k * 2 * DD + j];
        unsigned short hi = f2bf(v);
        w1h[(long)l * 32768 + fi] = hi;
        w1l[(long)l * 32768 + fi] = f2bf(v - bf2f(hi));
    } else {
        int ct = (fi >> 9) & 7, kk = fi >> 12;
        int k = kk * 32 + ((lane >> 4) << 3) + b;
        int j = (ct << 4) + (lane & 15);
        float v = W2[(long)l * 2 * DD * DD + (long)k * DD + j];
        unsigned short hi = f2bf(v);
        w2h[(long)l * 32768 + fi] = hi;
        w2l[(long)l * 32768 + fi] = f2bf(v - bf2f(hi));
    }
}

// ---------------------------------------------------------------------------
// BN prep: fold bias+BN into per-column scale/shift.
// ---------------------------------------------------------------------------
__global__ __launch_bounds__(256) void bnprep_kernel(
    const float* __restrict__ b1, const float* __restrict__ g1,
    const float* __restrict__ be1, const float* __restrict__ m1,
    const float* __restrict__ v1,
    const float* __restrict__ b2, const float* __restrict__ g2,
    const float* __restrict__ be2, const float* __restrict__ m2,
    const float* __restrict__ v2,
    float* __restrict__ sc1, float* __restrict__ sh1,
    float* __restrict__ sc2, float* __restrict__ sh2)
{
    int tid = blockIdx.x * 256 + threadIdx.x;
    if (tid < LL * 2 * DD) {
        float sc = g1[tid] / sqrtf(v1[tid] + BN_EPS);
        sc1[tid] = sc;
        sh1[tid] = (b1[tid] - m1[tid]) * sc + be1[tid];
    }
    int t2 = tid - LL * 2 * DD;
    if (t2 >= 0 && t2 < LL * DD) {
        float sc = g2[t2] / sqrtf(v2[t2] + BN_EPS);
        sc2[t2] = sc;
        sh2[t2] = (b2[t2] - m2[t2]) * sc + be2[t2];
    }
}

// ---------------------------------------------------------------------------
// K3 (MFMA): per 64-row block: u = relu(bn1(z@W1)); h = bn2(u@W2) [+relu].
// Split precision: X ~ Xh + Xl; X@Y ~ Xh@Yh + Xh@Yl + Xl@Yh.
// ---------------------------------------------------------------------------
__global__ __launch_bounds__(256, 2) void mlp_mfma_kernel(
    const float* __restrict__ z_in,
    const unsigned short* __restrict__ w1h, const unsigned short* __restrict__ w1l,
    const unsigned short* __restrict__ w2h, const unsigned short* __restrict__ w2l,
    const float* __restrict__ sc1, const float* __restrict__ sh1,
    const float* __restrict__ sc2, const float* __restrict__ sh2,
    float* __restrict__ h_out, int layer, int do_relu)
{
    __shared__ char lds[65536];
    const int tid  = threadIdx.x;
    const int lane = tid & 63;
    const int wv   = tid >> 6;
    const long row0 = (long)blockIdx.x * 64;

    // ---- stage z [64][128] fp32 -> hi/lo bf16 (z-hi at 0, z-lo at 16384) ----
    {
        const float4* zi = (const float4*)(z_in + row0 * DD);
        #pragma unroll
        for (int i = 0; i < 8; ++i) {
            int idx = tid + i * 256;
            float4 v = zi[idx];
            int r = idx >> 5;
            int c = (idx & 31) << 2;
            u16x4 hv, lv;
            hv.x = f2bf(v.x); lv.x = f2bf(v.x - bf2f(hv.x));
            hv.y = f2bf(v.y); lv.y = f2bf(v.y - bf2f(hv.y));
            hv.z = f2bf(v.z); lv.z = f2bf(v.z - bf2f(hv.z));
            hv.w = f2bf(v.w); lv.w = f2bf(v.w - bf2f(hv.w));
            int off = ((r << 8) + (c << 1)) ^ ((r & 7) << 4);
            *(u16x4*)(lds + off)         = hv;
            *(u16x4*)(lds + 16384 + off) = lv;
        }
    }
    __syncthreads();

    // ---- A1 fragments ----
    bf16x8 A1h[4][4], A1l[4][4];
    {
        const int kb = (lane >> 4) << 3;
        #pragma unroll
        for (int rt = 0; rt < 4; ++rt) {
            int r = (rt << 4) + (lane & 15);
            #pragma unroll
            for (int kk = 0; kk < 4; ++kk) {
                int off = ((r << 8) + (((kk << 5) + kb) << 1)) ^ ((r & 7) << 4);
                A1h[rt][kk] = *(const bf16x8*)(lds + off);
                A1l[rt][kk] = *(const bf16x8*)(lds + 16384 + off);
            }
        }
    }
    __syncthreads();

    // ---- GEMM1 + BN1 + relu -> u in LDS ----
    const unsigned short* w1hl = w1h + (long)layer * 32768;
    const unsigned short* w1ll = w1l + (long)layer * 32768;
    #pragma unroll
    for (int ct = 0; ct < 4; ++ct) {
        const int cg = (wv << 2) + ct;
        f32x4 acc[4];
        #pragma unroll
        for (int rt = 0; rt < 4; ++rt) acc[rt] = (f32x4){0.f, 0.f, 0.f, 0.f};
        #pragma unroll
        for (int kk = 0; kk < 4; ++kk) {
            const long boff = ((long)((kk << 4) + cg) * 64 + lane) << 3;
            bf16x8 Bh = *(const bf16x8*)(w1hl + boff);
            bf16x8 Bl = *(const bf16x8*)(w1ll + boff);
            #pragma unroll
            for (int rt = 0; rt < 4; ++rt) {
                acc[rt] = __builtin_amdgcn_mfma_f32_16x16x32_bf16(A1h[rt][kk], Bh, acc[rt], 0, 0, 0);
                acc[rt] = __builtin_amdgcn_mfma_f32_16x16x32_bf16(A1h[rt][kk], Bl, acc[rt], 0, 0, 0);
                acc[rt] = __builtin_amdgcn_mfma_f32_16x16x32_bf16(A1l[rt][kk], Bh, acc[rt], 0, 0, 0);
            }
        }
        const int j = (cg << 4) + (lane & 15);
        const float s = sc1[layer * 2 * DD + j];
        const float t = sh1[layer * 2 * DD + j];
        #pragma unroll
        for (int rt = 0; rt < 4; ++rt) {
            const int rb = (rt << 4) + ((lane >> 4) << 2);
            #pragma unroll
            for (int r = 0; r < 4; ++r) {
                float u = fmaf(acc[rt][r], s, t);
                u = fmaxf(u, 0.0f);
                unsigned short hi = f2bf(u);
                unsigned short lo = f2bf(u - bf2f(hi));
                int row = rb + r;
                int off = ((row << 9) + (j << 1)) ^ ((row & 7) << 4);
                *(unsigned short*)(lds + off)         = hi;
                *(unsigned short*)(lds + 32768 + off) = lo;
            }
        }
    }
    __syncthreads();

    // ---- GEMM2 + BN2 (+relu) -> h ----
    const unsigned short* w2hl = w2h + (long)layer * 32768;
    const unsigned short* w2ll = w2l + (long)layer * 32768;
    f32x4 acc2[2][4];
    #pragma unroll
    for (int c2 = 0; c2 < 2; ++c2)
        #pragma unroll
        for (int rt = 0; rt < 4; ++rt) acc2[c2][rt] = (f32x4){0.f, 0.f, 0.f, 0.f};

    #pragma unroll
    for (int kk = 0; kk < 8; ++kk) {
        bf16x8 A2h[4], A2l[4];
        const int kb = (kk << 5) + ((lane >> 4) << 3);
        #pragma unroll
        for (int rt = 0; rt < 4; ++rt) {
            int r = (rt << 4) + (lane & 15);
            int off = ((r << 9) + (kb << 1)) ^ ((r & 7) << 4);
            A2h[rt] = *(const bf16x8*)(lds + off);
            A2l[rt] = *(const bf16x8*)(lds + 32768 + off);
        }
        #pragma unroll
        for (int c2 = 0; c2 < 2; ++c2) {
            const int cg = (wv << 1) + c2;
            const long boff = ((long)((kk << 3) + cg) * 64 + lane) << 3;
            bf16x8 Bh = *(const bf16x8*)(w2hl + boff);
            bf16x8 Bl = *(const bf16x8*)(w2ll + boff);
            #pragma unroll
            for (int rt = 0; rt < 4; ++rt) {
                acc2[c2][rt] = __builtin_amdgcn_mfma_f32_16x16x32_bf16(A2h[rt], Bh, acc2[c2][rt], 0, 0, 0);
                acc2[c2][rt] = __builtin_amdgcn_mfma_f32_16x16x32_bf16(A2h[rt], Bl, acc2[c2][rt], 0, 0, 0);
                acc2[c2][rt] = __builtin_amdgcn_mfma_f32_16x16x32_bf16(A2l[rt], Bh, acc2[c2][rt], 0, 0, 0);
            }
        }
    }
    #pragma unroll
    for (int c2 = 0; c2 < 2; ++c2) {
        const int j = (((wv << 1) + c2) << 4) + (lane & 15);
        const float s = sc2[layer * DD + j];
        const float t = sh2[layer * DD + j];
        #pragma unroll
        for (int rt = 0; rt < 4; ++rt) {
            const int rb = (rt << 4) + ((lane >> 4) << 2);
            #pragma unroll
            for (int r = 0; r < 4; ++r) {
                long row = row0 + rb + r;
                if (row < NN) {
                    float u = fmaf(acc2[c2][rt][r], s, t);
                    if (do_relu) u = fmaxf(u, 0.0f);
                    h_out[row * DD + j] = u;
                }
            }
        }
    }
}

// ---------------------------------------------------------------------------
// K4: virtual-node MLP. One block per graph g.
// ---------------------------------------------------------------------------
__global__ __launch_bounds__(256) void vn_kernel(
    const float* __restrict__ vt, float* __restrict__ vn,
    const float* __restrict__ W1, const float* __restrict__ b1,
    const float* __restrict__ g1, const float* __restrict__ be1,
    const float* __restrict__ m1, const float* __restrict__ v1,
    const float* __restrict__ W2, const float* __restrict__ b2,
    const float* __restrict__ g2, const float* __restrict__ be2,
    const float* __restrict__ m2, const float* __restrict__ v2,
    int layer)
{
    __shared__ float row[DD];
    __shared__ float u[2 * DD];
    const int g = blockIdx.x;
    const int t = threadIdx.x;

    if (t < DD) row[t] = vt[(long)g * DD + t] + vn[(long)g * DD + t];
    __syncthreads();

    {
        const float* W = W1 + (long)layer * DD * 2 * DD;
        float acc = 0.0f;
        for (int k = 0; k < DD; ++k) acc = fmaf(row[k], W[k * 2 * DD + t], acc);
        const long o = (long)layer * 2 * DD + t;
        float sc = g1[o] / sqrtf(v1[o] + BN_EPS);
        float sh = be1[o] - m1[o] * sc;
        float val = (acc + b1[o]) * sc + sh;
        u[t] = val > 0.0f ? val : 0.0f;
    }
    __syncthreads();

    if (t < DD) {
        const float* W = W2 + (long)layer * 2 * DD * DD;
        float acc = 0.0f;
        for (int k = 0; k < 2 * DD; ++k) acc = fmaf(u[k], W[k * DD + t], acc);
        const long o = (long)layer * DD + t;
        float sc = g2[o] / sqrtf(v2[o] + BN_EPS);
        float sh = be2[o] - m2[o] * sc;
        float val = (acc + b2[o]) * sc + sh;
        vn[(long)g * DD + t] = val > 0.0f ? val : 0.0f;
    }
}

// ---------------------------------------------------------------------------
extern "C" void kernel_launch(void* const* d_in, const int* in_sizes, int n_in,
                              void* d_out, int out_size, void* d_ws, size_t ws_size,
                              hipStream_t stream)
{
    const int*   x       = (const int*)  d_in[0];
    const int*   ei      = (const int*)  d_in[1];
    const float* eattr   = (const float*)d_in[2];
    const int*   batch   = (const int*)  d_in[3];
    const float* node_emb= (const float*)d_in[4];
    const float* vn_emb  = (const float*)d_in[5];
    const float* edge_W  = (const float*)d_in[6];
    const float* edge_b  = (const float*)d_in[7];
    const float* eps     = (const float*)d_in[8];
    const float* mlp_W1  = (const float*)d_in[9];
    const float* mlp_b1  = (const float*)d_in[10];
    const float* mbn_g   = (const float*)d_in[11];
    const float* mbn_b   = (const float*)d_in[12];
    const float* mbn_m   = (const float*)d_in[13];
    const float* mbn_v   = (const float*)d_in[14];
    const float* mlp_W2  = (const float*)d_in[15];
    const float* mlp_b2  = (const float*)d_in[16];
    const float* bn_g    = (const float*)d_in[17];
    const float* bn_b    = (const float*)d_in[18];
    const float* bn_m    = (const float*)d_in[19];
    const float* bn_v    = (const float*)d_in[20];
    const float* vn_W1   = (const float*)d_in[21];
    const float* vn_b1   = (const float*)d_in[22];
    const float* vbn1_g  = (const float*)d_in[23];
    const float* vbn1_b  = (const float*)d_in[24];
    const float* vbn1_m  = (const float*)d_in[25];
    const float* vbn1_v  = (const float*)d_in[26];
    const float* vn_W2   = (const float*)d_in[27];
    const float* vn_b2   = (const float*)d_in[28];
    const float* vbn2_g  = (const float*)d_in[29];
    const float* vbn2_b  = (const float*)d_in[30];
    const float* vbn2_m  = (const float*)d_in[31];
    const float* vbn2_v  = (const float*)d_in[32];

    float* h = (float*)d_out;
    char*  ws = (char*)d_ws;

    size_t off = 0;
    auto alloc = [&](size_t bytes) -> void* {
        void* p = ws + off;
        off += (bytes + 255) & ~(size_t)255;
        return p;
    };
    const size_t GDB = (size_t)GG * DD * sizeof(float);

    float* agg      = (float*)alloc((size_t)NP * DD * sizeof(float));
    unsigned short* h16 = (unsigned short*)alloc((size_t)NN * DD * sizeof(unsigned short));
    float* vn       = (float*)alloc(GDB);
    float* vt       = (float*)alloc(GDB);
    int*   rp       = (int*)  alloc((NN + 1) * sizeof(int));
    int*   fill     = (int*)  alloc(NN * sizeof(int));
    int*   partials = (int*)  alloc(128 * sizeof(int));
    int*   src_arr  = (int*)  alloc((size_t)EE * sizeof(int));
    unsigned short* w1h = (unsigned short*)alloc(LL * 32768 * sizeof(unsigned short));
    unsigned short* w1l = (unsigned short*)alloc(LL * 32768 * sizeof(unsigned short));
    unsigned short* w2h = (unsigned short*)alloc(LL * 32768 * sizeof(unsigned short));
    unsigned short* w2l = (unsigned short*)alloc(LL * 32768 * sizeof(unsigned short));
    float* bn1sc = (float*)alloc(LL * 2 * DD * sizeof(float));
    float* bn1sh = (float*)alloc(LL * 2 * DD * sizeof(float));
    float* bn2sc = (float*)alloc(LL * DD * sizeof(float));
    float* bn2sh = (float*)alloc(LL * DD * sizeof(float));
    const size_t base_end = off;

    unsigned short* attr16 = nullptr;
    int* eid_perm = nullptr;
    if (ws_size >= base_end + (size_t)EE * 8 * sizeof(unsigned short))
        attr16 = (unsigned short*)alloc((size_t)EE * 8 * sizeof(unsigned short));
    else if (ws_size >= base_end + (size_t)EE * sizeof(int))
        eid_perm = (int*)alloc((size_t)EE * sizeof(int));
    const bool csr = (attr16 != nullptr) || (eid_perm != nullptr);

    // K0: init h and vn
    {
        long total = (long)NN * DD;
        init_kernel<<<(int)((total + 255) / 256), 256, 0, stream>>>(
            x, node_emb, vn_emb, h, vn);
    }

    // Weight/BN prep (once)
    wprep_kernel<<<(LL * 2 * 32768 + 255) / 256, 256, 0, stream>>>(
        mlp_W1, mlp_W2, w1h, w1l, w2h, w2l);
    bnprep_kernel<<<(LL * 2 * DD + LL * DD + 255) / 256, 256, 0, stream>>>(
        mlp_b1, mbn_g, mbn_b, mbn_m, mbn_v,
        mlp_b2, bn_g, bn_b, bn_m, bn_v,
        bn1sc, bn1sh, bn2sc, bn2sh);

    // CSR build (once)
    if (csr) {
        const int egrid = (EE + 255) / 256;
        const int ngrid = (NN + 1023) / 1024;
        hipMemsetAsync(fill, 0, NN * sizeof(int), stream);
        count_kernel<<<egrid, 256, 0, stream>>>(ei, fill);
        scan_a<<<ngrid, 1024, 0, stream>>>(fill, rp, partials);
        scan_b<<<1, 64, 0, stream>>>(partials, ngrid);
        scan_c<<<ngrid, 1024, 0, stream>>>(rp, fill, partials);
        scatter_kernel<<<egrid, 256, 0, stream>>>(ei, eattr, fill, attr16, src_arr, eid_perm);
    }

    for (int l = 0; l < LL; ++l) {
        int accum = (l < LL - 1) ? 1 : 0;
        if (accum)
            hipMemsetAsync(vt, 0, GDB, stream);

        hin_kernel<<<NN / (R1 * 2), 256, 0, stream>>>(
            h, h16, vn, batch, eps, agg, vt, l, accum, csr ? 0 : 1);

        if (attr16) {
            gin_agg_kernel<<<NN / 4, 256, 0, stream>>>(
                h, h16, rp, attr16, src_arr, edge_W, edge_b, eps, agg, l);
        } else if (eid_perm) {
            gin_agg_eid_kernel<<<NN / 2, 256, 0, stream>>>(
                h, rp, eid_perm, ei, eattr, edge_W, edge_b, eps, agg, l);
        } else {
            edge_kernel<<<(EE + EPB - 1) / EPB, 256, 0, stream>>>(
                h, ei, eattr, edge_W, edge_b, agg, l);
        }

        mlp_mfma_kernel<<<NP / 64, 256, 0, stream>>>(
            agg, w1h, w1l, w2h, w2l, bn1sc, bn1sh, bn2sc, bn2sh,
            h, l, accum);

        if (accum)
            vn_kernel<<<GG, 256, 0, stream>>>(
                vt, vn, vn_W1, vn_b1, vbn1_g, vbn1_b, vbn1_m, vbn1_v,
                vn_W2, vn_b2, vbn2_g, vbn2_b, vbn2_m, vbn2_v, l);
    }
}

// Round 6
// 801.432 us; speedup vs baseline: 3.6187x; 1.0490x over previous
//
#include <hip/hip_runtime.h>
#include <hip/hip_bf16.h>

#define NN 100000
#define NP 100032              // NN rounded up to 64
#define EE 1600000
#define GG 128
#define DD 128
#define LL 3
#define EAA 7
#define BN_EPS 1e-5f

typedef __attribute__((ext_vector_type(8))) short bf16x8;
typedef __attribute__((ext_vector_type(4))) float f32x4;
typedef __attribute__((ext_vector_type(4))) unsigned short u16x4;

__device__ __forceinline__ unsigned short f2bf(float x) {
    unsigned int u = __float_as_uint(x);
    u = (u + 0x7FFF + ((u >> 16) & 1)) >> 16;
    return (unsigned short)u;
}
__device__ __forceinline__ float bf2f(unsigned short h) {
    return __uint_as_float(((unsigned int)h) << 16);
}
__device__ __forceinline__ float bflo(unsigned int u) {
    return __uint_as_float(u << 16);
}
__device__ __forceinline__ float bfhi(unsigned int u) {
    return __uint_as_float(u & 0xFFFF0000u);
}

// ---------------------------------------------------------------------------
// K0: h[i,:] = node_emb[x[i],:]; vn[g,:] = vn_emb[0,:]
// ---------------------------------------------------------------------------
__global__ __launch_bounds__(256) void init_kernel(
    const int* __restrict__ x, const float* __restrict__ node_emb,
    const float* __restrict__ vn_emb, float* __restrict__ h,
    float* __restrict__ vn)
{
    long i = (long)blockIdx.x * 256 + threadIdx.x;
    if (i < (long)NN * DD) {
        int node = (int)(i >> 7), d = (int)(i & 127);
        h[i] = node_emb[(long)x[node] * DD + d];
    }
    if (i < GG * DD) vn[i] = vn_emb[i & 127];
}

// ---------------------------------------------------------------------------
// K1: in-place h -> h_in = h + vn[batch]; bf16 shadow copy h16 for gathers;
// optional agg=(1+eps)h_in (atomic fallback); optional vt[g] += h_in rows.
// ---------------------------------------------------------------------------
#define R1 8
__global__ __launch_bounds__(256) void hin_kernel(
    float* __restrict__ hbuf,
    unsigned short* __restrict__ h16,
    const float* __restrict__ vn,
    const int* __restrict__ batch,
    const float* __restrict__ eps,
    float* __restrict__ agg,
    float* __restrict__ vt,
    int layer, int accum_vt, int write_agg)
{
    const int d  = threadIdx.x & 127;
    const int rg = threadIdx.x >> 7;
    const float epl = 1.0f + eps[layer];
    const long row0 = (long)blockIdx.x * (R1 * 2);

    float vacc = 0.0f;
    int   vb   = -1;
    #pragma unroll
    for (int r = 0; r < R1; ++r) {
        long row = row0 + rg + 2 * r;
        if (row >= NN) break;
        int b = batch[row];
        long idx = row * DD + d;
        float hv = hbuf[idx] + vn[(long)b * DD + d];
        hbuf[idx] = hv;
        h16[idx]  = f2bf(hv);
        if (write_agg) agg[idx] = epl * hv;
        if (accum_vt) {
            if (b != vb) {
                if (vb >= 0) atomicAdd(&vt[(long)vb * DD + d], vacc);
                vb = b; vacc = 0.0f;
            }
            vacc += hv;
        }
    }
    if (accum_vt && vb >= 0) atomicAdd(&vt[(long)vb * DD + d], vacc);
}

// ---------------------------------------------------------------------------
// CSR build: count -> scan -> scatter. Built once, reused by all 3 layers.
// ---------------------------------------------------------------------------
__global__ __launch_bounds__(256) void count_kernel(
    const int* __restrict__ ei, int* __restrict__ deg)
{
    long e = (long)blockIdx.x * 256 + threadIdx.x;
    if (e < EE) atomicAdd(&deg[ei[EE + e]], 1);
}

__global__ __launch_bounds__(1024) void scan_a(
    const int* __restrict__ deg, int* __restrict__ rp, int* __restrict__ partials)
{
    __shared__ int s[1024];
    int t = threadIdx.x;
    long i = (long)blockIdx.x * 1024 + t;
    int v = (i < NN) ? deg[i] : 0;
    s[t] = v;
    __syncthreads();
    for (int off = 1; off < 1024; off <<= 1) {
        int u = (t >= off) ? s[t - off] : 0;
        __syncthreads();
        s[t] += u;
        __syncthreads();
    }
    if (i < NN) rp[i] = s[t] - v;
    if (t == 1023) partials[blockIdx.x] = s[1023];
}

__global__ void scan_b(int* __restrict__ partials, int nb)
{
    if (threadIdx.x == 0) {
        int run = 0;
        for (int i = 0; i < nb; ++i) { int v = partials[i]; partials[i] = run; run += v; }
    }
}

__global__ __launch_bounds__(1024) void scan_c(
    int* __restrict__ rp, int* __restrict__ fill, const int* __restrict__ partials)
{
    long i = (long)blockIdx.x * 1024 + threadIdx.x;
    if (i < NN) {
        int v = rp[i] + partials[blockIdx.x];
        rp[i] = v;
        fill[i] = v;
    }
    if (i == 0) rp[NN] = EE;
}

// Tier-1: attr16 = 8 ushorts per edge (7 bf16 attrs + pad), src separate.
__global__ __launch_bounds__(256) void scatter_kernel(
    const int* __restrict__ ei, const float* __restrict__ eattr,
    int* __restrict__ fill, unsigned short* __restrict__ attr16,
    int* __restrict__ src_arr, int* __restrict__ eid_perm)
{
    long e = (long)blockIdx.x * 256 + threadIdx.x;
    if (e >= EE) return;
    int dst = ei[EE + e];
    int pos = atomicAdd(&fill[dst], 1);
    if (attr16) {
        u16x4 w0, w1;
        w0.x = f2bf(eattr[e * EAA + 0]);
        w0.y = f2bf(eattr[e * EAA + 1]);
        w0.z = f2bf(eattr[e * EAA + 2]);
        w0.w = f2bf(eattr[e * EAA + 3]);
        w1.x = f2bf(eattr[e * EAA + 4]);
        w1.y = f2bf(eattr[e * EAA + 5]);
        w1.z = f2bf(eattr[e * EAA + 6]);
        w1.w = 0;
        *(u16x4*)(attr16 + (long)pos * 8)     = w0;
        *(u16x4*)(attr16 + (long)pos * 8 + 4) = w1;
        src_arr[pos] = ei[e];
    } else {
        eid_perm[pos] = (int)e;
    }
}

// ---------------------------------------------------------------------------
// K2 (CSR, ILP): one wave per dst node; lane owns cols {2l, 2l+1}; x4 unroll.
// Gathers read the bf16 shadow h16 (4 B/lane); attrs read packed bf16 (16 B).
// ---------------------------------------------------------------------------
__global__ __launch_bounds__(256) void gin_agg_kernel(
    const float* __restrict__ h_in,
    const unsigned short* __restrict__ h16,
    const int* __restrict__ rp,
    const unsigned short* __restrict__ attr16,
    const int* __restrict__ src_arr,
    const float* __restrict__ eW, const float* __restrict__ eb,
    const float* __restrict__ eps,
    float* __restrict__ agg, int layer)
{
    const int lane = threadIdx.x & 63;
    const int wid  = threadIdx.x >> 6;
    const long n   = (long)blockIdx.x * 4 + wid;
    const int d0   = lane * 2;

    const float* eWl = eW + (long)layer * EAA * DD;
    float2 w2[EAA];
    #pragma unroll
    for (int a = 0; a < EAA; ++a)
        w2[a] = *(const float2*)&eWl[a * DD + d0];
    const float2 bias = *(const float2*)&eb[layer * DD + d0];
    const float  epl  = 1.0f + eps[layer];

    float2 hn = *(const float2*)&h_in[n * DD + d0];
    float accx = epl * hn.x, accy = epl * hn.y;

    int p  = rp[n];
    const int p1 = rp[n + 1];

    #define EDGE(AU, GU)                                                      \
    {                                                                         \
        float a0 = bflo(AU.x), a1 = bfhi(AU.x);                               \
        float a2 = bflo(AU.y), a3 = bfhi(AU.y);                               \
        float a4 = bflo(AU.z), a5 = bfhi(AU.z);                               \
        float a6 = bflo(AU.w);                                                \
        float ex = bias.x, ey = bias.y;                                       \
        ex = fmaf(a0, w2[0].x, ex); ey = fmaf(a0, w2[0].y, ey);               \
        ex = fmaf(a1, w2[1].x, ex); ey = fmaf(a1, w2[1].y, ey);               \
        ex = fmaf(a2, w2[2].x, ex); ey = fmaf(a2, w2[2].y, ey);               \
        ex = fmaf(a3, w2[3].x, ex); ey = fmaf(a3, w2[3].y, ey);               \
        ex = fmaf(a4, w2[4].x, ex); ey = fmaf(a4, w2[4].y, ey);               \
        ex = fmaf(a5, w2[5].x, ex); ey = fmaf(a5, w2[5].y, ey);               \
        ex = fmaf(a6, w2[6].x, ex); ey = fmaf(a6, w2[6].y, ey);               \
        float mx = bflo(GU) + ex, my = bfhi(GU) + ey;                         \
        accx += fmaxf(mx, 0.0f); accy += fmaxf(my, 0.0f);                     \
    }

    for (; p + 4 <= p1; p += 4) {
        int s0 = src_arr[p];
        int s1 = src_arr[p + 1];
        int s2 = src_arr[p + 2];
        int s3 = src_arr[p + 3];
        const uint4* a4p = (const uint4*)(attr16 + (long)p * 8);
        uint4 A0 = a4p[0];
        uint4 A1 = a4p[1];
        uint4 A2 = a4p[2];
        uint4 A3 = a4p[3];
        unsigned int g0 = *(const unsigned int*)(h16 + (long)s0 * DD + d0);
        unsigned int g1 = *(const unsigned int*)(h16 + (long)s1 * DD + d0);
        unsigned int g2 = *(const unsigned int*)(h16 + (long)s2 * DD + d0);
        unsigned int g3 = *(const unsigned int*)(h16 + (long)s3 * DD + d0);
        EDGE(A0, g0)
        EDGE(A1, g1)
        EDGE(A2, g2)
        EDGE(A3, g3)
    }
    for (; p < p1; ++p) {
        int s = src_arr[p];
        uint4 A = *(const uint4*)(attr16 + (long)p * 8);
        unsigned int g = *(const unsigned int*)(h16 + (long)s * DD + d0);
        EDGE(A, g)
    }
    #undef EDGE

    *(float2*)&agg[n * DD + d0] = make_float2(accx, accy);
}

// ---------------------------------------------------------------------------
// K2 fallback A (eid indirection)
// ---------------------------------------------------------------------------
__global__ __launch_bounds__(256) void gin_agg_eid_kernel(
    const float* __restrict__ h_in,
    const int* __restrict__ rp,
    const int* __restrict__ eid_perm,
    const int* __restrict__ ei,
    const float* __restrict__ eattr,
    const float* __restrict__ eW, const float* __restrict__ eb,
    const float* __restrict__ eps,
    float* __restrict__ agg, int layer)
{
    const int d    = threadIdx.x & 127;
    const int half = threadIdx.x >> 7;
    const long n   = (long)blockIdx.x * 2 + half;

    float w[EAA];
    #pragma unroll
    for (int a = 0; a < EAA; ++a) w[a] = eW[layer * EAA * DD + a * DD + d];
    const float bias = eb[layer * DD + d];
    const float epl  = 1.0f + eps[layer];

    float acc = epl * h_in[n * DD + d];
    const int p0 = rp[n], p1 = rp[n + 1];
    for (int p = p0; p < p1; ++p) {
        int e = eid_perm[p];
        int src = ei[e];
        float ea = bias;
        #pragma unroll
        for (int a = 0; a < EAA; ++a)
            ea = fmaf(eattr[(long)e * EAA + a], w[a], ea);
        float m = h_in[(long)src * DD + d] + ea;
        acc += m > 0.0f ? m : 0.0f;
    }
    agg[n * DD + d] = acc;
}

// ---------------------------------------------------------------------------
// K2 fallback B (atomic path)
// ---------------------------------------------------------------------------
#define EPB 64
__global__ __launch_bounds__(256) void edge_kernel(
    const float* __restrict__ h_in,
    const int* __restrict__ ei,
    const float* __restrict__ eattr,
    const float* __restrict__ eW,
    const float* __restrict__ eb,
    float* __restrict__ agg,
    int layer)
{
    const int d    = threadIdx.x & 127;
    const int esub = threadIdx.x >> 7;
    float w[EAA];
    #pragma unroll
    for (int a = 0; a < EAA; ++a) w[a] = eW[layer * EAA * DD + a * DD + d];
    const float bias = eb[layer * DD + d];

    const long base = (long)blockIdx.x * EPB;
    for (int k = esub; k < EPB; k += 2) {
        long e = base + k;
        if (e >= EE) break;
        int s = ei[e];
        int t = ei[EE + e];
        float acc = bias;
        #pragma unroll
        for (int a = 0; a < EAA; ++a)
            acc = fmaf(eattr[e * EAA + a], w[a], acc);
        float m = h_in[(long)s * DD + d] + acc;
        m = m > 0.0f ? m : 0.0f;
        atomicAdd(&agg[(long)t * DD + d], m);
    }
}

// ---------------------------------------------------------------------------
// Weight prep (OPERAND-SWAPPED): weights are the MFMA *A* operand now.
// A-frag layout (16x16x32): lane holds A[row=lane&15][k=(lane>>4)*8+b].
// W1^T: fi = ((kk*16 + mt)*64 + lane)*8 + b; m(row of A)=mt*16+(lane&15),
//       k = kk*32+(lane>>4)*8+b; value = W1[k][m].  (mt 0..15, kk 0..3)
// W2^T: fi = ((kk*8 + mt)*64 + lane)*8 + b; value = W2[k][m]. (mt 0..7, kk 0..7)
// ---------------------------------------------------------------------------
__global__ __launch_bounds__(256) void wprep_kernel(
    const float* __restrict__ W1, const float* __restrict__ W2,
    unsigned short* __restrict__ w1h, unsigned short* __restrict__ w1l,
    unsigned short* __restrict__ w2h, unsigned short* __restrict__ w2l)
{
    int tid = blockIdx.x * 256 + threadIdx.x;
    if (tid >= LL * 2 * 32768) return;
    int l = tid / 65536;
    int rem = tid - l * 65536;
    int mat = rem >> 15;
    int fi = rem & 32767;
    int b = fi & 7, lane = (fi >> 3) & 63;
    int kgrp = ((lane >> 4) << 3) + b;
    if (mat == 0) {
        int mt = (fi >> 9) & 15, kk = fi >> 13;       // mt 0..15, kk 0..3
        int m = (mt << 4) + (lane & 15);
        int k = (kk << 5) + kgrp;
        float v = W1[(long)l * DD * 2 * DD + (long)k * 2 * DD + m];
        unsigned short hi = f2bf(v);
        w1h[(long)l * 32768 + fi] = hi;
        w1l[(long)l * 32768 + fi] = f2bf(v - bf2f(hi));
    } else {
        int mt = (fi >> 9) & 7, kk = fi >> 12;        // mt 0..7, kk 0..7
        int m = (mt << 4) + (lane & 15);
        int k = (kk << 5) + kgrp;
        float v = W2[(long)l * 2 * DD * DD + (long)k * DD + m];
        unsigned short hi = f2bf(v);
        w2h[(long)l * 32768 + fi] = hi;
        w2l[(long)l * 32768 + fi] = f2bf(v - bf2f(hi));
    }
}

// ---------------------------------------------------------------------------
// BN prep: fold bias+BN into per-column scale/shift.
// ---------------------------------------------------------------------------
__global__ __launch_bounds__(256) void bnprep_kernel(
    const float* __restrict__ b1, const float* __restrict__ g1,
    const float* __restrict__ be1, const float* __restrict__ m1,
    const float* __restrict__ v1,
    const float* __restrict__ b2, const float* __restrict__ g2,
    const float* __restrict__ be2, const float* __restrict__ m2,
    const float* __restrict__ v2,
    float* __restrict__ sc1, float* __restrict__ sh1,
    float* __restrict__ sc2, float* __restrict__ sh2)
{
    int tid = blockIdx.x * 256 + threadIdx.x;
    if (tid < LL * 2 * DD) {
        float sc = g1[tid] / sqrtf(v1[tid] + BN_EPS);
        sc1[tid] = sc;
        sh1[tid] = (b1[tid] - m1[tid]) * sc + be1[tid];
    }
    int t2 = tid - LL * 2 * DD;
    if (t2 >= 0 && t2 < LL * DD) {
        float sc = g2[t2] / sqrtf(v2[t2] + BN_EPS);
        sc2[t2] = sc;
        sh2[t2] = (b2[t2] - m2[t2]) * sc + be2[t2];
    }
}

// ---------------------------------------------------------------------------
// K3 (MFMA, operand-swapped): weights = A operand, activations = B operand.
// D[m][n]: m = output column, n = node row. Epilogue per lane = 4 consecutive
// cols at a fixed row -> ds_write_b64 for u (hi/lo), float4 global for h.
// Split precision: X ~ Xh + Xl; X@Y ~ Xh@Yh + Xh@Yl + Xl@Yh.
// LDS: z-hi [64][128]bf16 @0, z-lo @16384; then u-hi [64][256]bf16 @0, u-lo
// @32768. All row-swizzled byte^=(row&7)<<4. B1 frags preloaded to regs
// before u overwrites z.
// ---------------------------------------------------------------------------
__global__ __launch_bounds__(256, 2) void mlp_mfma_kernel(
    const float* __restrict__ z_in,
    const unsigned short* __restrict__ w1h, const unsigned short* __restrict__ w1l,
    const unsigned short* __restrict__ w2h, const unsigned short* __restrict__ w2l,
    const float* __restrict__ sc1, const float* __restrict__ sh1,
    const float* __restrict__ sc2, const float* __restrict__ sh2,
    float* __restrict__ h_out, int layer, int do_relu)
{
    __shared__ char lds[65536];
    const int tid  = threadIdx.x;
    const int lane = tid & 63;
    const int wv   = tid >> 6;
    const long row0 = (long)blockIdx.x * 64;
    const int kb = (lane >> 4) << 3;

    // ---- stage z [64][128] fp32 -> hi/lo bf16 (z-hi at 0, z-lo at 16384) ----
    {
        const float4* zi = (const float4*)(z_in + row0 * DD);
        #pragma unroll
        for (int i = 0; i < 8; ++i) {
            int idx = tid + i * 256;
            float4 v = zi[idx];
            int r = idx >> 5;
            int c = (idx & 31) << 2;
            u16x4 hv, lv;
            hv.x = f2bf(v.x); lv.x = f2bf(v.x - bf2f(hv.x));
            hv.y = f2bf(v.y); lv.y = f2bf(v.y - bf2f(hv.y));
            hv.z = f2bf(v.z); lv.z = f2bf(v.z - bf2f(hv.z));
            hv.w = f2bf(v.w); lv.w = f2bf(v.w - bf2f(hv.w));
            int off = ((r << 8) + (c << 1)) ^ ((r & 7) << 4);
            *(u16x4*)(lds + off)         = hv;
            *(u16x4*)(lds + 16384 + off) = lv;
        }
    }
    __syncthreads();

    // ---- B1 frags (z^T): B[k][n], lane&15 = n (node row within tile) ----
    bf16x8 B1h[4][4], B1l[4][4];
    #pragma unroll
    for (int nt = 0; nt < 4; ++nt) {
        int r = (nt << 4) + (lane & 15);
        #pragma unroll
        for (int kk = 0; kk < 4; ++kk) {
            int off = ((r << 8) + (((kk << 5) + kb) << 1)) ^ ((r & 7) << 4);
            B1h[nt][kk] = *(const bf16x8*)(lds + off);
            B1l[nt][kk] = *(const bf16x8*)(lds + 16384 + off);
        }
    }
    __syncthreads();   // z reads done; LDS becomes u (hi at 0, lo at 32768)

    // ---- GEMM1 + BN1 + relu -> u in LDS (wave owns m-tiles wv*4..wv*4+3) ----
    const unsigned short* w1hl = w1h + (long)layer * 32768;
    const unsigned short* w1ll = w1l + (long)layer * 32768;
    #pragma unroll
    for (int mtl = 0; mtl < 4; ++mtl) {
        const int mt = (wv << 2) + mtl;
        bf16x8 Ah[4], Al[4];
        #pragma unroll
        for (int kk = 0; kk < 4; ++kk) {
            const long boff = ((long)((kk << 4) + mt) * 64 + lane) << 3;
            Ah[kk] = *(const bf16x8*)(w1hl + boff);
            Al[kk] = *(const bf16x8*)(w1ll + boff);
        }
        f32x4 acc[4];
        #pragma unroll
        for (int nt = 0; nt < 4; ++nt) acc[nt] = (f32x4){0.f, 0.f, 0.f, 0.f};
        #pragma unroll
        for (int kk = 0; kk < 4; ++kk) {
            #pragma unroll
            for (int nt = 0; nt < 4; ++nt) {
                acc[nt] = __builtin_amdgcn_mfma_f32_16x16x32_bf16(Ah[kk], B1h[nt][kk], acc[nt], 0, 0, 0);
                acc[nt] = __builtin_amdgcn_mfma_f32_16x16x32_bf16(Ah[kk], B1l[nt][kk], acc[nt], 0, 0, 0);
                acc[nt] = __builtin_amdgcn_mfma_f32_16x16x32_bf16(Al[kk], B1h[nt][kk], acc[nt], 0, 0, 0);
            }
        }
        const int m0 = (mt << 4) + ((lane >> 4) << 2);
        const float4 s4 = *(const float4*)&sc1[layer * 2 * DD + m0];
        const float4 t4 = *(const float4*)&sh1[layer * 2 * DD + m0];
        #pragma unroll
        for (int nt = 0; nt < 4; ++nt) {
            int row = (nt << 4) + (lane & 15);
            float u0 = fmaxf(fmaf(acc[nt][0], s4.x, t4.x), 0.0f);
            float u1 = fmaxf(fmaf(acc[nt][1], s4.y, t4.y), 0.0f);
            float u2 = fmaxf(fmaf(acc[nt][2], s4.z, t4.z), 0.0f);
            float u3 = fmaxf(fmaf(acc[nt][3], s4.w, t4.w), 0.0f);
            u16x4 hv, lv;
            hv.x = f2bf(u0); lv.x = f2bf(u0 - bf2f(hv.x));
            hv.y = f2bf(u1); lv.y = f2bf(u1 - bf2f(hv.y));
            hv.z = f2bf(u2); lv.z = f2bf(u2 - bf2f(hv.z));
            hv.w = f2bf(u3); lv.w = f2bf(u3 - bf2f(hv.w));
            int off = ((row << 9) + (m0 << 1)) ^ ((row & 7) << 4);
            *(u16x4*)(lds + off)         = hv;
            *(u16x4*)(lds + 32768 + off) = lv;
        }
    }
    __syncthreads();

    // ---- GEMM2 + BN2 (+relu) -> h (wave owns m-tiles wv*2, wv*2+1) ----
    const unsigned short* w2hl = w2h + (long)layer * 32768;
    const unsigned short* w2ll = w2l + (long)layer * 32768;
    f32x4 acc2[2][4];
    #pragma unroll
    for (int mtl = 0; mtl < 2; ++mtl)
        #pragma unroll
        for (int nt = 0; nt < 4; ++nt) acc2[mtl][nt] = (f32x4){0.f, 0.f, 0.f, 0.f};

    #pragma unroll
    for (int kk = 0; kk < 8; ++kk) {
        bf16x8 Bh[4], Bl[4];
        #pragma unroll
        for (int nt = 0; nt < 4; ++nt) {
            int r = (nt << 4) + (lane & 15);
            int off = ((r << 9) + (((kk << 5) + kb) << 1)) ^ ((r & 7) << 4);
            Bh[nt] = *(const bf16x8*)(lds + off);
            Bl[nt] = *(const bf16x8*)(lds + 32768 + off);
        }
        #pragma unroll
        for (int mtl = 0; mtl < 2; ++mtl) {
            const int mt = (wv << 1) + mtl;
            const long boff = ((long)((kk << 3) + mt) * 64 + lane) << 3;
            bf16x8 Ah = *(const bf16x8*)(w2hl + boff);
            bf16x8 Al = *(const bf16x8*)(w2ll + boff);
            #pragma unroll
            for (int nt = 0; nt < 4; ++nt) {
                acc2[mtl][nt] = __builtin_amdgcn_mfma_f32_16x16x32_bf16(Ah, Bh[nt], acc2[mtl][nt], 0, 0, 0);
                acc2[mtl][nt] = __builtin_amdgcn_mfma_f32_16x16x32_bf16(Ah, Bl[nt], acc2[mtl][nt], 0, 0, 0);
                acc2[mtl][nt] = __builtin_amdgcn_mfma_f32_16x16x32_bf16(Al, Bh[nt], acc2[mtl][nt], 0, 0, 0);
            }
        }
    }
    #pragma unroll
    for (int mtl = 0; mtl < 2; ++mtl) {
        const int m0 = ((((wv << 1) + mtl)) << 4) + ((lane >> 4) << 2);
        const float4 s4 = *(const float4*)&sc2[layer * DD + m0];
        const float4 t4 = *(const float4*)&sh2[layer * DD + m0];
        #pragma unroll
        for (int nt = 0; nt < 4; ++nt) {
            long row = row0 + (nt << 4) + (lane & 15);
            if (row < NN) {
                float4 o;
                o.x = fmaf(acc2[mtl][nt][0], s4.x, t4.x);
                o.y = fmaf(acc2[mtl][nt][1], s4.y, t4.y);
                o.z = fmaf(acc2[mtl][nt][2], s4.z, t4.z);
                o.w = fmaf(acc2[mtl][nt][3], s4.w, t4.w);
                if (do_relu) {
                    o.x = fmaxf(o.x, 0.0f); o.y = fmaxf(o.y, 0.0f);
                    o.z = fmaxf(o.z, 0.0f); o.w = fmaxf(o.w, 0.0f);
                }
                *(float4*)&h_out[row * DD + m0] = o;
            }
        }
    }
}

// ---------------------------------------------------------------------------
// K4: virtual-node MLP. One block per graph g.
// ---------------------------------------------------------------------------
__global__ __launch_bounds__(256) void vn_kernel(
    const float* __restrict__ vt, float* __restrict__ vn,
    const float* __restrict__ W1, const float* __restrict__ b1,
    const float* __restrict__ g1, const float* __restrict__ be1,
    const float* __restrict__ m1, const float* __restrict__ v1,
    const float* __restrict__ W2, const float* __restrict__ b2,
    const float* __restrict__ g2, const float* __restrict__ be2,
    const float* __restrict__ m2, const float* __restrict__ v2,
    int layer)
{
    __shared__ float row[DD];
    __shared__ float u[2 * DD];
    const int g = blockIdx.x;
    const int t = threadIdx.x;

    if (t < DD) row[t] = vt[(long)g * DD + t] + vn[(long)g * DD + t];
    __syncthreads();

    {
        const float* W = W1 + (long)layer * DD * 2 * DD;
        float acc = 0.0f;
        for (int k = 0; k < DD; ++k) acc = fmaf(row[k], W[k * 2 * DD + t], acc);
        const long o = (long)layer * 2 * DD + t;
        float sc = g1[o] / sqrtf(v1[o] + BN_EPS);
        float sh = be1[o] - m1[o] * sc;
        float val = (acc + b1[o]) * sc + sh;
        u[t] = val > 0.0f ? val : 0.0f;
    }
    __syncthreads();

    if (t < DD) {
        const float* W = W2 + (long)layer * 2 * DD * DD;
        float acc = 0.0f;
        for (int k = 0; k < 2 * DD; ++k) acc = fmaf(u[k], W[k * DD + t], acc);
        const long o = (long)layer * DD + t;
        float sc = g2[o] / sqrtf(v2[o] + BN_EPS);
        float sh = be2[o] - m2[o] * sc;
        float val = (acc + b2[o]) * sc + sh;
        vn[(long)g * DD + t] = val > 0.0f ? val : 0.0f;
    }
}

// ---------------------------------------------------------------------------
extern "C" void kernel_launch(void* const* d_in, const int* in_sizes, int n_in,
                              void* d_out, int out_size, void* d_ws, size_t ws_size,
                              hipStream_t stream)
{
    const int*   x       = (const int*)  d_in[0];
    const int*   ei      = (const int*)  d_in[1];
    const float* eattr   = (const float*)d_in[2];
    const int*   batch   = (const int*)  d_in[3];
    const float* node_emb= (const float*)d_in[4];
    const float* vn_emb  = (const float*)d_in[5];
    const float* edge_W  = (const float*)d_in[6];
    const float* edge_b  = (const float*)d_in[7];
    const float* eps     = (const float*)d_in[8];
    const float* mlp_W1  = (const float*)d_in[9];
    const float* mlp_b1  = (const float*)d_in[10];
    const float* mbn_g   = (const float*)d_in[11];
    const float* mbn_b   = (const float*)d_in[12];
    const float* mbn_m   = (const float*)d_in[13];
    const float* mbn_v   = (const float*)d_in[14];
    const float* mlp_W2  = (const float*)d_in[15];
    const float* mlp_b2  = (const float*)d_in[16];
    const float* bn_g    = (const float*)d_in[17];
    const float* bn_b    = (const float*)d_in[18];
    const float* bn_m    = (const float*)d_in[19];
    const float* bn_v    = (const float*)d_in[20];
    const float* vn_W1   = (const float*)d_in[21];
    const float* vn_b1   = (const float*)d_in[22];
    const float* vbn1_g  = (const float*)d_in[23];
    const float* vbn1_b  = (const float*)d_in[24];
    const float* vbn1_m  = (const float*)d_in[25];
    const float* vbn1_v  = (const float*)d_in[26];
    const float* vn_W2   = (const float*)d_in[27];
    const float* vn_b2   = (const float*)d_in[28];
    const float* vbn2_g  = (const float*)d_in[29];
    const float* vbn2_b  = (const float*)d_in[30];
    const float* vbn2_m  = (const float*)d_in[31];
    const float* vbn2_v  = (const float*)d_in[32];

    float* h = (float*)d_out;
    char*  ws = (char*)d_ws;

    size_t off = 0;
    auto alloc = [&](size_t bytes) -> void* {
        void* p = ws + off;
        off += (bytes + 255) & ~(size_t)255;
        return p;
    };
    const size_t GDB = (size_t)GG * DD * sizeof(float);

    float* agg      = (float*)alloc((size_t)NP * DD * sizeof(float));
    unsigned short* h16 = (unsigned short*)alloc((size_t)NN * DD * sizeof(unsigned short));
    float* vn       = (float*)alloc(GDB);
    float* vt       = (float*)alloc(GDB);
    int*   rp       = (int*)  alloc((NN + 1) * sizeof(int));
    int*   fill     = (int*)  alloc(NN * sizeof(int));
    int*   partials = (int*)  alloc(128 * sizeof(int));
    int*   src_arr  = (int*)  alloc((size_t)EE * sizeof(int));
    unsigned short* w1h = (unsigned short*)alloc(LL * 32768 * sizeof(unsigned short));
    unsigned short* w1l = (unsigned short*)alloc(LL * 32768 * sizeof(unsigned short));
    unsigned short* w2h = (unsigned short*)alloc(LL * 32768 * sizeof(unsigned short));
    unsigned short* w2l = (unsigned short*)alloc(LL * 32768 * sizeof(unsigned short));
    float* bn1sc = (float*)alloc(LL * 2 * DD * sizeof(float));
    float* bn1sh = (float*)alloc(LL * 2 * DD * sizeof(float));
    float* bn2sc = (float*)alloc(LL * DD * sizeof(float));
    float* bn2sh = (float*)alloc(LL * DD * sizeof(float));
    const size_t base_end = off;

    unsigned short* attr16 = nullptr;
    int* eid_perm = nullptr;
    if (ws_size >= base_end + (size_t)EE * 8 * sizeof(unsigned short))
        attr16 = (unsigned short*)alloc((size_t)EE * 8 * sizeof(unsigned short));
    else if (ws_size >= base_end + (size_t)EE * sizeof(int))
        eid_perm = (int*)alloc((size_t)EE * sizeof(int));
    const bool csr = (attr16 != nullptr) || (eid_perm != nullptr);

    // K0: init h and vn
    {
        long total = (long)NN * DD;
        init_kernel<<<(int)((total + 255) / 256), 256, 0, stream>>>(
            x, node_emb, vn_emb, h, vn);
    }

    // Weight/BN prep (once)
    wprep_kernel<<<(LL * 2 * 32768 + 255) / 256, 256, 0, stream>>>(
        mlp_W1, mlp_W2, w1h, w1l, w2h, w2l);
    bnprep_kernel<<<(LL * 2 * DD + LL * DD + 255) / 256, 256, 0, stream>>>(
        mlp_b1, mbn_g, mbn_b, mbn_m, mbn_v,
        mlp_b2, bn_g, bn_b, bn_m, bn_v,
        bn1sc, bn1sh, bn2sc, bn2sh);

    // CSR build (once)
    if (csr) {
        const int egrid = (EE + 255) / 256;
        const int ngrid = (NN + 1023) / 1024;
        hipMemsetAsync(fill, 0, NN * sizeof(int), stream);
        count_kernel<<<egrid, 256, 0, stream>>>(ei, fill);
        scan_a<<<ngrid, 1024, 0, stream>>>(fill, rp, partials);
        scan_b<<<1, 64, 0, stream>>>(partials, ngrid);
        scan_c<<<ngrid, 1024, 0, stream>>>(rp, fill, partials);
        scatter_kernel<<<egrid, 256, 0, stream>>>(ei, eattr, fill, attr16, src_arr, eid_perm);
    }

    for (int l = 0; l < LL; ++l) {
        int accum = (l < LL - 1) ? 1 : 0;
        if (accum)
            hipMemsetAsync(vt, 0, GDB, stream);

        hin_kernel<<<NN / (R1 * 2), 256, 0, stream>>>(
            h, h16, vn, batch, eps, agg, vt, l, accum, csr ? 0 : 1);

        if (attr16) {
            gin_agg_kernel<<<NN / 4, 256, 0, stream>>>(
                h, h16, rp, attr16, src_arr, edge_W, edge_b, eps, agg, l);
        } else if (eid_perm) {
            gin_agg_eid_kernel<<<NN / 2, 256, 0, stream>>>(
                h, rp, eid_perm, ei, eattr, edge_W, edge_b, eps, agg, l);
        } else {
            edge_kernel<<<(EE + EPB - 1) / EPB, 256, 0, stream>>>(
                h, ei, eattr, edge_W, edge_b, agg, l);
        }

        mlp_mfma_kernel<<<NP / 64, 256, 0, stream>>>(
            agg, w1h, w1l, w2h, w2l, bn1sc, bn1sh, bn2sc, bn2sh,
            h, l, accum);

        if (accum)
            vn_kernel<<<GG, 256, 0, stream>>>(
                vt, vn, vn_W1, vn_b1, vbn1_g, vbn1_b, vbn1_m, vbn1_v,
                vn_W2, vn_b2, vbn2_g, vbn2_b, vbn2_m, vbn2_v, l);
    }
}

// Round 7
// 766.949 us; speedup vs baseline: 3.7814x; 1.0450x over previous
//
#include <hip/hip_runtime.h>
#include <hip/hip_bf16.h>

#define NN 100000
#define NP 100032              // NN rounded up to 64
#define EE 1600000
#define GG 128
#define DD 128
#define LL 3
#define EAA 7
#define BN_EPS 1e-5f

typedef __attribute__((ext_vector_type(8))) short bf16x8;
typedef __attribute__((ext_vector_type(4))) float f32x4;
typedef __attribute__((ext_vector_type(4))) unsigned short u16x4;

__device__ __forceinline__ unsigned short f2bf(float x) {
    unsigned int u = __float_as_uint(x);
    u = (u + 0x7FFF + ((u >> 16) & 1)) >> 16;
    return (unsigned short)u;
}
__device__ __forceinline__ float bf2f(unsigned short h) {
    return __uint_as_float(((unsigned int)h) << 16);
}
__device__ __forceinline__ float bflo(unsigned int u) {
    return __uint_as_float(u << 16);
}
__device__ __forceinline__ float bfhi(unsigned int u) {
    return __uint_as_float(u & 0xFFFF0000u);
}

// ---------------------------------------------------------------------------
// Fallback-only K0: h[i,:] = node_emb[x[i],:]; vn[g,:] = vn_emb[0,:]
// ---------------------------------------------------------------------------
__global__ __launch_bounds__(256) void init_kernel(
    const int* __restrict__ x, const float* __restrict__ node_emb,
    const float* __restrict__ vn_emb, float* __restrict__ h,
    float* __restrict__ vn)
{
    long i = (long)blockIdx.x * 256 + threadIdx.x;
    if (i < (long)NN * DD) {
        int node = (int)(i >> 7), d = (int)(i & 127);
        h[i] = node_emb[(long)x[node] * DD + d];
    }
    if (i < GG * DD) vn[i] = vn_emb[i & 127];
}

// ---------------------------------------------------------------------------
// Fallback-only K1: in-place h -> h_in = h + vn[batch]; h16 shadow; agg; vt.
// ---------------------------------------------------------------------------
#define R1 8
__global__ __launch_bounds__(256) void hin_kernel(
    float* __restrict__ hbuf,
    unsigned short* __restrict__ h16,
    const float* __restrict__ vn,
    const int* __restrict__ batch,
    const float* __restrict__ eps,
    float* __restrict__ agg,
    float* __restrict__ vt,
    int layer, int accum_vt, int write_agg)
{
    const int d  = threadIdx.x & 127;
    const int rg = threadIdx.x >> 7;
    const float epl = 1.0f + eps[layer];
    const long row0 = (long)blockIdx.x * (R1 * 2);

    float vacc = 0.0f;
    int   vb   = -1;
    #pragma unroll
    for (int r = 0; r < R1; ++r) {
        long row = row0 + rg + 2 * r;
        if (row >= NN) break;
        int b = batch[row];
        long idx = row * DD + d;
        float hv = hbuf[idx] + vn[(long)b * DD + d];
        hbuf[idx] = hv;
        h16[idx]  = f2bf(hv);
        if (write_agg) agg[idx] = epl * hv;
        if (accum_vt) {
            if (b != vb) {
                if (vb >= 0) atomicAdd(&vt[(long)vb * DD + d], vacc);
                vb = b; vacc = 0.0f;
            }
            vacc += hv;
        }
    }
    if (accum_vt && vb >= 0) atomicAdd(&vt[(long)vb * DD + d], vacc);
}

// ---------------------------------------------------------------------------
// vt segment-sum only (reads h_in fp32), run-length fused atomics.
// ---------------------------------------------------------------------------
__global__ __launch_bounds__(256) void vt_kernel(
    const float* __restrict__ hbuf, const int* __restrict__ batch,
    float* __restrict__ vt)
{
    const int d  = threadIdx.x & 127;
    const int rg = threadIdx.x >> 7;
    const long row0 = (long)blockIdx.x * 16;
    float vacc = 0.0f;
    int   vb   = -1;
    #pragma unroll
    for (int r = 0; r < 8; ++r) {
        long row = row0 + rg + 2 * r;
        if (row >= NN) break;
        int b = batch[row];
        float hv = hbuf[row * DD + d];
        if (b != vb) {
            if (vb >= 0) atomicAdd(&vt[(long)vb * DD + d], vacc);
            vb = b; vacc = 0.0f;
        }
        vacc += hv;
    }
    if (vb >= 0) atomicAdd(&vt[(long)vb * DD + d], vacc);
}

// ---------------------------------------------------------------------------
// Per-graph node counts (batch sorted; run-length fused atomics).
// ---------------------------------------------------------------------------
__global__ __launch_bounds__(256) void cnt_kernel(
    const int* __restrict__ batch, int* __restrict__ cnt)
{
    const int tid = blockIdx.x * 256 + threadIdx.x;     // 64*256 = 16384 threads
    const int CH  = (NN + 16383) / 16384;               // 7
    long s = (long)tid * CH;
    long e = s + CH; if (e > NN) e = NN;
    int vb = -1, c = 0;
    for (long i = s; i < e; ++i) {
        int b = batch[i];
        if (b != vb) { if (vb >= 0) atomicAdd(&cnt[vb], c); vb = b; c = 0; }
        ++c;
    }
    if (vb >= 0) atomicAdd(&cnt[vb], c);
}

// ---------------------------------------------------------------------------
// CSR build: count -> scan -> scatter. Built once, reused by all 3 layers.
// ---------------------------------------------------------------------------
__global__ __launch_bounds__(256) void count_kernel(
    const int* __restrict__ ei, int* __restrict__ deg)
{
    long e = (long)blockIdx.x * 256 + threadIdx.x;
    if (e < EE) atomicAdd(&deg[ei[EE + e]], 1);
}

__global__ __launch_bounds__(1024) void scan_a(
    const int* __restrict__ deg, int* __restrict__ rp, int* __restrict__ partials)
{
    __shared__ int s[1024];
    int t = threadIdx.x;
    long i = (long)blockIdx.x * 1024 + t;
    int v = (i < NN) ? deg[i] : 0;
    s[t] = v;
    __syncthreads();
    for (int off = 1; off < 1024; off <<= 1) {
        int u = (t >= off) ? s[t - off] : 0;
        __syncthreads();
        s[t] += u;
        __syncthreads();
    }
    if (i < NN) rp[i] = s[t] - v;
    if (t == 1023) partials[blockIdx.x] = s[1023];
}

__global__ void scan_b(int* __restrict__ partials, int nb)
{
    if (threadIdx.x == 0) {
        int run = 0;
        for (int i = 0; i < nb; ++i) { int v = partials[i]; partials[i] = run; run += v; }
    }
}

__global__ __launch_bounds__(1024) void scan_c(
    int* __restrict__ rp, int* __restrict__ fill, const int* __restrict__ partials)
{
    long i = (long)blockIdx.x * 1024 + threadIdx.x;
    if (i < NN) {
        int v = rp[i] + partials[blockIdx.x];
        rp[i] = v;
        fill[i] = v;
    }
    if (i == 0) rp[NN] = EE;
}

// Tier-1: attr16 = 8 ushorts per edge (7 bf16 attrs + pad), src separate.
__global__ __launch_bounds__(256) void scatter_kernel(
    const int* __restrict__ ei, const float* __restrict__ eattr,
    int* __restrict__ fill, unsigned short* __restrict__ attr16,
    int* __restrict__ src_arr, int* __restrict__ eid_perm)
{
    long e = (long)blockIdx.x * 256 + threadIdx.x;
    if (e >= EE) return;
    int dst = ei[EE + e];
    int pos = atomicAdd(&fill[dst], 1);
    if (attr16) {
        u16x4 w0, w1;
        w0.x = f2bf(eattr[e * EAA + 0]);
        w0.y = f2bf(eattr[e * EAA + 1]);
        w0.z = f2bf(eattr[e * EAA + 2]);
        w0.w = f2bf(eattr[e * EAA + 3]);
        w1.x = f2bf(eattr[e * EAA + 4]);
        w1.y = f2bf(eattr[e * EAA + 5]);
        w1.z = f2bf(eattr[e * EAA + 6]);
        w1.w = 0;
        *(u16x4*)(attr16 + (long)pos * 8)     = w0;
        *(u16x4*)(attr16 + (long)pos * 8 + 4) = w1;
        src_arr[pos] = ei[e];
    } else {
        eid_perm[pos] = (int)e;
    }
}

// ---------------------------------------------------------------------------
// K2 layer-0 special: h_in(0) is ONE constant row c = node_emb[0]+vn_emb[0]
// (x==0, Embedding(1,D)). No gathers, no src loads — attrs only.
// ---------------------------------------------------------------------------
__global__ __launch_bounds__(256) void gin0_kernel(
    const float* __restrict__ node_emb,
    const float* __restrict__ vn_emb,
    const int* __restrict__ rp,
    const unsigned short* __restrict__ attr16,
    const float* __restrict__ eW, const float* __restrict__ eb,
    const float* __restrict__ eps,
    float* __restrict__ agg)
{
    const int lane = threadIdx.x & 63;
    const int wid  = threadIdx.x >> 6;
    const long n   = (long)blockIdx.x * 4 + wid;
    const int d0   = lane * 2;

    float2 w2[EAA];
    #pragma unroll
    for (int a = 0; a < EAA; ++a)
        w2[a] = *(const float2*)&eW[a * DD + d0];
    const float2 bias = *(const float2*)&eb[d0];
    const float  epl  = 1.0f + eps[0];

    const float cx = node_emb[d0]     + vn_emb[d0];
    const float cy = node_emb[d0 + 1] + vn_emb[d0 + 1];
    float accx = epl * cx, accy = epl * cy;

    int p  = rp[n];
    const int p1 = rp[n + 1];

    #define EDGE0(AU)                                                         \
    {                                                                         \
        float a0 = bflo(AU.x), a1 = bfhi(AU.x);                               \
        float a2 = bflo(AU.y), a3 = bfhi(AU.y);                               \
        float a4 = bflo(AU.z), a5 = bfhi(AU.z);                               \
        float a6 = bflo(AU.w);                                                \
        float ex = bias.x, ey = bias.y;                                       \
        ex = fmaf(a0, w2[0].x, ex); ey = fmaf(a0, w2[0].y, ey);               \
        ex = fmaf(a1, w2[1].x, ex); ey = fmaf(a1, w2[1].y, ey);               \
        ex = fmaf(a2, w2[2].x, ex); ey = fmaf(a2, w2[2].y, ey);               \
        ex = fmaf(a3, w2[3].x, ex); ey = fmaf(a3, w2[3].y, ey);               \
        ex = fmaf(a4, w2[4].x, ex); ey = fmaf(a4, w2[4].y, ey);               \
        ex = fmaf(a5, w2[5].x, ex); ey = fmaf(a5, w2[5].y, ey);               \
        ex = fmaf(a6, w2[6].x, ex); ey = fmaf(a6, w2[6].y, ey);               \
        float mx = cx + ex, my = cy + ey;                                     \
        accx += fmaxf(mx, 0.0f); accy += fmaxf(my, 0.0f);                     \
    }

    for (; p + 4 <= p1; p += 4) {
        const uint4* a4p = (const uint4*)(attr16 + (long)p * 8);
        uint4 A0 = a4p[0];
        uint4 A1 = a4p[1];
        uint4 A2 = a4p[2];
        uint4 A3 = a4p[3];
        EDGE0(A0)
        EDGE0(A1)
        EDGE0(A2)
        EDGE0(A3)
    }
    for (; p < p1; ++p) {
        uint4 A = *(const uint4*)(attr16 + (long)p * 8);
        EDGE0(A)
    }
    #undef EDGE0

    *(float2*)&agg[n * DD + d0] = make_float2(accx, accy);
}

// ---------------------------------------------------------------------------
// K2 (CSR, ILP): one wave per dst node; lane owns cols {2l, 2l+1}; x4 unroll.
// ---------------------------------------------------------------------------
__global__ __launch_bounds__(256) void gin_agg_kernel(
    const float* __restrict__ h_in,
    const unsigned short* __restrict__ h16,
    const int* __restrict__ rp,
    const unsigned short* __restrict__ attr16,
    const int* __restrict__ src_arr,
    const float* __restrict__ eW, const float* __restrict__ eb,
    const float* __restrict__ eps,
    float* __restrict__ agg, int layer)
{
    const int lane = threadIdx.x & 63;
    const int wid  = threadIdx.x >> 6;
    const long n   = (long)blockIdx.x * 4 + wid;
    const int d0   = lane * 2;

    const float* eWl = eW + (long)layer * EAA * DD;
    float2 w2[EAA];
    #pragma unroll
    for (int a = 0; a < EAA; ++a)
        w2[a] = *(const float2*)&eWl[a * DD + d0];
    const float2 bias = *(const float2*)&eb[layer * DD + d0];
    const float  epl  = 1.0f + eps[layer];

    float2 hn = *(const float2*)&h_in[n * DD + d0];
    float accx = epl * hn.x, accy = epl * hn.y;

    int p  = rp[n];
    const int p1 = rp[n + 1];

    #define EDGE(AU, GU)                                                      \
    {                                                                         \
        float a0 = bflo(AU.x), a1 = bfhi(AU.x);                               \
        float a2 = bflo(AU.y), a3 = bfhi(AU.y);                               \
        float a4 = bflo(AU.z), a5 = bfhi(AU.z);                               \
        float a6 = bflo(AU.w);                                                \
        float ex = bias.x, ey = bias.y;                                       \
        ex = fmaf(a0, w2[0].x, ex); ey = fmaf(a0, w2[0].y, ey);               \
        ex = fmaf(a1, w2[1].x, ex); ey = fmaf(a1, w2[1].y, ey);               \
        ex = fmaf(a2, w2[2].x, ex); ey = fmaf(a2, w2[2].y, ey);               \
        ex = fmaf(a3, w2[3].x, ex); ey = fmaf(a3, w2[3].y, ey);               \
        ex = fmaf(a4, w2[4].x, ex); ey = fmaf(a4, w2[4].y, ey);               \
        ex = fmaf(a5, w2[5].x, ex); ey = fmaf(a5, w2[5].y, ey);               \
        ex = fmaf(a6, w2[6].x, ex); ey = fmaf(a6, w2[6].y, ey);               \
        float mx = bflo(GU) + ex, my = bfhi(GU) + ey;                         \
        accx += fmaxf(mx, 0.0f); accy += fmaxf(my, 0.0f);                     \
    }

    for (; p + 4 <= p1; p += 4) {
        int s0 = src_arr[p];
        int s1 = src_arr[p + 1];
        int s2 = src_arr[p + 2];
        int s3 = src_arr[p + 3];
        const uint4* a4p = (const uint4*)(attr16 + (long)p * 8);
        uint4 A0 = a4p[0];
        uint4 A1 = a4p[1];
        uint4 A2 = a4p[2];
        uint4 A3 = a4p[3];
        unsigned int g0 = *(const unsigned int*)(h16 + (long)s0 * DD + d0);
        unsigned int g1 = *(const unsigned int*)(h16 + (long)s1 * DD + d0);
        unsigned int g2 = *(const unsigned int*)(h16 + (long)s2 * DD + d0);
        unsigned int g3 = *(const unsigned int*)(h16 + (long)s3 * DD + d0);
        EDGE(A0, g0)
        EDGE(A1, g1)
        EDGE(A2, g2)
        EDGE(A3, g3)
    }
    for (; p < p1; ++p) {
        int s = src_arr[p];
        uint4 A = *(const uint4*)(attr16 + (long)p * 8);
        unsigned int g = *(const unsigned int*)(h16 + (long)s * DD + d0);
        EDGE(A, g)
    }
    #undef EDGE

    *(float2*)&agg[n * DD + d0] = make_float2(accx, accy);
}

// ---------------------------------------------------------------------------
// K2 fallback A (eid indirection)
// ---------------------------------------------------------------------------
__global__ __launch_bounds__(256) void gin_agg_eid_kernel(
    const float* __restrict__ h_in,
    const int* __restrict__ rp,
    const int* __restrict__ eid_perm,
    const int* __restrict__ ei,
    const float* __restrict__ eattr,
    const float* __restrict__ eW, const float* __restrict__ eb,
    const float* __restrict__ eps,
    float* __restrict__ agg, int layer)
{
    const int d    = threadIdx.x & 127;
    const int half = threadIdx.x >> 7;
    const long n   = (long)blockIdx.x * 2 + half;

    float w[EAA];
    #pragma unroll
    for (int a = 0; a < EAA; ++a) w[a] = eW[layer * EAA * DD + a * DD + d];
    const float bias = eb[layer * DD + d];
    const float epl  = 1.0f + eps[layer];

    float acc = epl * h_in[n * DD + d];
    const int p0 = rp[n], p1 = rp[n + 1];
    for (int p = p0; p < p1; ++p) {
        int e = eid_perm[p];
        int src = ei[e];
        float ea = bias;
        #pragma unroll
        for (int a = 0; a < EAA; ++a)
            ea = fmaf(eattr[(long)e * EAA + a], w[a], ea);
        float m = h_in[(long)src * DD + d] + ea;
        acc += m > 0.0f ? m : 0.0f;
    }
    agg[n * DD + d] = acc;
}

// ---------------------------------------------------------------------------
// K2 fallback B (atomic path)
// ---------------------------------------------------------------------------
#define EPB 64
__global__ __launch_bounds__(256) void edge_kernel(
    const float* __restrict__ h_in,
    const int* __restrict__ ei,
    const float* __restrict__ eattr,
    const float* __restrict__ eW,
    const float* __restrict__ eb,
    float* __restrict__ agg,
    int layer)
{
    const int d    = threadIdx.x & 127;
    const int esub = threadIdx.x >> 7;
    float w[EAA];
    #pragma unroll
    for (int a = 0; a < EAA; ++a) w[a] = eW[layer * EAA * DD + a * DD + d];
    const float bias = eb[layer * DD + d];

    const long base = (long)blockIdx.x * EPB;
    for (int k = esub; k < EPB; k += 2) {
        long e = base + k;
        if (e >= EE) break;
        int s = ei[e];
        int t = ei[EE + e];
        float acc = bias;
        #pragma unroll
        for (int a = 0; a < EAA; ++a)
            acc = fmaf(eattr[e * EAA + a], w[a], acc);
        float m = h_in[(long)s * DD + d] + acc;
        m = m > 0.0f ? m : 0.0f;
        atomicAdd(&agg[(long)t * DD + d], m);
    }
}

// ---------------------------------------------------------------------------
// Weight prep (operand-swapped; weights are the MFMA A operand). See R5 notes.
// ---------------------------------------------------------------------------
__global__ __launch_bounds__(256) void wprep_kernel(
    const float* __restrict__ W1, const float* __restrict__ W2,
    unsigned short* __restrict__ w1h, unsigned short* __restrict__ w1l,
    unsigned short* __restrict__ w2h, unsigned short* __restrict__ w2l)
{
    int tid = blockIdx.x * 256 + threadIdx.x;
    if (tid >= LL * 2 * 32768) return;
    int l = tid / 65536;
    int rem = tid - l * 65536;
    int mat = rem >> 15;
    int fi = rem & 32767;
    int b = fi & 7, lane = (fi >> 3) & 63;
    int kgrp = ((lane >> 4) << 3) + b;
    if (mat == 0) {
        int mt = (fi >> 9) & 15, kk = fi >> 13;
        int m = (mt << 4) + (lane & 15);
        int k = (kk << 5) + kgrp;
        float v = W1[(long)l * DD * 2 * DD + (long)k * 2 * DD + m];
        unsigned short hi = f2bf(v);
        w1h[(long)l * 32768 + fi] = hi;
        w1l[(long)l * 32768 + fi] = f2bf(v - bf2f(hi));
    } else {
        int mt = (fi >> 9) & 7, kk = fi >> 12;
        int m = (mt << 4) + (lane & 15);
        int k = (kk << 5) + kgrp;
        float v = W2[(long)l * 2 * DD * DD + (long)k * DD + m];
        unsigned short hi = f2bf(v);
        w2h[(long)l * 32768 + fi] = hi;
        w2l[(long)l * 32768 + fi] = f2bf(v - bf2f(hi));
    }
}

// ---------------------------------------------------------------------------
// BN prep: fold bias+BN into per-column scale/shift.
// ---------------------------------------------------------------------------
__global__ __launch_bounds__(256) void bnprep_kernel(
    const float* __restrict__ b1, const float* __restrict__ g1,
    const float* __restrict__ be1, const float* __restrict__ m1,
    const float* __restrict__ v1,
    const float* __restrict__ b2, const float* __restrict__ g2,
    const float* __restrict__ be2, const float* __restrict__ m2,
    const float* __restrict__ v2,
    float* __restrict__ sc1, float* __restrict__ sh1,
    float* __restrict__ sc2, float* __restrict__ sh2)
{
    int tid = blockIdx.x * 256 + threadIdx.x;
    if (tid < LL * 2 * DD) {
        float sc = g1[tid] / sqrtf(v1[tid] + BN_EPS);
        sc1[tid] = sc;
        sh1[tid] = (b1[tid] - m1[tid]) * sc + be1[tid];
    }
    int t2 = tid - LL * 2 * DD;
    if (t2 >= 0 && t2 < LL * DD) {
        float sc = g2[t2] / sqrtf(v2[t2] + BN_EPS);
        sc2[t2] = sc;
        sh2[t2] = (b2[t2] - m2[t2]) * sc + be2[t2];
    }
}

// ---------------------------------------------------------------------------
// K3 (MFMA, operand-swapped) with FUSED h_in epilogue:
// fuse=1: out = relu(bn2(h2)) + vn[batch[row]]; write d_out fp32 + h16 bf16.
// fuse=0: out = bn2(h2) (final layer), write d_out only.
// ---------------------------------------------------------------------------
__global__ __launch_bounds__(256, 2) void mlp_mfma_kernel(
    const float* __restrict__ z_in,
    const unsigned short* __restrict__ w1h, const unsigned short* __restrict__ w1l,
    const unsigned short* __restrict__ w2h, const unsigned short* __restrict__ w2l,
    const float* __restrict__ sc1, const float* __restrict__ sh1,
    const float* __restrict__ sc2, const float* __restrict__ sh2,
    float* __restrict__ h_out, int layer, int do_relu,
    const int* __restrict__ batch, const float* __restrict__ vnbuf,
    unsigned short* __restrict__ h16, int fuse)
{
    __shared__ char lds[65536];
    const int tid  = threadIdx.x;
    const int lane = tid & 63;
    const int wv   = tid >> 6;
    const long row0 = (long)blockIdx.x * 64;
    const int kb = (lane >> 4) << 3;

    // ---- stage z [64][128] fp32 -> hi/lo bf16 (z-hi at 0, z-lo at 16384) ----
    {
        const float4* zi = (const float4*)(z_in + row0 * DD);
        #pragma unroll
        for (int i = 0; i < 8; ++i) {
            int idx = tid + i * 256;
            float4 v = zi[idx];
            int r = idx >> 5;
            int c = (idx & 31) << 2;
            u16x4 hv, lv;
            hv.x = f2bf(v.x); lv.x = f2bf(v.x - bf2f(hv.x));
            hv.y = f2bf(v.y); lv.y = f2bf(v.y - bf2f(hv.y));
            hv.z = f2bf(v.z); lv.z = f2bf(v.z - bf2f(hv.z));
            hv.w = f2bf(v.w); lv.w = f2bf(v.w - bf2f(hv.w));
            int off = ((r << 8) + (c << 1)) ^ ((r & 7) << 4);
            *(u16x4*)(lds + off)         = hv;
            *(u16x4*)(lds + 16384 + off) = lv;
        }
    }
    __syncthreads();

    // ---- B1 frags (z^T): B[k][n], lane&15 = n (node row within tile) ----
    bf16x8 B1h[4][4], B1l[4][4];
    #pragma unroll
    for (int nt = 0; nt < 4; ++nt) {
        int r = (nt << 4) + (lane & 15);
        #pragma unroll
        for (int kk = 0; kk < 4; ++kk) {
            int off = ((r << 8) + (((kk << 5) + kb) << 1)) ^ ((r & 7) << 4);
            B1h[nt][kk] = *(const bf16x8*)(lds + off);
            B1l[nt][kk] = *(const bf16x8*)(lds + 16384 + off);
        }
    }
    __syncthreads();   // z reads done; LDS becomes u (hi at 0, lo at 32768)

    // ---- GEMM1 + BN1 + relu -> u in LDS (wave owns m-tiles wv*4..wv*4+3) ----
    const unsigned short* w1hl = w1h + (long)layer * 32768;
    const unsigned short* w1ll = w1l + (long)layer * 32768;
    #pragma unroll
    for (int mtl = 0; mtl < 4; ++mtl) {
        const int mt = (wv << 2) + mtl;
        bf16x8 Ah[4], Al[4];
        #pragma unroll
        for (int kk = 0; kk < 4; ++kk) {
            const long boff = ((long)((kk << 4) + mt) * 64 + lane) << 3;
            Ah[kk] = *(const bf16x8*)(w1hl + boff);
            Al[kk] = *(const bf16x8*)(w1ll + boff);
        }
        f32x4 acc[4];
        #pragma unroll
        for (int nt = 0; nt < 4; ++nt) acc[nt] = (f32x4){0.f, 0.f, 0.f, 0.f};
        #pragma unroll
        for (int kk = 0; kk < 4; ++kk) {
            #pragma unroll
            for (int nt = 0; nt < 4; ++nt) {
                acc[nt] = __builtin_amdgcn_mfma_f32_16x16x32_bf16(Ah[kk], B1h[nt][kk], acc[nt], 0, 0, 0);
                acc[nt] = __builtin_amdgcn_mfma_f32_16x16x32_bf16(Ah[kk], B1l[nt][kk], acc[nt], 0, 0, 0);
                acc[nt] = __builtin_amdgcn_mfma_f32_16x16x32_bf16(Al[kk], B1h[nt][kk], acc[nt], 0, 0, 0);
            }
        }
        const int m0 = (mt << 4) + ((lane >> 4) << 2);
        const float4 s4 = *(const float4*)&sc1[layer * 2 * DD + m0];
        const float4 t4 = *(const float4*)&sh1[layer * 2 * DD + m0];
        #pragma unroll
        for (int nt = 0; nt < 4; ++nt) {
            int row = (nt << 4) + (lane & 15);
            float u0 = fmaxf(fmaf(acc[nt][0], s4.x, t4.x), 0.0f);
            float u1 = fmaxf(fmaf(acc[nt][1], s4.y, t4.y), 0.0f);
            float u2 = fmaxf(fmaf(acc[nt][2], s4.z, t4.z), 0.0f);
            float u3 = fmaxf(fmaf(acc[nt][3], s4.w, t4.w), 0.0f);
            u16x4 hv, lv;
            hv.x = f2bf(u0); lv.x = f2bf(u0 - bf2f(hv.x));
            hv.y = f2bf(u1); lv.y = f2bf(u1 - bf2f(hv.y));
            hv.z = f2bf(u2); lv.z = f2bf(u2 - bf2f(hv.z));
            hv.w = f2bf(u3); lv.w = f2bf(u3 - bf2f(hv.w));
            int off = ((row << 9) + (m0 << 1)) ^ ((row & 7) << 4);
            *(u16x4*)(lds + off)         = hv;
            *(u16x4*)(lds + 32768 + off) = lv;
        }
    }
    __syncthreads();

    // ---- GEMM2 + BN2 (+relu/+vn) -> h (wave owns m-tiles wv*2, wv*2+1) ----
    const unsigned short* w2hl = w2h + (long)layer * 32768;
    const unsigned short* w2ll = w2l + (long)layer * 32768;
    f32x4 acc2[2][4];
    #pragma unroll
    for (int mtl = 0; mtl < 2; ++mtl)
        #pragma unroll
        for (int nt = 0; nt < 4; ++nt) acc2[mtl][nt] = (f32x4){0.f, 0.f, 0.f, 0.f};

    #pragma unroll
    for (int kk = 0; kk < 8; ++kk) {
        bf16x8 Bh[4], Bl[4];
        #pragma unroll
        for (int nt = 0; nt < 4; ++nt) {
            int r = (nt << 4) + (lane & 15);
            int off = ((r << 9) + (((kk << 5) + kb) << 1)) ^ ((r & 7) << 4);
            Bh[nt] = *(const bf16x8*)(lds + off);
            Bl[nt] = *(const bf16x8*)(lds + 32768 + off);
        }
        #pragma unroll
        for (int mtl = 0; mtl < 2; ++mtl) {
            const int mt = (wv << 1) + mtl;
            const long boff = ((long)((kk << 3) + mt) * 64 + lane) << 3;
            bf16x8 Ah = *(const bf16x8*)(w2hl + boff);
            bf16x8 Al = *(const bf16x8*)(w2ll + boff);
            #pragma unroll
            for (int nt = 0; nt < 4; ++nt) {
                acc2[mtl][nt] = __builtin_amdgcn_mfma_f32_16x16x32_bf16(Ah, Bh[nt], acc2[mtl][nt], 0, 0, 0);
                acc2[mtl][nt] = __builtin_amdgcn_mfma_f32_16x16x32_bf16(Ah, Bl[nt], acc2[mtl][nt], 0, 0, 0);
                acc2[mtl][nt] = __builtin_amdgcn_mfma_f32_16x16x32_bf16(Al, Bh[nt], acc2[mtl][nt], 0, 0, 0);
            }
        }
    }
    #pragma unroll
    for (int mtl = 0; mtl < 2; ++mtl) {
        const int m0 = ((((wv << 1) + mtl)) << 4) + ((lane >> 4) << 2);
        const float4 s4 = *(const float4*)&sc2[layer * DD + m0];
        const float4 t4 = *(const float4*)&sh2[layer * DD + m0];
        #pragma unroll
        for (int nt = 0; nt < 4; ++nt) {
            long row = row0 + (nt << 4) + (lane & 15);
            if (row < NN) {
                float o0 = fmaf(acc2[mtl][nt][0], s4.x, t4.x);
                float o1 = fmaf(acc2[mtl][nt][1], s4.y, t4.y);
                float o2 = fmaf(acc2[mtl][nt][2], s4.z, t4.z);
                float o3 = fmaf(acc2[mtl][nt][3], s4.w, t4.w);
                if (do_relu) {
                    o0 = fmaxf(o0, 0.0f); o1 = fmaxf(o1, 0.0f);
                    o2 = fmaxf(o2, 0.0f); o3 = fmaxf(o3, 0.0f);
                }
                if (fuse) {
                    int b = batch[row];
                    float4 vnv = *(const float4*)&vnbuf[(long)b * DD + m0];
                    o0 += vnv.x; o1 += vnv.y; o2 += vnv.z; o3 += vnv.w;
                    u16x4 hv;
                    hv.x = f2bf(o0); hv.y = f2bf(o1);
                    hv.z = f2bf(o2); hv.w = f2bf(o3);
                    *(u16x4*)&h16[row * DD + m0] = hv;
                }
                *(float4*)&h_out[row * DD + m0] = make_float4(o0, o1, o2, o3);
            }
        }
    }
}

// ---------------------------------------------------------------------------
// K4: virtual-node MLP. One block per graph g. row = vt[g] + vn[g].
// ---------------------------------------------------------------------------
__global__ __launch_bounds__(256) void vn_kernel(
    const float* __restrict__ vt, float* __restrict__ vn,
    const float* __restrict__ W1, const float* __restrict__ b1,
    const float* __restrict__ g1, const float* __restrict__ be1,
    const float* __restrict__ m1, const float* __restrict__ v1,
    const float* __restrict__ W2, const float* __restrict__ b2,
    const float* __restrict__ g2, const float* __restrict__ be2,
    const float* __restrict__ m2, const float* __restrict__ v2,
    int layer)
{
    __shared__ float row[DD];
    __shared__ float u[2 * DD];
    const int g = blockIdx.x;
    const int t = threadIdx.x;

    if (t < DD) row[t] = vt[(long)g * DD + t] + vn[(long)g * DD + t];
    __syncthreads();

    {
        const float* W = W1 + (long)layer * DD * 2 * DD;
        float acc = 0.0f;
        for (int k = 0; k < DD; ++k) acc = fmaf(row[k], W[k * 2 * DD + t], acc);
        const long o = (long)layer * 2 * DD + t;
        float sc = g1[o] / sqrtf(v1[o] + BN_EPS);
        float sh = be1[o] - m1[o] * sc;
        float val = (acc + b1[o]) * sc + sh;
        u[t] = val > 0.0f ? val : 0.0f;
    }
    __syncthreads();

    if (t < DD) {
        const float* W = W2 + (long)layer * 2 * DD * DD;
        float acc = 0.0f;
        for (int k = 0; k < 2 * DD; ++k) acc = fmaf(u[k], W[k * DD + t], acc);
        const long o = (long)layer * DD + t;
        float sc = g2[o] / sqrtf(v2[o] + BN_EPS);
        float sh = be2[o] - m2[o] * sc;
        float val = (acc + b2[o]) * sc + sh;
        vn[(long)g * DD + t] = val > 0.0f ? val : 0.0f;
    }
}

// ---------------------------------------------------------------------------
// K4 layer-0 special: vt(0)+vn(0) = cnt[g]*(node_emb+vn_emb) + vn_emb.
// Writes vn <- vn(1). Uses layer-0 VN weights.
// ---------------------------------------------------------------------------
__global__ __launch_bounds__(256) void vn0_kernel(
    const int* __restrict__ cnt,
    const float* __restrict__ node_emb, const float* __restrict__ vn_emb,
    float* __restrict__ vn,
    const float* __restrict__ W1, const float* __restrict__ b1,
    const float* __restrict__ g1, const float* __restrict__ be1,
    const float* __restrict__ m1, const float* __restrict__ v1,
    const float* __restrict__ W2, const float* __restrict__ b2,
    const float* __restrict__ g2, const float* __restrict__ be2,
    const float* __restrict__ m2, const float* __restrict__ v2)
{
    __shared__ float row[DD];
    __shared__ float u[2 * DD];
    const int g = blockIdx.x;
    const int t = threadIdx.x;

    if (t < DD) {
        float c = node_emb[t] + vn_emb[t];
        row[t] = (float)cnt[g] * c + vn_emb[t];
    }
    __syncthreads();

    {
        float acc = 0.0f;
        for (int k = 0; k < DD; ++k) acc = fmaf(row[k], W1[k * 2 * DD + t], acc);
        float sc = g1[t] / sqrtf(v1[t] + BN_EPS);
        float sh = be1[t] - m1[t] * sc;
        float val = (acc + b1[t]) * sc + sh;
        u[t] = val > 0.0f ? val : 0.0f;
    }
    __syncthreads();

    if (t < DD) {
        float acc = 0.0f;
        for (int k = 0; k < 2 * DD; ++k) acc = fmaf(u[k], W2[k * DD + t], acc);
        float sc = g2[t] / sqrtf(v2[t] + BN_EPS);
        float sh = be2[t] - m2[t] * sc;
        float val = (acc + b2[t]) * sc + sh;
        vn[(long)g * DD + t] = val > 0.0f ? val : 0.0f;
    }
}

// ---------------------------------------------------------------------------
extern "C" void kernel_launch(void* const* d_in, const int* in_sizes, int n_in,
                              void* d_out, int out_size, void* d_ws, size_t ws_size,
                              hipStream_t stream)
{
    const int*   x       = (const int*)  d_in[0];
    const int*   ei      = (const int*)  d_in[1];
    const float* eattr   = (const float*)d_in[2];
    const int*   batch   = (const int*)  d_in[3];
    const float* node_emb= (const float*)d_in[4];
    const float* vn_emb  = (const float*)d_in[5];
    const float* edge_W  = (const float*)d_in[6];
    const float* edge_b  = (const float*)d_in[7];
    const float* eps     = (const float*)d_in[8];
    const float* mlp_W1  = (const float*)d_in[9];
    const float* mlp_b1  = (const float*)d_in[10];
    const float* mbn_g   = (const float*)d_in[11];
    const float* mbn_b   = (const float*)d_in[12];
    const float* mbn_m   = (const float*)d_in[13];
    const float* mbn_v   = (const float*)d_in[14];
    const float* mlp_W2  = (const float*)d_in[15];
    const float* mlp_b2  = (const float*)d_in[16];
    const float* bn_g    = (const float*)d_in[17];
    const float* bn_b    = (const float*)d_in[18];
    const float* bn_m    = (const float*)d_in[19];
    const float* bn_v    = (const float*)d_in[20];
    const float* vn_W1   = (const float*)d_in[21];
    const float* vn_b1   = (const float*)d_in[22];
    const float* vbn1_g  = (const float*)d_in[23];
    const float* vbn1_b  = (const float*)d_in[24];
    const float* vbn1_m  = (const float*)d_in[25];
    const float* vbn1_v  = (const float*)d_in[26];
    const float* vn_W2   = (const float*)d_in[27];
    const float* vn_b2   = (const float*)d_in[28];
    const float* vbn2_g  = (const float*)d_in[29];
    const float* vbn2_b  = (const float*)d_in[30];
    const float* vbn2_m  = (const float*)d_in[31];
    const float* vbn2_v  = (const float*)d_in[32];

    float* h = (float*)d_out;
    char*  ws = (char*)d_ws;

    size_t off = 0;
    auto alloc = [&](size_t bytes) -> void* {
        void* p = ws + off;
        off += (bytes + 255) & ~(size_t)255;
        return p;
    };
    const size_t GDB = (size_t)GG * DD * sizeof(float);

    float* agg      = (float*)alloc((size_t)NP * DD * sizeof(float));
    unsigned short* h16 = (unsigned short*)alloc((size_t)NN * DD * sizeof(unsigned short));
    float* vn       = (float*)alloc(GDB);
    float* vt       = (float*)alloc(GDB);
    int*   rp       = (int*)  alloc((NN + 1) * sizeof(int));
    int*   fill     = (int*)  alloc(NN * sizeof(int));
    int*   partials = (int*)  alloc(128 * sizeof(int));
    int*   cnt      = (int*)  alloc(GG * sizeof(int));
    int*   src_arr  = (int*)  alloc((size_t)EE * sizeof(int));
    unsigned short* w1h = (unsigned short*)alloc(LL * 32768 * sizeof(unsigned short));
    unsigned short* w1l = (unsigned short*)alloc(LL * 32768 * sizeof(unsigned short));
    unsigned short* w2h = (unsigned short*)alloc(LL * 32768 * sizeof(unsigned short));
    unsigned short* w2l = (unsigned short*)alloc(LL * 32768 * sizeof(unsigned short));
    float* bn1sc = (float*)alloc(LL * 2 * DD * sizeof(float));
    float* bn1sh = (float*)alloc(LL * 2 * DD * sizeof(float));
    float* bn2sc = (float*)alloc(LL * DD * sizeof(float));
    float* bn2sh = (float*)alloc(LL * DD * sizeof(float));
    const size_t base_end = off;

    unsigned short* attr16 = nullptr;
    int* eid_perm = nullptr;
    if (ws_size >= base_end + (size_t)EE * 8 * sizeof(unsigned short))
        attr16 = (unsigned short*)alloc((size_t)EE * 8 * sizeof(unsigned short));
    else if (ws_size >= base_end + (size_t)EE * sizeof(int))
        eid_perm = (int*)alloc((size_t)EE * sizeof(int));

    // Weight/BN prep (once)
    wprep_kernel<<<(LL * 2 * 32768 + 255) / 256, 256, 0, stream>>>(
        mlp_W1, mlp_W2, w1h, w1l, w2h, w2l);
    bnprep_kernel<<<(LL * 2 * DD + LL * DD + 255) / 256, 256, 0, stream>>>(
        mlp_b1, mbn_g, mbn_b, mbn_m, mbn_v,
        mlp_b2, bn_g, bn_b, bn_m, bn_v,
        bn1sc, bn1sh, bn2sc, bn2sh);

    // CSR build (once)
    const bool csr = (attr16 != nullptr) || (eid_perm != nullptr);
    if (csr) {
        const int egrid = (EE + 255) / 256;
        const int ngrid = (NN + 1023) / 1024;
        hipMemsetAsync(fill, 0, NN * sizeof(int), stream);
        count_kernel<<<egrid, 256, 0, stream>>>(ei, fill);
        scan_a<<<ngrid, 1024, 0, stream>>>(fill, rp, partials);
        scan_b<<<1, 64, 0, stream>>>(partials, ngrid);
        scan_c<<<ngrid, 1024, 0, stream>>>(rp, fill, partials);
        scatter_kernel<<<egrid, 256, 0, stream>>>(ei, eattr, fill, attr16, src_arr, eid_perm);
    }

    if (attr16) {
        // ---- fast path: layer-0 constant-row specialization + fused h_in ----
        hipMemsetAsync(cnt, 0, GG * sizeof(int), stream);
        cnt_kernel<<<64, 256, 0, stream>>>(batch, cnt);

        // layer 0
        vn0_kernel<<<GG, 256, 0, stream>>>(
            cnt, node_emb, vn_emb, vn,
            vn_W1, vn_b1, vbn1_g, vbn1_b, vbn1_m, vbn1_v,
            vn_W2, vn_b2, vbn2_g, vbn2_b, vbn2_m, vbn2_v);
        gin0_kernel<<<NN / 4, 256, 0, stream>>>(
            node_emb, vn_emb, rp, attr16, edge_W, edge_b, eps, agg);
        mlp_mfma_kernel<<<NP / 64, 256, 0, stream>>>(
            agg, w1h, w1l, w2h, w2l, bn1sc, bn1sh, bn2sc, bn2sh,
            h, 0, 1, batch, vn, h16, 1);          // h <- h_in(1), h16 shadow

        // layer 1
        hipMemsetAsync(vt, 0, GDB, stream);
        vt_kernel<<<NN / 16, 256, 0, stream>>>(h, batch, vt);
        vn_kernel<<<GG, 256, 0, stream>>>(
            vt, vn, vn_W1, vn_b1, vbn1_g, vbn1_b, vbn1_m, vbn1_v,
            vn_W2, vn_b2, vbn2_g, vbn2_b, vbn2_m, vbn2_v, 1);   // vn <- vn(2)
        gin_agg_kernel<<<NN / 4, 256, 0, stream>>>(
            h, h16, rp, attr16, src_arr, edge_W, edge_b, eps, agg, 1);
        mlp_mfma_kernel<<<NP / 64, 256, 0, stream>>>(
            agg, w1h, w1l, w2h, w2l, bn1sc, bn1sh, bn2sc, bn2sh,
            h, 1, 1, batch, vn, h16, 1);          // h <- h_in(2), h16 shadow

        // layer 2 (final; no vn add, no relu)
        gin_agg_kernel<<<NN / 4, 256, 0, stream>>>(
            h, h16, rp, attr16, src_arr, edge_W, edge_b, eps, agg, 2);
        mlp_mfma_kernel<<<NP / 64, 256, 0, stream>>>(
            agg, w1h, w1l, w2h, w2l, bn1sc, bn1sh, bn2sc, bn2sh,
            h, 2, 0, batch, vn, h16, 0);
    } else {
        // ---- fallback: original schedule ----
        {
            long total = (long)NN * DD;
            init_kernel<<<(int)((total + 255) / 256), 256, 0, stream>>>(
                x, node_emb, vn_emb, h, vn);
        }
        for (int l = 0; l < LL; ++l) {
            int accum = (l < LL - 1) ? 1 : 0;
            if (accum)
                hipMemsetAsync(vt, 0, GDB, stream);

            hin_kernel<<<NN / (R1 * 2), 256, 0, stream>>>(
                h, h16, vn, batch, eps, agg, vt, l, accum, csr ? 0 : 1);

            if (eid_perm) {
                gin_agg_eid_kernel<<<NN / 2, 256, 0, stream>>>(
                    h, rp, eid_perm, ei, eattr, edge_W, edge_b, eps, agg, l);
            } else {
                edge_kernel<<<(EE + EPB - 1) / EPB, 256, 0, stream>>>(
                    h, ei, eattr, edge_W, edge_b, agg, l);
            }

            mlp_mfma_kernel<<<NP / 64, 256, 0, stream>>>(
                agg, w1h, w1l, w2h, w2l, bn1sc, bn1sh, bn2sc, bn2sh,
                h, l, accum, batch, vn, h16, 0);

            if (accum)
                vn_kernel<<<GG, 256, 0, stream>>>(
                    vt, vn, vn_W1, vn_b1, vbn1_g, vbn1_b, vbn1_m, vbn1_v,
                    vn_W2, vn_b2, vbn2_g, vbn2_b, vbn2_m, vbn2_v, l);
        }
    }
}

// Round 8
// 743.072 us; speedup vs baseline: 3.9029x; 1.0321x over previous
//
#include <hip/hip_runtime.h>
#include <hip/hip_bf16.h>

#define NN 100000
#define NP 100032              // NN rounded up to 64
#define EE 1600000
#define GG 128
#define DD 128
#define LL 3
#define EAA 7
#define BN_EPS 1e-5f

typedef __attribute__((ext_vector_type(8))) short bf16x8;
typedef __attribute__((ext_vector_type(4))) float f32x4;
typedef __attribute__((ext_vector_type(4))) unsigned short u16x4;
typedef _Float16 f16x2 __attribute__((ext_vector_type(2)));

__device__ __forceinline__ unsigned short f2bf(float x) {
    unsigned int u = __float_as_uint(x);
    u = (u + 0x7FFF + ((u >> 16) & 1)) >> 16;
    return (unsigned short)u;
}
__device__ __forceinline__ float bf2f(unsigned short h) {
    return __uint_as_float(((unsigned int)h) << 16);
}
__device__ __forceinline__ float bflo(unsigned int u) {
    return __uint_as_float(u << 16);
}
__device__ __forceinline__ float bfhi(unsigned int u) {
    return __uint_as_float(u & 0xFFFF0000u);
}
__device__ __forceinline__ unsigned int pkf16(float a, float b) {
    f16x2 v = {(_Float16)a, (_Float16)b};
    return __builtin_bit_cast(unsigned int, v);
}

#if __has_builtin(__builtin_amdgcn_fdot2)
#define DOT2(q, w, c) __builtin_amdgcn_fdot2((q), (w), (c), false)
#else
__device__ __forceinline__ float dot2_sw(f16x2 a, f16x2 b, float c) {
    return fmaf((float)a.x, (float)b.x, fmaf((float)a.y, (float)b.y, c));
}
#define DOT2(q, w, c) dot2_sw((q), (w), (c))
#endif

// ---------------------------------------------------------------------------
// Fallback-only K0: h[i,:] = node_emb[x[i],:]; vn[g,:] = vn_emb[0,:]
// ---------------------------------------------------------------------------
__global__ __launch_bounds__(256) void init_kernel(
    const int* __restrict__ x, const float* __restrict__ node_emb,
    const float* __restrict__ vn_emb, float* __restrict__ h,
    float* __restrict__ vn)
{
    long i = (long)blockIdx.x * 256 + threadIdx.x;
    if (i < (long)NN * DD) {
        int node = (int)(i >> 7), d = (int)(i & 127);
        h[i] = node_emb[(long)x[node] * DD + d];
    }
    if (i < GG * DD) vn[i] = vn_emb[i & 127];
}

// ---------------------------------------------------------------------------
// Fallback-only K1: in-place h -> h_in = h + vn[batch]; h16 shadow; agg; vt.
// ---------------------------------------------------------------------------
#define R1 8
__global__ __launch_bounds__(256) void hin_kernel(
    float* __restrict__ hbuf,
    unsigned short* __restrict__ h16,
    const float* __restrict__ vn,
    const int* __restrict__ batch,
    const float* __restrict__ eps,
    float* __restrict__ agg,
    float* __restrict__ vt,
    int layer, int accum_vt, int write_agg)
{
    const int d  = threadIdx.x & 127;
    const int rg = threadIdx.x >> 7;
    const float epl = 1.0f + eps[layer];
    const long row0 = (long)blockIdx.x * (R1 * 2);

    float vacc = 0.0f;
    int   vb   = -1;
    #pragma unroll
    for (int r = 0; r < R1; ++r) {
        long row = row0 + rg + 2 * r;
        if (row >= NN) break;
        int b = batch[row];
        long idx = row * DD + d;
        float hv = hbuf[idx] + vn[(long)b * DD + d];
        hbuf[idx] = hv;
        h16[idx]  = f2bf(hv);
        if (write_agg) agg[idx] = epl * hv;
        if (accum_vt) {
            if (b != vb) {
                if (vb >= 0) atomicAdd(&vt[(long)vb * DD + d], vacc);
                vb = b; vacc = 0.0f;
            }
            vacc += hv;
        }
    }
    if (accum_vt && vb >= 0) atomicAdd(&vt[(long)vb * DD + d], vacc);
}

// ---------------------------------------------------------------------------
// vt segment-sum only (reads h_in fp32), run-length fused atomics.
// ---------------------------------------------------------------------------
__global__ __launch_bounds__(256) void vt_kernel(
    const float* __restrict__ hbuf, const int* __restrict__ batch,
    float* __restrict__ vt)
{
    const int d  = threadIdx.x & 127;
    const int rg = threadIdx.x >> 7;
    const long row0 = (long)blockIdx.x * 16;
    float vacc = 0.0f;
    int   vb   = -1;
    #pragma unroll
    for (int r = 0; r < 8; ++r) {
        long row = row0 + rg + 2 * r;
        if (row >= NN) break;
        int b = batch[row];
        float hv = hbuf[row * DD + d];
        if (b != vb) {
            if (vb >= 0) atomicAdd(&vt[(long)vb * DD + d], vacc);
            vb = b; vacc = 0.0f;
        }
        vacc += hv;
    }
    if (vb >= 0) atomicAdd(&vt[(long)vb * DD + d], vacc);
}

// ---------------------------------------------------------------------------
// Per-graph node counts (batch sorted; run-length fused atomics).
// ---------------------------------------------------------------------------
__global__ __launch_bounds__(256) void cnt_kernel(
    const int* __restrict__ batch, int* __restrict__ cnt)
{
    const int tid = blockIdx.x * 256 + threadIdx.x;     // 64*256 = 16384 threads
    const int CH  = (NN + 16383) / 16384;               // 7
    long s = (long)tid * CH;
    long e = s + CH; if (e > NN) e = NN;
    int vb = -1, c = 0;
    for (long i = s; i < e; ++i) {
        int b = batch[i];
        if (b != vb) { if (vb >= 0) atomicAdd(&cnt[vb], c); vb = b; c = 0; }
        ++c;
    }
    if (vb >= 0) atomicAdd(&cnt[vb], c);
}

// ---------------------------------------------------------------------------
// CSR build: count -> scan -> scatter. Built once, reused by all 3 layers.
// ---------------------------------------------------------------------------
__global__ __launch_bounds__(256) void count_kernel(
    const int* __restrict__ ei, int* __restrict__ deg)
{
    long e = (long)blockIdx.x * 256 + threadIdx.x;
    if (e < EE) atomicAdd(&deg[ei[EE + e]], 1);
}

__global__ __launch_bounds__(1024) void scan_a(
    const int* __restrict__ deg, int* __restrict__ rp, int* __restrict__ partials)
{
    __shared__ int s[1024];
    int t = threadIdx.x;
    long i = (long)blockIdx.x * 1024 + t;
    int v = (i < NN) ? deg[i] : 0;
    s[t] = v;
    __syncthreads();
    for (int off = 1; off < 1024; off <<= 1) {
        int u = (t >= off) ? s[t - off] : 0;
        __syncthreads();
        s[t] += u;
        __syncthreads();
    }
    if (i < NN) rp[i] = s[t] - v;
    if (t == 1023) partials[blockIdx.x] = s[1023];
}

__global__ void scan_b(int* __restrict__ partials, int nb)
{
    if (threadIdx.x == 0) {
        int run = 0;
        for (int i = 0; i < nb; ++i) { int v = partials[i]; partials[i] = run; run += v; }
    }
}

__global__ __launch_bounds__(1024) void scan_c(
    int* __restrict__ rp, int* __restrict__ fill, const int* __restrict__ partials)
{
    long i = (long)blockIdx.x * 1024 + threadIdx.x;
    if (i < NN) {
        int v = rp[i] + partials[blockIdx.x];
        rp[i] = v;
        fill[i] = v;
    }
    if (i == 0) rp[NN] = EE;
}

// Tier-1: attr16 = 4 dwords per edge (7 fp16 attrs packed in pairs + pad).
__global__ __launch_bounds__(256) void scatter_kernel(
    const int* __restrict__ ei, const float* __restrict__ eattr,
    int* __restrict__ fill, unsigned int* __restrict__ attr16,
    int* __restrict__ src_arr, int* __restrict__ eid_perm)
{
    long e = (long)blockIdx.x * 256 + threadIdx.x;
    if (e >= EE) return;
    int dst = ei[EE + e];
    int pos = atomicAdd(&fill[dst], 1);
    if (attr16) {
        uint4 w;
        w.x = pkf16(eattr[e * EAA + 0], eattr[e * EAA + 1]);
        w.y = pkf16(eattr[e * EAA + 2], eattr[e * EAA + 3]);
        w.z = pkf16(eattr[e * EAA + 4], eattr[e * EAA + 5]);
        w.w = pkf16(eattr[e * EAA + 6], 0.0f);
        *(uint4*)(attr16 + (long)pos * 4) = w;
        src_arr[pos] = ei[e];
    } else {
        eid_perm[pos] = (int)e;
    }
}

// Shared edge-transform macro pieces: weight-pair preamble builds
// wx[4]/wy[4] (fp16 pairs along attr dim) for this lane's 2 columns.
#define WPAIR_PREAMBLE(eWl)                                                   \
    f16x2 wx[4], wy[4];                                                       \
    {                                                                         \
        _Pragma("unroll")                                                     \
        for (int j = 0; j < 3; ++j) {                                         \
            float2 p0 = *(const float2*)&(eWl)[(2 * j) * DD + d0];            \
            float2 p1 = *(const float2*)&(eWl)[(2 * j + 1) * DD + d0];        \
            wx[j] = (f16x2){(_Float16)p0.x, (_Float16)p1.x};                  \
            wy[j] = (f16x2){(_Float16)p0.y, (_Float16)p1.y};                  \
        }                                                                     \
        float2 p6 = *(const float2*)&(eWl)[6 * DD + d0];                      \
        wx[3] = (f16x2){(_Float16)p6.x, (_Float16)0.0f};                      \
        wy[3] = (f16x2){(_Float16)p6.y, (_Float16)0.0f};                      \
    }

#define EDOT(AU, EX, EY)                                                      \
    float EX = bias.x, EY = bias.y;                                           \
    {                                                                         \
        f16x2 q0 = __builtin_bit_cast(f16x2, AU.x);                           \
        f16x2 q1 = __builtin_bit_cast(f16x2, AU.y);                           \
        f16x2 q2 = __builtin_bit_cast(f16x2, AU.z);                           \
        f16x2 q3 = __builtin_bit_cast(f16x2, AU.w);                           \
        EX = DOT2(q0, wx[0], EX); EY = DOT2(q0, wy[0], EY);                   \
        EX = DOT2(q1, wx[1], EX); EY = DOT2(q1, wy[1], EY);                   \
        EX = DOT2(q2, wx[2], EX); EY = DOT2(q2, wy[2], EY);                   \
        EX = DOT2(q3, wx[3], EX); EY = DOT2(q3, wy[3], EY);                   \
    }

// ---------------------------------------------------------------------------
// K2 layer-0 special: h_in(0) is ONE constant row c = node_emb[0]+vn_emb[0].
// No gathers. Writes z as bf16 hi/lo.
// ---------------------------------------------------------------------------
__global__ __launch_bounds__(256) void gin0_kernel(
    const float* __restrict__ node_emb,
    const float* __restrict__ vn_emb,
    const int* __restrict__ rp,
    const unsigned int* __restrict__ attr16,
    const float* __restrict__ eW, const float* __restrict__ eb,
    const float* __restrict__ eps,
    unsigned short* __restrict__ aggh, unsigned short* __restrict__ aggl)
{
    const int lane = threadIdx.x & 63;
    const int wid  = threadIdx.x >> 6;
    const long n   = (long)blockIdx.x * 4 + wid;
    const int d0   = lane * 2;

    WPAIR_PREAMBLE(eW)
    const float2 bias = *(const float2*)&eb[d0];
    const float  epl  = 1.0f + eps[0];

    const float cx = node_emb[d0]     + vn_emb[d0];
    const float cy = node_emb[d0 + 1] + vn_emb[d0 + 1];
    float accx = epl * cx, accy = epl * cy;

    int p  = rp[n];
    const int p1 = rp[n + 1];

    #define EDGE0(AU)                                                         \
    {                                                                         \
        EDOT(AU, ex, ey)                                                      \
        float mx = cx + ex, my = cy + ey;                                     \
        accx += fmaxf(mx, 0.0f); accy += fmaxf(my, 0.0f);                     \
    }

    for (; p + 4 <= p1; p += 4) {
        const uint4* a4p = (const uint4*)(attr16 + (long)p * 4);
        uint4 A0 = a4p[0];
        uint4 A1 = a4p[1];
        uint4 A2 = a4p[2];
        uint4 A3 = a4p[3];
        EDGE0(A0)
        EDGE0(A1)
        EDGE0(A2)
        EDGE0(A3)
    }
    for (; p < p1; ++p) {
        uint4 A = *(const uint4*)(attr16 + (long)p * 4);
        EDGE0(A)
    }
    #undef EDGE0

    unsigned short hx = f2bf(accx), hy = f2bf(accy);
    *(unsigned int*)&aggh[n * DD + d0] = (unsigned int)hx | ((unsigned int)hy << 16);
    *(unsigned int*)&aggl[n * DD + d0] =
        (unsigned int)f2bf(accx - bf2f(hx)) | ((unsigned int)f2bf(accy - bf2f(hy)) << 16);
}

// ---------------------------------------------------------------------------
// K2 (CSR, ILP): one wave per dst node; lane owns cols {2l, 2l+1}; x4 unroll.
// fdot2 edge transform; bf16 shadow gathers; writes z as bf16 hi/lo.
// ---------------------------------------------------------------------------
__global__ __launch_bounds__(256) void gin_agg_kernel(
    const float* __restrict__ h_in,
    const unsigned short* __restrict__ h16,
    const int* __restrict__ rp,
    const unsigned int* __restrict__ attr16,
    const int* __restrict__ src_arr,
    const float* __restrict__ eW, const float* __restrict__ eb,
    const float* __restrict__ eps,
    unsigned short* __restrict__ aggh, unsigned short* __restrict__ aggl,
    int layer)
{
    const int lane = threadIdx.x & 63;
    const int wid  = threadIdx.x >> 6;
    const long n   = (long)blockIdx.x * 4 + wid;
    const int d0   = lane * 2;

    const float* eWl = eW + (long)layer * EAA * DD;
    WPAIR_PREAMBLE(eWl)
    const float2 bias = *(const float2*)&eb[layer * DD + d0];
    const float  epl  = 1.0f + eps[layer];

    float2 hn = *(const float2*)&h_in[n * DD + d0];
    float accx = epl * hn.x, accy = epl * hn.y;

    int p  = rp[n];
    const int p1 = rp[n + 1];

    #define EDGE(AU, GU)                                                      \
    {                                                                         \
        EDOT(AU, ex, ey)                                                      \
        float mx = bflo(GU) + ex, my = bfhi(GU) + ey;                         \
        accx += fmaxf(mx, 0.0f); accy += fmaxf(my, 0.0f);                     \
    }

    for (; p + 4 <= p1; p += 4) {
        int s0 = src_arr[p];
        int s1 = src_arr[p + 1];
        int s2 = src_arr[p + 2];
        int s3 = src_arr[p + 3];
        const uint4* a4p = (const uint4*)(attr16 + (long)p * 4);
        uint4 A0 = a4p[0];
        uint4 A1 = a4p[1];
        uint4 A2 = a4p[2];
        uint4 A3 = a4p[3];
        unsigned int g0 = *(const unsigned int*)(h16 + (long)s0 * DD + d0);
        unsigned int g1 = *(const unsigned int*)(h16 + (long)s1 * DD + d0);
        unsigned int g2 = *(const unsigned int*)(h16 + (long)s2 * DD + d0);
        unsigned int g3 = *(const unsigned int*)(h16 + (long)s3 * DD + d0);
        EDGE(A0, g0)
        EDGE(A1, g1)
        EDGE(A2, g2)
        EDGE(A3, g3)
    }
    for (; p < p1; ++p) {
        int s = src_arr[p];
        uint4 A = *(const uint4*)(attr16 + (long)p * 4);
        unsigned int g = *(const unsigned int*)(h16 + (long)s * DD + d0);
        EDGE(A, g)
    }
    #undef EDGE

    unsigned short hx = f2bf(accx), hy = f2bf(accy);
    *(unsigned int*)&aggh[n * DD + d0] = (unsigned int)hx | ((unsigned int)hy << 16);
    *(unsigned int*)&aggl[n * DD + d0] =
        (unsigned int)f2bf(accx - bf2f(hx)) | ((unsigned int)f2bf(accy - bf2f(hy)) << 16);
}

// ---------------------------------------------------------------------------
// K2 fallback A (eid indirection) — fp32 agg
// ---------------------------------------------------------------------------
__global__ __launch_bounds__(256) void gin_agg_eid_kernel(
    const float* __restrict__ h_in,
    const int* __restrict__ rp,
    const int* __restrict__ eid_perm,
    const int* __restrict__ ei,
    const float* __restrict__ eattr,
    const float* __restrict__ eW, const float* __restrict__ eb,
    const float* __restrict__ eps,
    float* __restrict__ agg, int layer)
{
    const int d    = threadIdx.x & 127;
    const int half = threadIdx.x >> 7;
    const long n   = (long)blockIdx.x * 2 + half;

    float w[EAA];
    #pragma unroll
    for (int a = 0; a < EAA; ++a) w[a] = eW[layer * EAA * DD + a * DD + d];
    const float bias = eb[layer * DD + d];
    const float epl  = 1.0f + eps[layer];

    float acc = epl * h_in[n * DD + d];
    const int p0 = rp[n], p1 = rp[n + 1];
    for (int p = p0; p < p1; ++p) {
        int e = eid_perm[p];
        int src = ei[e];
        float ea = bias;
        #pragma unroll
        for (int a = 0; a < EAA; ++a)
            ea = fmaf(eattr[(long)e * EAA + a], w[a], ea);
        float m = h_in[(long)src * DD + d] + ea;
        acc += m > 0.0f ? m : 0.0f;
    }
    agg[n * DD + d] = acc;
}

// ---------------------------------------------------------------------------
// K2 fallback B (atomic path) — fp32 agg
// ---------------------------------------------------------------------------
#define EPB 64
__global__ __launch_bounds__(256) void edge_kernel(
    const float* __restrict__ h_in,
    const int* __restrict__ ei,
    const float* __restrict__ eattr,
    const float* __restrict__ eW,
    const float* __restrict__ eb,
    float* __restrict__ agg,
    int layer)
{
    const int d    = threadIdx.x & 127;
    const int esub = threadIdx.x >> 7;
    float w[EAA];
    #pragma unroll
    for (int a = 0; a < EAA; ++a) w[a] = eW[layer * EAA * DD + a * DD + d];
    const float bias = eb[layer * DD + d];

    const long base = (long)blockIdx.x * EPB;
    for (int k = esub; k < EPB; k += 2) {
        long e = base + k;
        if (e >= EE) break;
        int s = ei[e];
        int t = ei[EE + e];
        float acc = bias;
        #pragma unroll
        for (int a = 0; a < EAA; ++a)
            acc = fmaf(eattr[e * EAA + a], w[a], acc);
        float m = h_in[(long)s * DD + d] + acc;
        m = m > 0.0f ? m : 0.0f;
        atomicAdd(&agg[(long)t * DD + d], m);
    }
}

// ---------------------------------------------------------------------------
// Weight prep (operand-swapped; weights are the MFMA A operand). See R5 notes.
// ---------------------------------------------------------------------------
__global__ __launch_bounds__(256) void wprep_kernel(
    const float* __restrict__ W1, const float* __restrict__ W2,
    unsigned short* __restrict__ w1h, unsigned short* __restrict__ w1l,
    unsigned short* __restrict__ w2h, unsigned short* __restrict__ w2l)
{
    int tid = blockIdx.x * 256 + threadIdx.x;
    if (tid >= LL * 2 * 32768) return;
    int l = tid / 65536;
    int rem = tid - l * 65536;
    int mat = rem >> 15;
    int fi = rem & 32767;
    int b = fi & 7, lane = (fi >> 3) & 63;
    int kgrp = ((lane >> 4) << 3) + b;
    if (mat == 0) {
        int mt = (fi >> 9) & 15, kk = fi >> 13;
        int m = (mt << 4) + (lane & 15);
        int k = (kk << 5) + kgrp;
        float v = W1[(long)l * DD * 2 * DD + (long)k * 2 * DD + m];
        unsigned short hi = f2bf(v);
        w1h[(long)l * 32768 + fi] = hi;
        w1l[(long)l * 32768 + fi] = f2bf(v - bf2f(hi));
    } else {
        int mt = (fi >> 9) & 7, kk = fi >> 12;
        int m = (mt << 4) + (lane & 15);
        int k = (kk << 5) + kgrp;
        float v = W2[(long)l * 2 * DD * DD + (long)k * DD + m];
        unsigned short hi = f2bf(v);
        w2h[(long)l * 32768 + fi] = hi;
        w2l[(long)l * 32768 + fi] = f2bf(v - bf2f(hi));
    }
}

// ---------------------------------------------------------------------------
// BN prep: fold bias+BN into per-column scale/shift.
// ---------------------------------------------------------------------------
__global__ __launch_bounds__(256) void bnprep_kernel(
    const float* __restrict__ b1, const float* __restrict__ g1,
    const float* __restrict__ be1, const float* __restrict__ m1,
    const float* __restrict__ v1,
    const float* __restrict__ b2, const float* __restrict__ g2,
    const float* __restrict__ be2, const float* __restrict__ m2,
    const float* __restrict__ v2,
    float* __restrict__ sc1, float* __restrict__ sh1,
    float* __restrict__ sc2, float* __restrict__ sh2)
{
    int tid = blockIdx.x * 256 + threadIdx.x;
    if (tid < LL * 2 * DD) {
        float sc = g1[tid] / sqrtf(v1[tid] + BN_EPS);
        sc1[tid] = sc;
        sh1[tid] = (b1[tid] - m1[tid]) * sc + be1[tid];
    }
    int t2 = tid - LL * 2 * DD;
    if (t2 >= 0 && t2 < LL * DD) {
        float sc = g2[t2] / sqrtf(v2[t2] + BN_EPS);
        sc2[t2] = sc;
        sh2[t2] = (b2[t2] - m2[t2]) * sc + be2[t2];
    }
}

// ---------------------------------------------------------------------------
// K3 (MFMA, operand-swapped) with FUSED h_in epilogue.
// zfmt=1: z already split as bf16 hi/lo arrays (no staging conversion).
// zfmt=0: z fp32, split during staging (fallback path).
// fuse=1: out = relu(bn2(h2)) + vn[batch[row]]; write d_out fp32 + h16 bf16.
// ---------------------------------------------------------------------------
__global__ __launch_bounds__(256, 2) void mlp_mfma_kernel(
    const float* __restrict__ z_in,
    const unsigned short* __restrict__ z16h, const unsigned short* __restrict__ z16l,
    int zfmt,
    const unsigned short* __restrict__ w1h, const unsigned short* __restrict__ w1l,
    const unsigned short* __restrict__ w2h, const unsigned short* __restrict__ w2l,
    const float* __restrict__ sc1, const float* __restrict__ sh1,
    const float* __restrict__ sc2, const float* __restrict__ sh2,
    float* __restrict__ h_out, int layer, int do_relu,
    const int* __restrict__ batch, const float* __restrict__ vnbuf,
    unsigned short* __restrict__ h16, int fuse)
{
    __shared__ char lds[65536];
    const int tid  = threadIdx.x;
    const int lane = tid & 63;
    const int wv   = tid >> 6;
    const long row0 = (long)blockIdx.x * 64;
    const int kb = (lane >> 4) << 3;

    // ---- stage z [64][128] -> hi/lo bf16 LDS (hi at 0, lo at 16384) ----
    if (zfmt) {
        const uint4* zh = (const uint4*)(z16h + row0 * DD);
        const uint4* zl = (const uint4*)(z16l + row0 * DD);
        #pragma unroll
        for (int i = 0; i < 4; ++i) {
            int idx = tid + i * 256;
            uint4 hv = zh[idx];
            uint4 lv = zl[idx];
            int r = idx >> 4;
            int c = (idx & 15) << 3;
            int off = ((r << 8) + (c << 1)) ^ ((r & 7) << 4);
            *(uint4*)(lds + off)         = hv;
            *(uint4*)(lds + 16384 + off) = lv;
        }
    } else {
        const float4* zi = (const float4*)(z_in + row0 * DD);
        #pragma unroll
        for (int i = 0; i < 8; ++i) {
            int idx = tid + i * 256;
            float4 v = zi[idx];
            int r = idx >> 5;
            int c = (idx & 31) << 2;
            u16x4 hv, lv;
            hv.x = f2bf(v.x); lv.x = f2bf(v.x - bf2f(hv.x));
            hv.y = f2bf(v.y); lv.y = f2bf(v.y - bf2f(hv.y));
            hv.z = f2bf(v.z); lv.z = f2bf(v.z - bf2f(hv.z));
            hv.w = f2bf(v.w); lv.w = f2bf(v.w - bf2f(hv.w));
            int off = ((r << 8) + (c << 1)) ^ ((r & 7) << 4);
            *(u16x4*)(lds + off)         = hv;
            *(u16x4*)(lds + 16384 + off) = lv;
        }
    }
    __syncthreads();

    // ---- B1 frags (z^T): B[k][n], lane&15 = n (node row within tile) ----
    bf16x8 B1h[4][4], B1l[4][4];
    #pragma unroll
    for (int nt = 0; nt < 4; ++nt) {
        int r = (nt << 4) + (lane & 15);
        #pragma unroll
        for (int kk = 0; kk < 4; ++kk) {
            int off = ((r << 8) + (((kk << 5) + kb) << 1)) ^ ((r & 7) << 4);
            B1h[nt][kk] = *(const bf16x8*)(lds + off);
            B1l[nt][kk] = *(const bf16x8*)(lds + 16384 + off);
        }
    }
    __syncthreads();   // z reads done; LDS becomes u (hi at 0, lo at 32768)

    // ---- GEMM1 + BN1 + relu -> u in LDS (wave owns m-tiles wv*4..wv*4+3) ----
    const unsigned short* w1hl = w1h + (long)layer * 32768;
    const unsigned short* w1ll = w1l + (long)layer * 32768;
    #pragma unroll
    for (int mtl = 0; mtl < 4; ++mtl) {
        const int mt = (wv << 2) + mtl;
        bf16x8 Ah[4], Al[4];
        #pragma unroll
        for (int kk = 0; kk < 4; ++kk) {
            const long boff = ((long)((kk << 4) + mt) * 64 + lane) << 3;
            Ah[kk] = *(const bf16x8*)(w1hl + boff);
            Al[kk] = *(const bf16x8*)(w1ll + boff);
        }
        f32x4 acc[4];
        #pragma unroll
        for (int nt = 0; nt < 4; ++nt) acc[nt] = (f32x4){0.f, 0.f, 0.f, 0.f};
        #pragma unroll
        for (int kk = 0; kk < 4; ++kk) {
            #pragma unroll
            for (int nt = 0; nt < 4; ++nt) {
                acc[nt] = __builtin_amdgcn_mfma_f32_16x16x32_bf16(Ah[kk], B1h[nt][kk], acc[nt], 0, 0, 0);
                acc[nt] = __builtin_amdgcn_mfma_f32_16x16x32_bf16(Ah[kk], B1l[nt][kk], acc[nt], 0, 0, 0);
                acc[nt] = __builtin_amdgcn_mfma_f32_16x16x32_bf16(Al[kk], B1h[nt][kk], acc[nt], 0, 0, 0);
            }
        }
        const int m0 = (mt << 4) + ((lane >> 4) << 2);
        const float4 s4 = *(const float4*)&sc1[layer * 2 * DD + m0];
        const float4 t4 = *(const float4*)&sh1[layer * 2 * DD + m0];
        #pragma unroll
        for (int nt = 0; nt < 4; ++nt) {
            int row = (nt << 4) + (lane & 15);
            float u0 = fmaxf(fmaf(acc[nt][0], s4.x, t4.x), 0.0f);
            float u1 = fmaxf(fmaf(acc[nt][1], s4.y, t4.y), 0.0f);
            float u2 = fmaxf(fmaf(acc[nt][2], s4.z, t4.z), 0.0f);
            float u3 = fmaxf(fmaf(acc[nt][3], s4.w, t4.w), 0.0f);
            u16x4 hv, lv;
            hv.x = f2bf(u0); lv.x = f2bf(u0 - bf2f(hv.x));
            hv.y = f2bf(u1); lv.y = f2bf(u1 - bf2f(hv.y));
            hv.z = f2bf(u2); lv.z = f2bf(u2 - bf2f(hv.z));
            hv.w = f2bf(u3); lv.w = f2bf(u3 - bf2f(hv.w));
            int off = ((row << 9) + (m0 << 1)) ^ ((row & 7) << 4);
            *(u16x4*)(lds + off)         = hv;
            *(u16x4*)(lds + 32768 + off) = lv;
        }
    }
    __syncthreads();

    // ---- GEMM2 + BN2 (+relu/+vn) -> h (wave owns m-tiles wv*2, wv*2+1) ----
    const unsigned short* w2hl = w2h + (long)layer * 32768;
    const unsigned short* w2ll = w2l + (long)layer * 32768;
    f32x4 acc2[2][4];
    #pragma unroll
    for (int mtl = 0; mtl < 2; ++mtl)
        #pragma unroll
        for (int nt = 0; nt < 4; ++nt) acc2[mtl][nt] = (f32x4){0.f, 0.f, 0.f, 0.f};

    #pragma unroll
    for (int kk = 0; kk < 8; ++kk) {
        bf16x8 Bh[4], Bl[4];
        #pragma unroll
        for (int nt = 0; nt < 4; ++nt) {
            int r = (nt << 4) + (lane & 15);
            int off = ((r << 9) + (((kk << 5) + kb) << 1)) ^ ((r & 7) << 4);
            Bh[nt] = *(const bf16x8*)(lds + off);
            Bl[nt] = *(const bf16x8*)(lds + 32768 + off);
        }
        #pragma unroll
        for (int mtl = 0; mtl < 2; ++mtl) {
            const int mt = (wv << 1) + mtl;
            const long boff = ((long)((kk << 3) + mt) * 64 + lane) << 3;
            bf16x8 Ah = *(const bf16x8*)(w2hl + boff);
            bf16x8 Al = *(const bf16x8*)(w2ll + boff);
            #pragma unroll
            for (int nt = 0; nt < 4; ++nt) {
                acc2[mtl][nt] = __builtin_amdgcn_mfma_f32_16x16x32_bf16(Ah, Bh[nt], acc2[mtl][nt], 0, 0, 0);
                acc2[mtl][nt] = __builtin_amdgcn_mfma_f32_16x16x32_bf16(Ah, Bl[nt], acc2[mtl][nt], 0, 0, 0);
                acc2[mtl][nt] = __builtin_amdgcn_mfma_f32_16x16x32_bf16(Al, Bh[nt], acc2[mtl][nt], 0, 0, 0);
            }
        }
    }
    #pragma unroll
    for (int mtl = 0; mtl < 2; ++mtl) {
        const int m0 = ((((wv << 1) + mtl)) << 4) + ((lane >> 4) << 2);
        const float4 s4 = *(const float4*)&sc2[layer * DD + m0];
        const float4 t4 = *(const float4*)&sh2[layer * DD + m0];
        #pragma unroll
        for (int nt = 0; nt < 4; ++nt) {
            long row = row0 + (nt << 4) + (lane & 15);
            if (row < NN) {
                float o0 = fmaf(acc2[mtl][nt][0], s4.x, t4.x);
                float o1 = fmaf(acc2[mtl][nt][1], s4.y, t4.y);
                float o2 = fmaf(acc2[mtl][nt][2], s4.z, t4.z);
                float o3 = fmaf(acc2[mtl][nt][3], s4.w, t4.w);
                if (do_relu) {
                    o0 = fmaxf(o0, 0.0f); o1 = fmaxf(o1, 0.0f);
                    o2 = fmaxf(o2, 0.0f); o3 = fmaxf(o3, 0.0f);
                }
                if (fuse) {
                    int b = batch[row];
                    float4 vnv = *(const float4*)&vnbuf[(long)b * DD + m0];
                    o0 += vnv.x; o1 += vnv.y; o2 += vnv.z; o3 += vnv.w;
                    u16x4 hv;
                    hv.x = f2bf(o0); hv.y = f2bf(o1);
                    hv.z = f2bf(o2); hv.w = f2bf(o3);
                    *(u16x4*)&h16[row * DD + m0] = hv;
                }
                *(float4*)&h_out[row * DD + m0] = make_float4(o0, o1, o2, o3);
            }
        }
    }
}

// ---------------------------------------------------------------------------
// K4: virtual-node MLP. One block per graph g. row = vt[g] + vn[g].
// ---------------------------------------------------------------------------
__global__ __launch_bounds__(256) void vn_kernel(
    const float* __restrict__ vt, float* __restrict__ vn,
    const float* __restrict__ W1, const float* __restrict__ b1,
    const float* __restrict__ g1, const float* __restrict__ be1,
    const float* __restrict__ m1, const float* __restrict__ v1,
    const float* __restrict__ W2, const float* __restrict__ b2,
    const float* __restrict__ g2, const float* __restrict__ be2,
    const float* __restrict__ m2, const float* __restrict__ v2,
    int layer)
{
    __shared__ float row[DD];
    __shared__ float u[2 * DD];
    const int g = blockIdx.x;
    const int t = threadIdx.x;

    if (t < DD) row[t] = vt[(long)g * DD + t] + vn[(long)g * DD + t];
    __syncthreads();

    {
        const float* W = W1 + (long)layer * DD * 2 * DD;
        float acc = 0.0f;
        for (int k = 0; k < DD; ++k) acc = fmaf(row[k], W[k * 2 * DD + t], acc);
        const long o = (long)layer * 2 * DD + t;
        float sc = g1[o] / sqrtf(v1[o] + BN_EPS);
        float sh = be1[o] - m1[o] * sc;
        float val = (acc + b1[o]) * sc + sh;
        u[t] = val > 0.0f ? val : 0.0f;
    }
    __syncthreads();

    if (t < DD) {
        const float* W = W2 + (long)layer * 2 * DD * DD;
        float acc = 0.0f;
        for (int k = 0; k < 2 * DD; ++k) acc = fmaf(u[k], W[k * DD + t], acc);
        const long o = (long)layer * DD + t;
        float sc = g2[o] / sqrtf(v2[o] + BN_EPS);
        float sh = be2[o] - m2[o] * sc;
        float val = (acc + b2[o]) * sc + sh;
        vn[(long)g * DD + t] = val > 0.0f ? val : 0.0f;
    }
}

// ---------------------------------------------------------------------------
// K4 layer-0 special: vt(0)+vn(0) = cnt[g]*(node_emb+vn_emb) + vn_emb.
// ---------------------------------------------------------------------------
__global__ __launch_bounds__(256) void vn0_kernel(
    const int* __restrict__ cnt,
    const float* __restrict__ node_emb, const float* __restrict__ vn_emb,
    float* __restrict__ vn,
    const float* __restrict__ W1, const float* __restrict__ b1,
    const float* __restrict__ g1, const float* __restrict__ be1,
    const float* __restrict__ m1, const float* __restrict__ v1,
    const float* __restrict__ W2, const float* __restrict__ b2,
    const float* __restrict__ g2, const float* __restrict__ be2,
    const float* __restrict__ m2, const float* __restrict__ v2)
{
    __shared__ float row[DD];
    __shared__ float u[2 * DD];
    const int g = blockIdx.x;
    const int t = threadIdx.x;

    if (t < DD) {
        float c = node_emb[t] + vn_emb[t];
        row[t] = (float)cnt[g] * c + vn_emb[t];
    }
    __syncthreads();

    {
        float acc = 0.0f;
        for (int k = 0; k < DD; ++k) acc = fmaf(row[k], W1[k * 2 * DD + t], acc);
        float sc = g1[t] / sqrtf(v1[t] + BN_EPS);
        float sh = be1[t] - m1[t] * sc;
        float val = (acc + b1[t]) * sc + sh;
        u[t] = val > 0.0f ? val : 0.0f;
    }
    __syncthreads();

    if (t < DD) {
        float acc = 0.0f;
        for (int k = 0; k < 2 * DD; ++k) acc = fmaf(u[k], W2[k * DD + t], acc);
        float sc = g2[t] / sqrtf(v2[t] + BN_EPS);
        float sh = be2[t] - m2[t] * sc;
        float val = (acc + b2[t]) * sc + sh;
        vn[(long)g * DD + t] = val > 0.0f ? val : 0.0f;
    }
}

// ---------------------------------------------------------------------------
extern "C" void kernel_launch(void* const* d_in, const int* in_sizes, int n_in,
                              void* d_out, int out_size, void* d_ws, size_t ws_size,
                              hipStream_t stream)
{
    const int*   x       = (const int*)  d_in[0];
    const int*   ei      = (const int*)  d_in[1];
    const float* eattr   = (const float*)d_in[2];
    const int*   batch   = (const int*)  d_in[3];
    const float* node_emb= (const float*)d_in[4];
    const float* vn_emb  = (const float*)d_in[5];
    const float* edge_W  = (const float*)d_in[6];
    const float* edge_b  = (const float*)d_in[7];
    const float* eps     = (const float*)d_in[8];
    const float* mlp_W1  = (const float*)d_in[9];
    const float* mlp_b1  = (const float*)d_in[10];
    const float* mbn_g   = (const float*)d_in[11];
    const float* mbn_b   = (const float*)d_in[12];
    const float* mbn_m   = (const float*)d_in[13];
    const float* mbn_v   = (const float*)d_in[14];
    const float* mlp_W2  = (const float*)d_in[15];
    const float* mlp_b2  = (const float*)d_in[16];
    const float* bn_g    = (const float*)d_in[17];
    const float* bn_b    = (const float*)d_in[18];
    const float* bn_m    = (const float*)d_in[19];
    const float* bn_v    = (const float*)d_in[20];
    const float* vn_W1   = (const float*)d_in[21];
    const float* vn_b1   = (const float*)d_in[22];
    const float* vbn1_g  = (const float*)d_in[23];
    const float* vbn1_b  = (const float*)d_in[24];
    const float* vbn1_m  = (const float*)d_in[25];
    const float* vbn1_v  = (const float*)d_in[26];
    const float* vn_W2   = (const float*)d_in[27];
    const float* vn_b2   = (const float*)d_in[28];
    const float* vbn2_g  = (const float*)d_in[29];
    const float* vbn2_b  = (const float*)d_in[30];
    const float* vbn2_m  = (const float*)d_in[31];
    const float* vbn2_v  = (const float*)d_in[32];

    float* h = (float*)d_out;
    char*  ws = (char*)d_ws;

    size_t off = 0;
    auto alloc = [&](size_t bytes) -> void* {
        void* p = ws + off;
        off += (bytes + 255) & ~(size_t)255;
        return p;
    };
    const size_t GDB = (size_t)GG * DD * sizeof(float);

    float* agg      = (float*)alloc((size_t)NP * DD * sizeof(float));
    unsigned short* aggh = (unsigned short*)agg;                 // alias: z hi
    unsigned short* aggl = aggh + (size_t)NP * DD;               // alias: z lo
    unsigned short* h16 = (unsigned short*)alloc((size_t)NN * DD * sizeof(unsigned short));
    float* vn       = (float*)alloc(GDB);
    float* vt       = (float*)alloc(GDB);
    int*   rp       = (int*)  alloc((NN + 1) * sizeof(int));
    int*   fill     = (int*)  alloc(NN * sizeof(int));
    int*   partials = (int*)  alloc(128 * sizeof(int));
    int*   cnt      = (int*)  alloc(GG * sizeof(int));
    int*   src_arr  = (int*)  alloc((size_t)EE * sizeof(int));
    unsigned short* w1h = (unsigned short*)alloc(LL * 32768 * sizeof(unsigned short));
    unsigned short* w1l = (unsigned short*)alloc(LL * 32768 * sizeof(unsigned short));
    unsigned short* w2h = (unsigned short*)alloc(LL * 32768 * sizeof(unsigned short));
    unsigned short* w2l = (unsigned short*)alloc(LL * 32768 * sizeof(unsigned short));
    float* bn1sc = (float*)alloc(LL * 2 * DD * sizeof(float));
    float* bn1sh = (float*)alloc(LL * 2 * DD * sizeof(float));
    float* bn2sc = (float*)alloc(LL * DD * sizeof(float));
    float* bn2sh = (float*)alloc(LL * DD * sizeof(float));
    const size_t base_end = off;

    unsigned int* attr16 = nullptr;
    int* eid_perm = nullptr;
    if (ws_size >= base_end + (size_t)EE * 4 * sizeof(unsigned int))
        attr16 = (unsigned int*)alloc((size_t)EE * 4 * sizeof(unsigned int));
    else if (ws_size >= base_end + (size_t)EE * sizeof(int))
        eid_perm = (int*)alloc((size_t)EE * sizeof(int));

    // Weight/BN prep (once)
    wprep_kernel<<<(LL * 2 * 32768 + 255) / 256, 256, 0, stream>>>(
        mlp_W1, mlp_W2, w1h, w1l, w2h, w2l);
    bnprep_kernel<<<(LL * 2 * DD + LL * DD + 255) / 256, 256, 0, stream>>>(
        mlp_b1, mbn_g, mbn_b, mbn_m, mbn_v,
        mlp_b2, bn_g, bn_b, bn_m, bn_v,
        bn1sc, bn1sh, bn2sc, bn2sh);

    // CSR build (once)
    const bool csr = (attr16 != nullptr) || (eid_perm != nullptr);
    if (csr) {
        const int egrid = (EE + 255) / 256;
        const int ngrid = (NN + 1023) / 1024;
        hipMemsetAsync(fill, 0, NN * sizeof(int), stream);
        count_kernel<<<egrid, 256, 0, stream>>>(ei, fill);
        scan_a<<<ngrid, 1024, 0, stream>>>(fill, rp, partials);
        scan_b<<<1, 64, 0, stream>>>(partials, ngrid);
        scan_c<<<ngrid, 1024, 0, stream>>>(rp, fill, partials);
        scatter_kernel<<<egrid, 256, 0, stream>>>(ei, eattr, fill, attr16, src_arr, eid_perm);
    }

    if (attr16) {
        // ---- fast path: layer-0 constant-row + fused h_in + bf16 z ----
        hipMemsetAsync(cnt, 0, GG * sizeof(int), stream);
        cnt_kernel<<<64, 256, 0, stream>>>(batch, cnt);

        // layer 0
        vn0_kernel<<<GG, 256, 0, stream>>>(
            cnt, node_emb, vn_emb, vn,
            vn_W1, vn_b1, vbn1_g, vbn1_b, vbn1_m, vbn1_v,
            vn_W2, vn_b2, vbn2_g, vbn2_b, vbn2_m, vbn2_v);
        gin0_kernel<<<NN / 4, 256, 0, stream>>>(
            node_emb, vn_emb, rp, attr16, edge_W, edge_b, eps, aggh, aggl);
        mlp_mfma_kernel<<<NP / 64, 256, 0, stream>>>(
            agg, aggh, aggl, 1, w1h, w1l, w2h, w2l, bn1sc, bn1sh, bn2sc, bn2sh,
            h, 0, 1, batch, vn, h16, 1);          // h <- h_in(1), h16 shadow

        // layer 1
        hipMemsetAsync(vt, 0, GDB, stream);
        vt_kernel<<<NN / 16, 256, 0, stream>>>(h, batch, vt);
        vn_kernel<<<GG, 256, 0, stream>>>(
            vt, vn, vn_W1, vn_b1, vbn1_g, vbn1_b, vbn1_m, vbn1_v,
            vn_W2, vn_b2, vbn2_g, vbn2_b, vbn2_m, vbn2_v, 1);   // vn <- vn(2)
        gin_agg_kernel<<<NN / 4, 256, 0, stream>>>(
            h, h16, rp, attr16, src_arr, edge_W, edge_b, eps, aggh, aggl, 1);
        mlp_mfma_kernel<<<NP / 64, 256, 0, stream>>>(
            agg, aggh, aggl, 1, w1h, w1l, w2h, w2l, bn1sc, bn1sh, bn2sc, bn2sh,
            h, 1, 1, batch, vn, h16, 1);          // h <- h_in(2), h16 shadow

        // layer 2 (final; no vn add, no relu)
        gin_agg_kernel<<<NN / 4, 256, 0, stream>>>(
            h, h16, rp, attr16, src_arr, edge_W, edge_b, eps, aggh, aggl, 2);
        mlp_mfma_kernel<<<NP / 64, 256, 0, stream>>>(
            agg, aggh, aggl, 1, w1h, w1l, w2h, w2l, bn1sc, bn1sh, bn2sc, bn2sh,
            h, 2, 0, batch, vn, h16, 0);
    } else {
        // ---- fallback: original schedule (fp32 z) ----
        {
            long total = (long)NN * DD;
            init_kernel<<<(int)((total + 255) / 256), 256, 0, stream>>>(
                x, node_emb, vn_emb, h, vn);
        }
        for (int l = 0; l < LL; ++l) {
            int accum = (l < LL - 1) ? 1 : 0;
            if (accum)
                hipMemsetAsync(vt, 0, GDB, stream);

            hin_kernel<<<NN / (R1 * 2), 256, 0, stream>>>(
                h, h16, vn, batch, eps, agg, vt, l, accum, 1);

            if (eid_perm) {
                gin_agg_eid_kernel<<<NN / 2, 256, 0, stream>>>(
                    h, rp, eid_perm, ei, eattr, edge_W, edge_b, eps, agg, l);
            } else {
                edge_kernel<<<(EE + EPB - 1) / EPB, 256, 0, stream>>>(
                    h, ei, eattr, edge_W, edge_b, agg, l);
            }

            mlp_mfma_kernel<<<NP / 64, 256, 0, stream>>>(
                agg, nullptr, nullptr, 0, w1h, w1l, w2h, w2l,
                bn1sc, bn1sh, bn2sc, bn2sh,
                h, l, accum, batch, vn, h16, 0);

            if (accum)
                vn_kernel<<<GG, 256, 0, stream>>>(
                    vt, vn, vn_W1, vn_b1, vbn1_g, vbn1_b, vbn1_m, vbn1_v,
                    vn_W2, vn_b2, vbn2_g, vbn2_b, vbn2_m, vbn2_v, l);
        }
    }
}

// Round 9
// 653.323 us; speedup vs baseline: 4.4390x; 1.1374x over previous
//
#include <hip/hip_runtime.h>
#include <hip/hip_bf16.h>

#define NN 100000
#define NP 100032              // NN rounded up to 64
#define EE 1600000
#define GG 128
#define DD 128
#define LL 3
#define EAA 7
#define BN_EPS 1e-5f

typedef __attribute__((ext_vector_type(8))) short bf16x8;
typedef __attribute__((ext_vector_type(4))) float f32x4;
typedef __attribute__((ext_vector_type(4))) unsigned short u16x4;
typedef _Float16 f16x2 __attribute__((ext_vector_type(2)));

__device__ __forceinline__ unsigned short f2bf(float x) {
    unsigned int u = __float_as_uint(x);
    u = (u + 0x7FFF + ((u >> 16) & 1)) >> 16;
    return (unsigned short)u;
}
__device__ __forceinline__ float bf2f(unsigned short h) {
    return __uint_as_float(((unsigned int)h) << 16);
}
__device__ __forceinline__ float bflo(unsigned int u) {
    return __uint_as_float(u << 16);
}
__device__ __forceinline__ float bfhi(unsigned int u) {
    return __uint_as_float(u & 0xFFFF0000u);
}
__device__ __forceinline__ unsigned int pkf16(float a, float b) {
    f16x2 v = {(_Float16)a, (_Float16)b};
    return __builtin_bit_cast(unsigned int, v);
}

#if __has_builtin(__builtin_amdgcn_fdot2)
#define DOT2(q, w, c) __builtin_amdgcn_fdot2((q), (w), (c), false)
#else
__device__ __forceinline__ float dot2_sw(f16x2 a, f16x2 b, float c) {
    return fmaf((float)a.x, (float)b.x, fmaf((float)a.y, (float)b.y, c));
}
#define DOT2(q, w, c) dot2_sw((q), (w), (c))
#endif

// ---------------------------------------------------------------------------
// Fallback-only K0: h[i,:] = node_emb[x[i],:]; vn[g,:] = vn_emb[0,:]
// ---------------------------------------------------------------------------
__global__ __launch_bounds__(256) void init_kernel(
    const int* __restrict__ x, const float* __restrict__ node_emb,
    const float* __restrict__ vn_emb, float* __restrict__ h,
    float* __restrict__ vn)
{
    long i = (long)blockIdx.x * 256 + threadIdx.x;
    if (i < (long)NN * DD) {
        int node = (int)(i >> 7), d = (int)(i & 127);
        h[i] = node_emb[(long)x[node] * DD + d];
    }
    if (i < GG * DD) vn[i] = vn_emb[i & 127];
}

// ---------------------------------------------------------------------------
// Fallback-only K1: in-place h -> h_in = h + vn[batch]; h16 shadow; agg; vt.
// ---------------------------------------------------------------------------
#define R1 8
__global__ __launch_bounds__(256) void hin_kernel(
    float* __restrict__ hbuf,
    unsigned short* __restrict__ h16,
    const float* __restrict__ vn,
    const int* __restrict__ batch,
    const float* __restrict__ eps,
    float* __restrict__ agg,
    float* __restrict__ vt,
    int layer, int accum_vt, int write_agg)
{
    const int d  = threadIdx.x & 127;
    const int rg = threadIdx.x >> 7;
    const float epl = 1.0f + eps[layer];
    const long row0 = (long)blockIdx.x * (R1 * 2);

    float vacc = 0.0f;
    int   vb   = -1;
    #pragma unroll
    for (int r = 0; r < R1; ++r) {
        long row = row0 + rg + 2 * r;
        if (row >= NN) break;
        int b = batch[row];
        long idx = row * DD + d;
        float hv = hbuf[idx] + vn[(long)b * DD + d];
        hbuf[idx] = hv;
        h16[idx]  = f2bf(hv);
        if (write_agg) agg[idx] = epl * hv;
        if (accum_vt) {
            if (b != vb) {
                if (vb >= 0) atomicAdd(&vt[(long)vb * DD + d], vacc);
                vb = b; vacc = 0.0f;
            }
            vacc += hv;
        }
    }
    if (accum_vt && vb >= 0) atomicAdd(&vt[(long)vb * DD + d], vacc);
}

// ---------------------------------------------------------------------------
// vt segment-sum only (reads h_in fp32), run-length fused atomics.
// ---------------------------------------------------------------------------
__global__ __launch_bounds__(256) void vt_kernel(
    const float* __restrict__ hbuf, const int* __restrict__ batch,
    float* __restrict__ vt)
{
    const int d  = threadIdx.x & 127;
    const int rg = threadIdx.x >> 7;
    const long row0 = (long)blockIdx.x * 16;
    float vacc = 0.0f;
    int   vb   = -1;
    #pragma unroll
    for (int r = 0; r < 8; ++r) {
        long row = row0 + rg + 2 * r;
        if (row >= NN) break;
        int b = batch[row];
        float hv = hbuf[row * DD + d];
        if (b != vb) {
            if (vb >= 0) atomicAdd(&vt[(long)vb * DD + d], vacc);
            vb = b; vacc = 0.0f;
        }
        vacc += hv;
    }
    if (vb >= 0) atomicAdd(&vt[(long)vb * DD + d], vacc);
}

// ---------------------------------------------------------------------------
// Per-graph node counts (batch sorted; run-length fused atomics).
// ---------------------------------------------------------------------------
__global__ __launch_bounds__(256) void cnt_kernel(
    const int* __restrict__ batch, int* __restrict__ cnt)
{
    const int tid = blockIdx.x * 256 + threadIdx.x;     // 64*256 = 16384 threads
    const int CH  = (NN + 16383) / 16384;               // 7
    long s = (long)tid * CH;
    long e = s + CH; if (e > NN) e = NN;
    int vb = -1, c = 0;
    for (long i = s; i < e; ++i) {
        int b = batch[i];
        if (b != vb) { if (vb >= 0) atomicAdd(&cnt[vb], c); vb = b; c = 0; }
        ++c;
    }
    if (vb >= 0) atomicAdd(&cnt[vb], c);
}

// ---------------------------------------------------------------------------
// CSR build: count -> scan -> scatter. Built once, reused by all 3 layers.
// ---------------------------------------------------------------------------
__global__ __launch_bounds__(256) void count_kernel(
    const int* __restrict__ ei, int* __restrict__ deg)
{
    long e = (long)blockIdx.x * 256 + threadIdx.x;
    if (e < EE) atomicAdd(&deg[ei[EE + e]], 1);
}

__global__ __launch_bounds__(1024) void scan_a(
    const int* __restrict__ deg, int* __restrict__ rp, int* __restrict__ partials)
{
    __shared__ int s[1024];
    int t = threadIdx.x;
    long i = (long)blockIdx.x * 1024 + t;
    int v = (i < NN) ? deg[i] : 0;
    s[t] = v;
    __syncthreads();
    for (int off = 1; off < 1024; off <<= 1) {
        int u = (t >= off) ? s[t - off] : 0;
        __syncthreads();
        s[t] += u;
        __syncthreads();
    }
    if (i < NN) rp[i] = s[t] - v;
    if (t == 1023) partials[blockIdx.x] = s[1023];
}

__global__ void scan_b(int* __restrict__ partials, int nb)
{
    if (threadIdx.x == 0) {
        int run = 0;
        for (int i = 0; i < nb; ++i) { int v = partials[i]; partials[i] = run; run += v; }
    }
}

__global__ __launch_bounds__(1024) void scan_c(
    int* __restrict__ rp, int* __restrict__ fill, const int* __restrict__ partials)
{
    long i = (long)blockIdx.x * 1024 + threadIdx.x;
    if (i < NN) {
        int v = rp[i] + partials[blockIdx.x];
        rp[i] = v;
        fill[i] = v;
    }
    if (i == 0) rp[NN] = EE;
}

// Tier-1: attr16 = 4 dwords per edge (7 fp16 attrs packed in pairs + pad).
__global__ __launch_bounds__(256) void scatter_kernel(
    const int* __restrict__ ei, const float* __restrict__ eattr,
    int* __restrict__ fill, unsigned int* __restrict__ attr16,
    int* __restrict__ src_arr, int* __restrict__ eid_perm)
{
    long e = (long)blockIdx.x * 256 + threadIdx.x;
    if (e >= EE) return;
    int dst = ei[EE + e];
    int pos = atomicAdd(&fill[dst], 1);
    if (attr16) {
        uint4 w;
        w.x = pkf16(eattr[e * EAA + 0], eattr[e * EAA + 1]);
        w.y = pkf16(eattr[e * EAA + 2], eattr[e * EAA + 3]);
        w.z = pkf16(eattr[e * EAA + 4], eattr[e * EAA + 5]);
        w.w = pkf16(eattr[e * EAA + 6], 0.0f);
        *(uint4*)(attr16 + (long)pos * 4) = w;
        src_arr[pos] = ei[e];
    } else {
        eid_perm[pos] = (int)e;
    }
}

// Shared edge-transform macro pieces: weight-pair preamble builds
// wx[4]/wy[4] (fp16 pairs along attr dim) for this lane's 2 columns.
#define WPAIR_PREAMBLE(eWl)                                                   \
    f16x2 wx[4], wy[4];                                                       \
    {                                                                         \
        _Pragma("unroll")                                                     \
        for (int j = 0; j < 3; ++j) {                                         \
            float2 p0 = *(const float2*)&(eWl)[(2 * j) * DD + d0];            \
            float2 p1 = *(const float2*)&(eWl)[(2 * j + 1) * DD + d0];        \
            wx[j] = (f16x2){(_Float16)p0.x, (_Float16)p1.x};                  \
            wy[j] = (f16x2){(_Float16)p0.y, (_Float16)p1.y};                  \
        }                                                                     \
        float2 p6 = *(const float2*)&(eWl)[6 * DD + d0];                      \
        wx[3] = (f16x2){(_Float16)p6.x, (_Float16)0.0f};                      \
        wy[3] = (f16x2){(_Float16)p6.y, (_Float16)0.0f};                      \
    }

#define EDOT(AU, EX, EY)                                                      \
    float EX = bias.x, EY = bias.y;                                           \
    {                                                                         \
        f16x2 q0 = __builtin_bit_cast(f16x2, AU.x);                           \
        f16x2 q1 = __builtin_bit_cast(f16x2, AU.y);                           \
        f16x2 q2 = __builtin_bit_cast(f16x2, AU.z);                           \
        f16x2 q3 = __builtin_bit_cast(f16x2, AU.w);                           \
        EX = DOT2(q0, wx[0], EX); EY = DOT2(q0, wy[0], EY);                   \
        EX = DOT2(q1, wx[1], EX); EY = DOT2(q1, wy[1], EY);                   \
        EX = DOT2(q2, wx[2], EX); EY = DOT2(q2, wy[2], EY);                   \
        EX = DOT2(q3, wx[3], EX); EY = DOT2(q3, wy[3], EY);                   \
    }

// ---------------------------------------------------------------------------
// K2 layer-0 special: h_in(0) is ONE constant row c = node_emb[0]+vn_emb[0].
// No gathers. Wave-uniform CSR walk via readfirstlane -> scalar (SMEM) loads.
// ---------------------------------------------------------------------------
__global__ __launch_bounds__(256) void gin0_kernel(
    const float* __restrict__ node_emb,
    const float* __restrict__ vn_emb,
    const int* __restrict__ rp,
    const unsigned int* __restrict__ attr16,
    const float* __restrict__ eW, const float* __restrict__ eb,
    const float* __restrict__ eps,
    unsigned short* __restrict__ aggh, unsigned short* __restrict__ aggl)
{
    const int lane = threadIdx.x & 63;
    const int wid  = __builtin_amdgcn_readfirstlane(threadIdx.x >> 6);
    const int n    = blockIdx.x * 4 + wid;               // wave-uniform (SGPR)
    const int d0   = lane * 2;

    WPAIR_PREAMBLE(eW)
    const float2 bias = *(const float2*)&eb[d0];
    const float  epl  = 1.0f + eps[0];

    const float cx = node_emb[d0]     + vn_emb[d0];
    const float cy = node_emb[d0 + 1] + vn_emb[d0 + 1];
    float accx = epl * cx, accy = epl * cy;

    int p        = __builtin_amdgcn_readfirstlane(rp[n]);
    const int p1 = __builtin_amdgcn_readfirstlane(rp[n + 1]);

    #define EDGE0(AU)                                                         \
    {                                                                         \
        EDOT(AU, ex, ey)                                                      \
        float mx = cx + ex, my = cy + ey;                                     \
        accx += fmaxf(mx, 0.0f); accy += fmaxf(my, 0.0f);                     \
    }

    for (; p + 4 <= p1; p += 4) {
        const uint4* a4p = (const uint4*)(attr16 + (long)p * 4);
        uint4 A0 = a4p[0];
        uint4 A1 = a4p[1];
        uint4 A2 = a4p[2];
        uint4 A3 = a4p[3];
        EDGE0(A0)
        EDGE0(A1)
        EDGE0(A2)
        EDGE0(A3)
    }
    for (; p < p1; ++p) {
        uint4 A = *(const uint4*)(attr16 + (long)p * 4);
        EDGE0(A)
    }
    #undef EDGE0

    unsigned short hx = f2bf(accx), hy = f2bf(accy);
    *(unsigned int*)&aggh[(long)n * DD + d0] = (unsigned int)hx | ((unsigned int)hy << 16);
    *(unsigned int*)&aggl[(long)n * DD + d0] =
        (unsigned int)f2bf(accx - bf2f(hx)) | ((unsigned int)f2bf(accy - bf2f(hy)) << 16);
}

// ---------------------------------------------------------------------------
// K2 (CSR): one wave per dst node; lane owns cols {2l, 2l+1}; x4 unroll.
// Wave-uniform p/src/attr via readfirstlane -> SMEM scalar loads; gathers are
// SGPR-base + lane-offset coalesced reads of the bf16 shadow.
// ---------------------------------------------------------------------------
__global__ __launch_bounds__(256) void gin_agg_kernel(
    const float* __restrict__ h_in,
    const unsigned short* __restrict__ h16,
    const int* __restrict__ rp,
    const unsigned int* __restrict__ attr16,
    const int* __restrict__ src_arr,
    const float* __restrict__ eW, const float* __restrict__ eb,
    const float* __restrict__ eps,
    unsigned short* __restrict__ aggh, unsigned short* __restrict__ aggl,
    int layer)
{
    const int lane = threadIdx.x & 63;
    const int wid  = __builtin_amdgcn_readfirstlane(threadIdx.x >> 6);
    const int n    = blockIdx.x * 4 + wid;               // wave-uniform (SGPR)
    const int d0   = lane * 2;

    const float* eWl = eW + (long)layer * EAA * DD;
    WPAIR_PREAMBLE(eWl)
    const float2 bias = *(const float2*)&eb[layer * DD + d0];
    const float  epl  = 1.0f + eps[layer];

    float2 hn = *(const float2*)&h_in[(long)n * DD + d0];
    float accx = epl * hn.x, accy = epl * hn.y;

    int p        = __builtin_amdgcn_readfirstlane(rp[n]);
    const int p1 = __builtin_amdgcn_readfirstlane(rp[n + 1]);

    #define EDGE(AU, GU)                                                      \
    {                                                                         \
        EDOT(AU, ex, ey)                                                      \
        float mx = bflo(GU) + ex, my = bfhi(GU) + ey;                         \
        accx += fmaxf(mx, 0.0f); accy += fmaxf(my, 0.0f);                     \
    }

    for (; p + 4 <= p1; p += 4) {
        int4 sv = *(const int4*)(src_arr + p);           // s_load_dwordx4
        int s0 = __builtin_amdgcn_readfirstlane(sv.x);
        int s1 = __builtin_amdgcn_readfirstlane(sv.y);
        int s2 = __builtin_amdgcn_readfirstlane(sv.z);
        int s3 = __builtin_amdgcn_readfirstlane(sv.w);
        const uint4* a4p = (const uint4*)(attr16 + (long)p * 4);
        uint4 A0 = a4p[0];
        uint4 A1 = a4p[1];
        uint4 A2 = a4p[2];
        uint4 A3 = a4p[3];
        unsigned int g0 = *(const unsigned int*)(h16 + (long)s0 * DD + d0);
        unsigned int g1 = *(const unsigned int*)(h16 + (long)s1 * DD + d0);
        unsigned int g2 = *(const unsigned int*)(h16 + (long)s2 * DD + d0);
        unsigned int g3 = *(const unsigned int*)(h16 + (long)s3 * DD + d0);
        EDGE(A0, g0)
        EDGE(A1, g1)
        EDGE(A2, g2)
        EDGE(A3, g3)
    }
    for (; p < p1; ++p) {
        int s = __builtin_amdgcn_readfirstlane(src_arr[p]);
        uint4 A = *(const uint4*)(attr16 + (long)p * 4);
        unsigned int g = *(const unsigned int*)(h16 + (long)s * DD + d0);
        EDGE(A, g)
    }
    #undef EDGE

    unsigned short hx = f2bf(accx), hy = f2bf(accy);
    *(unsigned int*)&aggh[(long)n * DD + d0] = (unsigned int)hx | ((unsigned int)hy << 16);
    *(unsigned int*)&aggl[(long)n * DD + d0] =
        (unsigned int)f2bf(accx - bf2f(hx)) | ((unsigned int)f2bf(accy - bf2f(hy)) << 16);
}

// ---------------------------------------------------------------------------
// K2 fallback A (eid indirection) — fp32 agg
// ---------------------------------------------------------------------------
__global__ __launch_bounds__(256) void gin_agg_eid_kernel(
    const float* __restrict__ h_in,
    const int* __restrict__ rp,
    const int* __restrict__ eid_perm,
    const int* __restrict__ ei,
    const float* __restrict__ eattr,
    const float* __restrict__ eW, const float* __restrict__ eb,
    const float* __restrict__ eps,
    float* __restrict__ agg, int layer)
{
    const int d    = threadIdx.x & 127;
    const int half = threadIdx.x >> 7;
    const long n   = (long)blockIdx.x * 2 + half;

    float w[EAA];
    #pragma unroll
    for (int a = 0; a < EAA; ++a) w[a] = eW[layer * EAA * DD + a * DD + d];
    const float bias = eb[layer * DD + d];
    const float epl  = 1.0f + eps[layer];

    float acc = epl * h_in[n * DD + d];
    const int p0 = rp[n], p1 = rp[n + 1];
    for (int p = p0; p < p1; ++p) {
        int e = eid_perm[p];
        int src = ei[e];
        float ea = bias;
        #pragma unroll
        for (int a = 0; a < EAA; ++a)
            ea = fmaf(eattr[(long)e * EAA + a], w[a], ea);
        float m = h_in[(long)src * DD + d] + ea;
        acc += m > 0.0f ? m : 0.0f;
    }
    agg[n * DD + d] = acc;
}

// ---------------------------------------------------------------------------
// K2 fallback B (atomic path) — fp32 agg
// ---------------------------------------------------------------------------
#define EPB 64
__global__ __launch_bounds__(256) void edge_kernel(
    const float* __restrict__ h_in,
    const int* __restrict__ ei,
    const float* __restrict__ eattr,
    const float* __restrict__ eW,
    const float* __restrict__ eb,
    float* __restrict__ agg,
    int layer)
{
    const int d    = threadIdx.x & 127;
    const int esub = threadIdx.x >> 7;
    float w[EAA];
    #pragma unroll
    for (int a = 0; a < EAA; ++a) w[a] = eW[layer * EAA * DD + a * DD + d];
    const float bias = eb[layer * DD + d];

    const long base = (long)blockIdx.x * EPB;
    for (int k = esub; k < EPB; k += 2) {
        long e = base + k;
        if (e >= EE) break;
        int s = ei[e];
        int t = ei[EE + e];
        float acc = bias;
        #pragma unroll
        for (int a = 0; a < EAA; ++a)
            acc = fmaf(eattr[e * EAA + a], w[a], acc);
        float m = h_in[(long)s * DD + d] + acc;
        m = m > 0.0f ? m : 0.0f;
        atomicAdd(&agg[(long)t * DD + d], m);
    }
}

// ---------------------------------------------------------------------------
// Weight prep (operand-swapped; weights are the MFMA A operand). See R5 notes.
// ---------------------------------------------------------------------------
__global__ __launch_bounds__(256) void wprep_kernel(
    const float* __restrict__ W1, const float* __restrict__ W2,
    unsigned short* __restrict__ w1h, unsigned short* __restrict__ w1l,
    unsigned short* __restrict__ w2h, unsigned short* __restrict__ w2l)
{
    int tid = blockIdx.x * 256 + threadIdx.x;
    if (tid >= LL * 2 * 32768) return;
    int l = tid / 65536;
    int rem = tid - l * 65536;
    int mat = rem >> 15;
    int fi = rem & 32767;
    int b = fi & 7, lane = (fi >> 3) & 63;
    int kgrp = ((lane >> 4) << 3) + b;
    if (mat == 0) {
        int mt = (fi >> 9) & 15, kk = fi >> 13;
        int m = (mt << 4) + (lane & 15);
        int k = (kk << 5) + kgrp;
        float v = W1[(long)l * DD * 2 * DD + (long)k * 2 * DD + m];
        unsigned short hi = f2bf(v);
        w1h[(long)l * 32768 + fi] = hi;
        w1l[(long)l * 32768 + fi] = f2bf(v - bf2f(hi));
    } else {
        int mt = (fi >> 9) & 7, kk = fi >> 12;
        int m = (mt << 4) + (lane & 15);
        int k = (kk << 5) + kgrp;
        float v = W2[(long)l * 2 * DD * DD + (long)k * DD + m];
        unsigned short hi = f2bf(v);
        w2h[(long)l * 32768 + fi] = hi;
        w2l[(long)l * 32768 + fi] = f2bf(v - bf2f(hi));
    }
}

// ---------------------------------------------------------------------------
// BN prep: fold bias+BN into per-column scale/shift.
// ---------------------------------------------------------------------------
__global__ __launch_bounds__(256) void bnprep_kernel(
    const float* __restrict__ b1, const float* __restrict__ g1,
    const float* __restrict__ be1, const float* __restrict__ m1,
    const float* __restrict__ v1,
    const float* __restrict__ b2, const float* __restrict__ g2,
    const float* __restrict__ be2, const float* __restrict__ m2,
    const float* __restrict__ v2,
    float* __restrict__ sc1, float* __restrict__ sh1,
    float* __restrict__ sc2, float* __restrict__ sh2)
{
    int tid = blockIdx.x * 256 + threadIdx.x;
    if (tid < LL * 2 * DD) {
        float sc = g1[tid] / sqrtf(v1[tid] + BN_EPS);
        sc1[tid] = sc;
        sh1[tid] = (b1[tid] - m1[tid]) * sc + be1[tid];
    }
    int t2 = tid - LL * 2 * DD;
    if (t2 >= 0 && t2 < LL * DD) {
        float sc = g2[t2] / sqrtf(v2[t2] + BN_EPS);
        sc2[t2] = sc;
        sh2[t2] = (b2[t2] - m2[t2]) * sc + be2[t2];
    }
}

// ---------------------------------------------------------------------------
// K3 (MFMA, operand-swapped) with FUSED h_in epilogue.
// zfmt=1: z already split as bf16 hi/lo arrays (no staging conversion).
// zfmt=0: z fp32, split during staging (fallback path).
// fuse=1: out = relu(bn2(h2)) + vn[batch[row]]; write d_out fp32 + h16 bf16.
// ---------------------------------------------------------------------------
__global__ __launch_bounds__(256, 2) void mlp_mfma_kernel(
    const float* __restrict__ z_in,
    const unsigned short* __restrict__ z16h, const unsigned short* __restrict__ z16l,
    int zfmt,
    const unsigned short* __restrict__ w1h, const unsigned short* __restrict__ w1l,
    const unsigned short* __restrict__ w2h, const unsigned short* __restrict__ w2l,
    const float* __restrict__ sc1, const float* __restrict__ sh1,
    const float* __restrict__ sc2, const float* __restrict__ sh2,
    float* __restrict__ h_out, int layer, int do_relu,
    const int* __restrict__ batch, const float* __restrict__ vnbuf,
    unsigned short* __restrict__ h16, int fuse)
{
    __shared__ char lds[65536];
    const int tid  = threadIdx.x;
    const int lane = tid & 63;
    const int wv   = tid >> 6;
    const long row0 = (long)blockIdx.x * 64;
    const int kb = (lane >> 4) << 3;

    // ---- stage z [64][128] -> hi/lo bf16 LDS (hi at 0, lo at 16384) ----
    if (zfmt) {
        const uint4* zh = (const uint4*)(z16h + row0 * DD);
        const uint4* zl = (const uint4*)(z16l + row0 * DD);
        #pragma unroll
        for (int i = 0; i < 4; ++i) {
            int idx = tid + i * 256;
            uint4 hv = zh[idx];
            uint4 lv = zl[idx];
            int r = idx >> 4;
            int c = (idx & 15) << 3;
            int off = ((r << 8) + (c << 1)) ^ ((r & 7) << 4);
            *(uint4*)(lds + off)         = hv;
            *(uint4*)(lds + 16384 + off) = lv;
        }
    } else {
        const float4* zi = (const float4*)(z_in + row0 * DD);
        #pragma unroll
        for (int i = 0; i < 8; ++i) {
            int idx = tid + i * 256;
            float4 v = zi[idx];
            int r = idx >> 5;
            int c = (idx & 31) << 2;
            u16x4 hv, lv;
            hv.x = f2bf(v.x); lv.x = f2bf(v.x - bf2f(hv.x));
            hv.y = f2bf(v.y); lv.y = f2bf(v.y - bf2f(hv.y));
            hv.z = f2bf(v.z); lv.z = f2bf(v.z - bf2f(hv.z));
            hv.w = f2bf(v.w); lv.w = f2bf(v.w - bf2f(hv.w));
            int off = ((r << 8) + (c << 1)) ^ ((r & 7) << 4);
            *(u16x4*)(lds + off)         = hv;
            *(u16x4*)(lds + 16384 + off) = lv;
        }
    }
    __syncthreads();

    // ---- B1 frags (z^T): B[k][n], lane&15 = n (node row within tile) ----
    bf16x8 B1h[4][4], B1l[4][4];
    #pragma unroll
    for (int nt = 0; nt < 4; ++nt) {
        int r = (nt << 4) + (lane & 15);
        #pragma unroll
        for (int kk = 0; kk < 4; ++kk) {
            int off = ((r << 8) + (((kk << 5) + kb) << 1)) ^ ((r & 7) << 4);
            B1h[nt][kk] = *(const bf16x8*)(lds + off);
            B1l[nt][kk] = *(const bf16x8*)(lds + 16384 + off);
        }
    }
    __syncthreads();   // z reads done; LDS becomes u (hi at 0, lo at 32768)

    // ---- GEMM1 + BN1 + relu -> u in LDS (wave owns m-tiles wv*4..wv*4+3) ----
    const unsigned short* w1hl = w1h + (long)layer * 32768;
    const unsigned short* w1ll = w1l + (long)layer * 32768;
    #pragma unroll
    for (int mtl = 0; mtl < 4; ++mtl) {
        const int mt = (wv << 2) + mtl;
        bf16x8 Ah[4], Al[4];
        #pragma unroll
        for (int kk = 0; kk < 4; ++kk) {
            const long boff = ((long)((kk << 4) + mt) * 64 + lane) << 3;
            Ah[kk] = *(const bf16x8*)(w1hl + boff);
            Al[kk] = *(const bf16x8*)(w1ll + boff);
        }
        f32x4 acc[4];
        #pragma unroll
        for (int nt = 0; nt < 4; ++nt) acc[nt] = (f32x4){0.f, 0.f, 0.f, 0.f};
        #pragma unroll
        for (int kk = 0; kk < 4; ++kk) {
            #pragma unroll
            for (int nt = 0; nt < 4; ++nt) {
                acc[nt] = __builtin_amdgcn_mfma_f32_16x16x32_bf16(Ah[kk], B1h[nt][kk], acc[nt], 0, 0, 0);
                acc[nt] = __builtin_amdgcn_mfma_f32_16x16x32_bf16(Ah[kk], B1l[nt][kk], acc[nt], 0, 0, 0);
                acc[nt] = __builtin_amdgcn_mfma_f32_16x16x32_bf16(Al[kk], B1h[nt][kk], acc[nt], 0, 0, 0);
            }
        }
        const int m0 = (mt << 4) + ((lane >> 4) << 2);
        const float4 s4 = *(const float4*)&sc1[layer * 2 * DD + m0];
        const float4 t4 = *(const float4*)&sh1[layer * 2 * DD + m0];
        #pragma unroll
        for (int nt = 0; nt < 4; ++nt) {
            int row = (nt << 4) + (lane & 15);
            float u0 = fmaxf(fmaf(acc[nt][0], s4.x, t4.x), 0.0f);
            float u1 = fmaxf(fmaf(acc[nt][1], s4.y, t4.y), 0.0f);
            float u2 = fmaxf(fmaf(acc[nt][2], s4.z, t4.z), 0.0f);
            float u3 = fmaxf(fmaf(acc[nt][3], s4.w, t4.w), 0.0f);
            u16x4 hv, lv;
            hv.x = f2bf(u0); lv.x = f2bf(u0 - bf2f(hv.x));
            hv.y = f2bf(u1); lv.y = f2bf(u1 - bf2f(hv.y));
            hv.z = f2bf(u2); lv.z = f2bf(u2 - bf2f(hv.z));
            hv.w = f2bf(u3); lv.w = f2bf(u3 - bf2f(hv.w));
            int off = ((row << 9) + (m0 << 1)) ^ ((row & 7) << 4);
            *(u16x4*)(lds + off)         = hv;
            *(u16x4*)(lds + 32768 + off) = lv;
        }
    }
    __syncthreads();

    // ---- GEMM2 + BN2 (+relu/+vn) -> h (wave owns m-tiles wv*2, wv*2+1) ----
    const unsigned short* w2hl = w2h + (long)layer * 32768;
    const unsigned short* w2ll = w2l + (long)layer * 32768;
    f32x4 acc2[2][4];
    #pragma unroll
    for (int mtl = 0; mtl < 2; ++mtl)
        #pragma unroll
        for (int nt = 0; nt < 4; ++nt) acc2[mtl][nt] = (f32x4){0.f, 0.f, 0.f, 0.f};

    #pragma unroll
    for (int kk = 0; kk < 8; ++kk) {
        bf16x8 Bh[4], Bl[4];
        #pragma unroll
        for (int nt = 0; nt < 4; ++nt) {
            int r = (nt << 4) + (lane & 15);
            int off = ((r << 9) + (((kk << 5) + kb) << 1)) ^ ((r & 7) << 4);
            Bh[nt] = *(const bf16x8*)(lds + off);
            Bl[nt] = *(const bf16x8*)(lds + 32768 + off);
        }
        #pragma unroll
        for (int mtl = 0; mtl < 2; ++mtl) {
            const int mt = (wv << 1) + mtl;
            const long boff = ((long)((kk << 3) + mt) * 64 + lane) << 3;
            bf16x8 Ah = *(const bf16x8*)(w2hl + boff);
            bf16x8 Al = *(const bf16x8*)(w2ll + boff);
            #pragma unroll
            for (int nt = 0; nt < 4; ++nt) {
                acc2[mtl][nt] = __builtin_amdgcn_mfma_f32_16x16x32_bf16(Ah, Bh[nt], acc2[mtl][nt], 0, 0, 0);
                acc2[mtl][nt] = __builtin_amdgcn_mfma_f32_16x16x32_bf16(Ah, Bl[nt], acc2[mtl][nt], 0, 0, 0);
                acc2[mtl][nt] = __builtin_amdgcn_mfma_f32_16x16x32_bf16(Al, Bh[nt], acc2[mtl][nt], 0, 0, 0);
            }
        }
    }
    #pragma unroll
    for (int mtl = 0; mtl < 2; ++mtl) {
        const int m0 = ((((wv << 1) + mtl)) << 4) + ((lane >> 4) << 2);
        const float4 s4 = *(const float4*)&sc2[layer * DD + m0];
        const float4 t4 = *(const float4*)&sh2[layer * DD + m0];
        #pragma unroll
        for (int nt = 0; nt < 4; ++nt) {
            long row = row0 + (nt << 4) + (lane & 15);
            if (row < NN) {
                float o0 = fmaf(acc2[mtl][nt][0], s4.x, t4.x);
                float o1 = fmaf(acc2[mtl][nt][1], s4.y, t4.y);
                float o2 = fmaf(acc2[mtl][nt][2], s4.z, t4.z);
                float o3 = fmaf(acc2[mtl][nt][3], s4.w, t4.w);
                if (do_relu) {
                    o0 = fmaxf(o0, 0.0f); o1 = fmaxf(o1, 0.0f);
                    o2 = fmaxf(o2, 0.0f); o3 = fmaxf(o3, 0.0f);
                }
                if (fuse) {
                    int b = batch[row];
                    float4 vnv = *(const float4*)&vnbuf[(long)b * DD + m0];
                    o0 += vnv.x; o1 += vnv.y; o2 += vnv.z; o3 += vnv.w;
                    u16x4 hv;
                    hv.x = f2bf(o0); hv.y = f2bf(o1);
                    hv.z = f2bf(o2); hv.w = f2bf(o3);
                    *(u16x4*)&h16[row * DD + m0] = hv;
                }
                *(float4*)&h_out[row * DD + m0] = make_float4(o0, o1, o2, o3);
            }
        }
    }
}

// ---------------------------------------------------------------------------
// K4: virtual-node MLP. One block per graph g. row = vt[g] + vn[g].
// ---------------------------------------------------------------------------
__global__ __launch_bounds__(256) void vn_kernel(
    const float* __restrict__ vt, float* __restrict__ vn,
    const float* __restrict__ W1, const float* __restrict__ b1,
    const float* __restrict__ g1, const float* __restrict__ be1,
    const float* __restrict__ m1, const float* __restrict__ v1,
    const float* __restrict__ W2, const float* __restrict__ b2,
    const float* __restrict__ g2, const float* __restrict__ be2,
    const float* __restrict__ m2, const float* __restrict__ v2,
    int layer)
{
    __shared__ float row[DD];
    __shared__ float u[2 * DD];
    const int g = blockIdx.x;
    const int t = threadIdx.x;

    if (t < DD) row[t] = vt[(long)g * DD + t] + vn[(long)g * DD + t];
    __syncthreads();

    {
        const float* W = W1 + (long)layer * DD * 2 * DD;
        float acc = 0.0f;
        for (int k = 0; k < DD; ++k) acc = fmaf(row[k], W[k * 2 * DD + t], acc);
        const long o = (long)layer * 2 * DD + t;
        float sc = g1[o] / sqrtf(v1[o] + BN_EPS);
        float sh = be1[o] - m1[o] * sc;
        float val = (acc + b1[o]) * sc + sh;
        u[t] = val > 0.0f ? val : 0.0f;
    }
    __syncthreads();

    if (t < DD) {
        const float* W = W2 + (long)layer * 2 * DD * DD;
        float acc = 0.0f;
        for (int k = 0; k < 2 * DD; ++k) acc = fmaf(u[k], W[k * DD + t], acc);
        const long o = (long)layer * DD + t;
        float sc = g2[o] / sqrtf(v2[o] + BN_EPS);
        float sh = be2[o] - m2[o] * sc;
        float val = (acc + b2[o]) * sc + sh;
        vn[(long)g * DD + t] = val > 0.0f ? val : 0.0f;
    }
}

// ---------------------------------------------------------------------------
// K4 layer-0 special: vt(0)+vn(0) = cnt[g]*(node_emb+vn_emb) + vn_emb.
// ---------------------------------------------------------------------------
__global__ __launch_bounds__(256) void vn0_kernel(
    const int* __restrict__ cnt,
    const float* __restrict__ node_emb, const float* __restrict__ vn_emb,
    float* __restrict__ vn,
    const float* __restrict__ W1, const float* __restrict__ b1,
    const float* __restrict__ g1, const float* __restrict__ be1,
    const float* __restrict__ m1, const float* __restrict__ v1,
    const float* __restrict__ W2, const float* __restrict__ b2,
    const float* __restrict__ g2, const float* __restrict__ be2,
    const float* __restrict__ m2, const float* __restrict__ v2)
{
    __shared__ float row[DD];
    __shared__ float u[2 * DD];
    const int g = blockIdx.x;
    const int t = threadIdx.x;

    if (t < DD) {
        float c = node_emb[t] + vn_emb[t];
        row[t] = (float)cnt[g] * c + vn_emb[t];
    }
    __syncthreads();

    {
        float acc = 0.0f;
        for (int k = 0; k < DD; ++k) acc = fmaf(row[k], W1[k * 2 * DD + t], acc);
        float sc = g1[t] / sqrtf(v1[t] + BN_EPS);
        float sh = be1[t] - m1[t] * sc;
        float val = (acc + b1[t]) * sc + sh;
        u[t] = val > 0.0f ? val : 0.0f;
    }
    __syncthreads();

    if (t < DD) {
        float acc = 0.0f;
        for (int k = 0; k < 2 * DD; ++k) acc = fmaf(u[k], W2[k * DD + t], acc);
        float sc = g2[t] / sqrtf(v2[t] + BN_EPS);
        float sh = be2[t] - m2[t] * sc;
        float val = (acc + b2[t]) * sc + sh;
        vn[(long)g * DD + t] = val > 0.0f ? val : 0.0f;
    }
}

// ---------------------------------------------------------------------------
extern "C" void kernel_launch(void* const* d_in, const int* in_sizes, int n_in,
                              void* d_out, int out_size, void* d_ws, size_t ws_size,
                              hipStream_t stream)
{
    const int*   x       = (const int*)  d_in[0];
    const int*   ei      = (const int*)  d_in[1];
    const float* eattr   = (const float*)d_in[2];
    const int*   batch   = (const int*)  d_in[3];
    const float* node_emb= (const float*)d_in[4];
    const float* vn_emb  = (const float*)d_in[5];
    const float* edge_W  = (const float*)d_in[6];
    const float* edge_b  = (const float*)d_in[7];
    const float* eps     = (const float*)d_in[8];
    const float* mlp_W1  = (const float*)d_in[9];
    const float* mlp_b1  = (const float*)d_in[10];
    const float* mbn_g   = (const float*)d_in[11];
    const float* mbn_b   = (const float*)d_in[12];
    const float* mbn_m   = (const float*)d_in[13];
    const float* mbn_v   = (const float*)d_in[14];
    const float* mlp_W2  = (const float*)d_in[15];
    const float* mlp_b2  = (const float*)d_in[16];
    const float* bn_g    = (const float*)d_in[17];
    const float* bn_b    = (const float*)d_in[18];
    const float* bn_m    = (const float*)d_in[19];
    const float* bn_v    = (const float*)d_in[20];
    const float* vn_W1   = (const float*)d_in[21];
    const float* vn_b1   = (const float*)d_in[22];
    const float* vbn1_g  = (const float*)d_in[23];
    const float* vbn1_b  = (const float*)d_in[24];
    const float* vbn1_m  = (const float*)d_in[25];
    const float* vbn1_v  = (const float*)d_in[26];
    const float* vn_W2   = (const float*)d_in[27];
    const float* vn_b2   = (const float*)d_in[28];
    const float* vbn2_g  = (const float*)d_in[29];
    const float* vbn2_b  = (const float*)d_in[30];
    const float* vbn2_m  = (const float*)d_in[31];
    const float* vbn2_v  = (const float*)d_in[32];

    float* h = (float*)d_out;
    char*  ws = (char*)d_ws;

    size_t off = 0;
    auto alloc = [&](size_t bytes) -> void* {
        void* p = ws + off;
        off += (bytes + 255) & ~(size_t)255;
        return p;
    };
    const size_t GDB = (size_t)GG * DD * sizeof(float);

    float* agg      = (float*)alloc((size_t)NP * DD * sizeof(float));
    unsigned short* aggh = (unsigned short*)agg;                 // alias: z hi
    unsigned short* aggl = aggh + (size_t)NP * DD;               // alias: z lo
    unsigned short* h16 = (unsigned short*)alloc((size_t)NN * DD * sizeof(unsigned short));
    float* vn       = (float*)alloc(GDB);
    float* vt       = (float*)alloc(GDB);
    int*   rp       = (int*)  alloc((NN + 1) * sizeof(int));
    int*   fill     = (int*)  alloc(NN * sizeof(int));
    int*   partials = (int*)  alloc(128 * sizeof(int));
    int*   cnt      = (int*)  alloc(GG * sizeof(int));
    int*   src_arr  = (int*)  alloc((size_t)EE * sizeof(int));
    unsigned short* w1h = (unsigned short*)alloc(LL * 32768 * sizeof(unsigned short));
    unsigned short* w1l = (unsigned short*)alloc(LL * 32768 * sizeof(unsigned short));
    unsigned short* w2h = (unsigned short*)alloc(LL * 32768 * sizeof(unsigned short));
    unsigned short* w2l = (unsigned short*)alloc(LL * 32768 * sizeof(unsigned short));
    float* bn1sc = (float*)alloc(LL * 2 * DD * sizeof(float));
    float* bn1sh = (float*)alloc(LL * 2 * DD * sizeof(float));
    float* bn2sc = (float*)alloc(LL * DD * sizeof(float));
    float* bn2sh = (float*)alloc(LL * DD * sizeof(float));
    const size_t base_end = off;

    unsigned int* attr16 = nullptr;
    int* eid_perm = nullptr;
    if (ws_size >= base_end + (size_t)EE * 4 * sizeof(unsigned int))
        attr16 = (unsigned int*)alloc((size_t)EE * 4 * sizeof(unsigned int));
    else if (ws_size >= base_end + (size_t)EE * sizeof(int))
        eid_perm = (int*)alloc((size_t)EE * sizeof(int));

    // Weight/BN prep (once)
    wprep_kernel<<<(LL * 2 * 32768 + 255) / 256, 256, 0, stream>>>(
        mlp_W1, mlp_W2, w1h, w1l, w2h, w2l);
    bnprep_kernel<<<(LL * 2 * DD + LL * DD + 255) / 256, 256, 0, stream>>>(
        mlp_b1, mbn_g, mbn_b, mbn_m, mbn_v,
        mlp_b2, bn_g, bn_b, bn_m, bn_v,
        bn1sc, bn1sh, bn2sc, bn2sh);

    // CSR build (once)
    const bool csr = (attr16 != nullptr) || (eid_perm != nullptr);
    if (csr) {
        const int egrid = (EE + 255) / 256;
        const int ngrid = (NN + 1023) / 1024;
        hipMemsetAsync(fill, 0, NN * sizeof(int), stream);
        count_kernel<<<egrid, 256, 0, stream>>>(ei, fill);
        scan_a<<<ngrid, 1024, 0, stream>>>(fill, rp, partials);
        scan_b<<<1, 64, 0, stream>>>(partials, ngrid);
        scan_c<<<ngrid, 1024, 0, stream>>>(rp, fill, partials);
        scatter_kernel<<<egrid, 256, 0, stream>>>(ei, eattr, fill, attr16, src_arr, eid_perm);
    }

    if (attr16) {
        // ---- fast path: layer-0 constant-row + fused h_in + bf16 z ----
        hipMemsetAsync(cnt, 0, GG * sizeof(int), stream);
        cnt_kernel<<<64, 256, 0, stream>>>(batch, cnt);

        // layer 0
        vn0_kernel<<<GG, 256, 0, stream>>>(
            cnt, node_emb, vn_emb, vn,
            vn_W1, vn_b1, vbn1_g, vbn1_b, vbn1_m, vbn1_v,
            vn_W2, vn_b2, vbn2_g, vbn2_b, vbn2_m, vbn2_v);
        gin0_kernel<<<NN / 4, 256, 0, stream>>>(
            node_emb, vn_emb, rp, attr16, edge_W, edge_b, eps, aggh, aggl);
        mlp_mfma_kernel<<<NP / 64, 256, 0, stream>>>(
            agg, aggh, aggl, 1, w1h, w1l, w2h, w2l, bn1sc, bn1sh, bn2sc, bn2sh,
            h, 0, 1, batch, vn, h16, 1);          // h <- h_in(1), h16 shadow

        // layer 1
        hipMemsetAsync(vt, 0, GDB, stream);
        vt_kernel<<<NN / 16, 256, 0, stream>>>(h, batch, vt);
        vn_kernel<<<GG, 256, 0, stream>>>(
            vt, vn, vn_W1, vn_b1, vbn1_g, vbn1_b, vbn1_m, vbn1_v,
            vn_W2, vn_b2, vbn2_g, vbn2_b, vbn2_m, vbn2_v, 1);   // vn <- vn(2)
        gin_agg_kernel<<<NN / 4, 256, 0, stream>>>(
            h, h16, rp, attr16, src_arr, edge_W, edge_b, eps, aggh, aggl, 1);
        mlp_mfma_kernel<<<NP / 64, 256, 0, stream>>>(
            agg, aggh, aggl, 1, w1h, w1l, w2h, w2l, bn1sc, bn1sh, bn2sc, bn2sh,
            h, 1, 1, batch, vn, h16, 1);          // h <- h_in(2), h16 shadow

        // layer 2 (final; no vn add, no relu)
        gin_agg_kernel<<<NN / 4, 256, 0, stream>>>(
            h, h16, rp, attr16, src_arr, edge_W, edge_b, eps, aggh, aggl, 2);
        mlp_mfma_kernel<<<NP / 64, 256, 0, stream>>>(
            agg, aggh, aggl, 1, w1h, w1l, w2h, w2l, bn1sc, bn1sh, bn2sc, bn2sh,
            h, 2, 0, batch, vn, h16, 0);
    } else {
        // ---- fallback: original schedule (fp32 z) ----
        {
            long total = (long)NN * DD;
            init_kernel<<<(int)((total + 255) / 256), 256, 0, stream>>>(
                x, node_emb, vn_emb, h, vn);
        }
        for (int l = 0; l < LL; ++l) {
            int accum = (l < LL - 1) ? 1 : 0;
            if (accum)
                hipMemsetAsync(vt, 0, GDB, stream);

            hin_kernel<<<NN / (R1 * 2), 256, 0, stream>>>(
                h, h16, vn, batch, eps, agg, vt, l, accum, 1);

            if (eid_perm) {
                gin_agg_eid_kernel<<<NN / 2, 256, 0, stream>>>(
                    h, rp, eid_perm, ei, eattr, edge_W, edge_b, eps, agg, l);
            } else {
                edge_kernel<<<(EE + EPB - 1) / EPB, 256, 0, stream>>>(
                    h, ei, eattr, edge_W, edge_b, agg, l);
            }

            mlp_mfma_kernel<<<NP / 64, 256, 0, stream>>>(
                agg, nullptr, nullptr, 0, w1h, w1l, w2h, w2l,
                bn1sc, bn1sh, bn2sc, bn2sh,
                h, l, accum, batch, vn, h16, 0);

            if (accum)
                vn_kernel<<<GG, 256, 0, stream>>>(
                    vt, vn, vn_W1, vn_b1, vbn1_g, vbn1_b, vbn1_m, vbn1_v,
                    vn_W2, vn_b2, vbn2_g, vbn2_b, vbn2_m, vbn2_v, l);
        }
    }
}